// Round 9
// baseline (3922.075 us; speedup 1.0000x reference)
//
#include <hip/hip_runtime.h>

#define NN 100000
#define NE 400000
#define DD 128
#define D3 384
#define KL 2
#define EPSBN 1e-5f
#define EB2 (NE/128)
#define SCB ((NN + 1023) / 1024)

typedef __attribute__((ext_vector_type(8))) short s16x8;
typedef __attribute__((ext_vector_type(4))) float f32x4;
typedef __attribute__((ext_vector_type(4))) unsigned short u16x4;

#define ST_SUM    0      // [384]
#define ST_SQ     384    // [384]
#define ST_SCALE  768    // [384]
#define ST_SHIFT  1152   // [384]
#define ST_SUM1   1536
#define ST_SQ1    1537
#define ST_MAX    1538
#define ST_SEXP   1539
#define ST_SCALE1 1540
#define ST_SHIFT1 1541
#define ST_SUM2   1542   // [128]
#define ST_SQ2    1670   // [128]
#define ST_SCALE2 1798   // [128]
#define ST_SHIFT2 1926   // [128]
#define ST_TOTAL  2054

__device__ __forceinline__ float bf2f(unsigned short u){
  return __uint_as_float(((unsigned int)u) << 16);
}
__device__ __forceinline__ unsigned short f2bf(float f){
  unsigned int x = __float_as_uint(f);
  x = x + 0x7FFFu + ((x >> 16) & 1u);
  return (unsigned short)(x >> 16);
}

// ---------------- init: x -> xcur (f32) + xb (bf16), vectorized ----------------
__global__ void init_x(const float* __restrict__ x, float* __restrict__ xcur,
                       unsigned short* __restrict__ xb){
  const int tot = NN*DD/4;
  int stride = gridDim.x * blockDim.x;
  for (int i = blockIdx.x*blockDim.x + threadIdx.x; i < tot; i += stride){
    f32x4 v = ((const f32x4*)x)[i];
    ((f32x4*)xcur)[i] = v;
    u16x4 o; o[0]=f2bf(v[0]); o[1]=f2bf(v[1]); o[2]=f2bf(v[2]); o[3]=f2bf(v[3]);
    ((u16x4*)xb)[i] = o;
  }
}

// ---------------- weight prep (per layer) ----------------
__global__ void wprep(const float* __restrict__ WT, const float* __restrict__ WM,
                      const float* __restrict__ WB, const float* __restrict__ Wtw,
                      unsigned short* __restrict__ Wcat, unsigned short* __restrict__ Wtwb){
  int stride = gridDim.x * blockDim.x;
  int tid = blockIdx.x*blockDim.x + threadIdx.x;
  for (int i = tid; i < 384*384; i += stride){
    int n = i / 384, k = i - n*384;
    float v;
    if (n < 128)      v = WT[n*384 + k];
    else if (n < 256) v = WM[(n-128)*384 + k];
    else              v = WB[(n-256)*384 + k];
    Wcat[i] = f2bf(v);
  }
  for (int i = tid; i < 128*128; i += stride) Wtwb[i] = f2bf(Wtw[i]);
}

// ---------------- CSR build ----------------
__global__ void csr_cnt(const int* __restrict__ twi, int* __restrict__ cnt){
  int e = blockIdx.x*blockDim.x + threadIdx.x;
  if (e < NE){
    atomicAdd(&cnt[0*NN + twi[0*NE + e]], 1);
    atomicAdd(&cnt[1*NN + twi[1*NE + e]], 1);
    atomicAdd(&cnt[2*NN + twi[2*NE + e]], 1);
  }
}

__global__ void scan_bs(const int* __restrict__ cnt, int* __restrict__ bsums){
  const int p = blockIdx.y, b = blockIdx.x, t = threadIdx.x;
  const int base = b * 1024;
  int s = 0;
  #pragma unroll
  for (int j = 0; j < 4; j++){
    int i = base + t + j*256;
    if (i < NN) s += cnt[p*NN + i];
  }
  __shared__ int red[256];
  red[t] = s; __syncthreads();
  #pragma unroll
  for (int o = 128; o; o >>= 1){
    if (t < o) red[t] += red[t+o];
    __syncthreads();
  }
  if (t == 0) bsums[p*SCB + b] = red[0];
}

__global__ void scan_top(int* __restrict__ bsums){
  const int p = threadIdx.x;
  if (p < 3){
    int run = 0;
    for (int i = 0; i < SCB; i++){ int v = bsums[p*SCB + i]; bsums[p*SCB + i] = run; run += v; }
  }
}

__global__ void scan_fin(const int* __restrict__ cnt, const int* __restrict__ bsums,
                         int* __restrict__ start){
  const int p = blockIdx.y, b = blockIdx.x, t = threadIdx.x;
  const int base = b * 1024;
  int v[4]; int s = 0;
  #pragma unroll
  for (int j = 0; j < 4; j++){
    int i = base + t*4 + j;
    v[j] = (i < NN) ? cnt[p*NN + i] : 0;
    s += v[j];
  }
  __shared__ int red[256];
  red[t] = s; __syncthreads();
  #pragma unroll
  for (int o = 1; o < 256; o <<= 1){
    int other = (t >= o) ? red[t - o] : 0;
    __syncthreads();
    red[t] += other;
    __syncthreads();
  }
  int ex = red[t] - s + bsums[p*SCB + b];
  #pragma unroll
  for (int j = 0; j < 4; j++){
    int i = base + t*4 + j;
    if (i < NN) start[p*NN + i] = ex;
    ex += v[j];
  }
}

__global__ void csr_fill(const int* __restrict__ twi, const int* __restrict__ start,
                         int* __restrict__ cursor, int* __restrict__ lists){
  int e = blockIdx.x*blockDim.x + threadIdx.x;
  if (e < NE){
    #pragma unroll
    for (int p = 0; p < 3; p++){
      int n = twi[p*NE + e];
      int pos = atomicAdd(&cursor[p*NN + n], 1);
      lists[(size_t)p*NE + start[p*NN + n] + pos] = e;
    }
  }
}

// --- gathered GEMM: 2 edge-groups/wave (24 pinned gathers), NP parts/dispatch ---
template<int NP, int DOSCORE>
__launch_bounds__(256)
__global__ void g1k(const unsigned short* __restrict__ xb,
                    const unsigned short* __restrict__ Wcat,
                    const float* __restrict__ W1,
                    const int* __restrict__ twi,
                    unsigned short* __restrict__ h,
                    float* __restrict__ sp,
                    float* __restrict__ stats,
                    int p0){
  __shared__ unsigned short ltu[4][16][128];   // 16 KB bf16 repack
  __shared__ float ssum[128], ssq[128];
  __shared__ float s1s[4], s1q[4];
  const int t = threadIdx.x;
  const int w = t >> 6, lane = t & 63;
  const int lc = lane & 15, kg = lane >> 4;
  const int eBase = blockIdx.x * 128;
  const int edgeA = eBase + w*16 + lc;
  const int edgeB = edgeA + 64;
  const int ndA0 = twi[edgeA], ndA1 = twi[NE + edgeA], ndA2 = twi[2*NE + edgeA];
  const int ndB0 = twi[edgeB], ndB1 = twi[NE + edgeB], ndB2 = twi[2*NE + edgeB];

  // ---- issue ALL 24 gathers back-to-back; opaque asm pins (no remat/sink) ----
  s16x8 arA[12], arB[12];
  #pragma unroll
  for (int ks = 0; ks < 12; ks++){
    const int nd = (ks < 4) ? ndA0 : ((ks < 8) ? ndA1 : ndA2);
    arA[ks] = *(const s16x8*)(xb + (size_t)nd*DD + (ks & 3)*32 + kg*8);
  }
  #pragma unroll
  for (int ks = 0; ks < 12; ks++){
    const int nd = (ks < 4) ? ndB0 : ((ks < 8) ? ndB1 : ndB2);
    arB[ks] = *(const s16x8*)(xb + (size_t)nd*DD + (ks & 3)*32 + kg*8);
  }
  asm volatile(""
    : "+v"(arA[0]), "+v"(arA[1]), "+v"(arA[2]),  "+v"(arA[3]),
      "+v"(arA[4]), "+v"(arA[5]), "+v"(arA[6]),  "+v"(arA[7]),
      "+v"(arA[8]), "+v"(arA[9]), "+v"(arA[10]), "+v"(arA[11]));
  asm volatile(""
    : "+v"(arB[0]), "+v"(arB[1]), "+v"(arB[2]),  "+v"(arB[3]),
      "+v"(arB[4]), "+v"(arB[5]), "+v"(arB[6]),  "+v"(arB[7]),
      "+v"(arB[8]), "+v"(arB[9]), "+v"(arB[10]), "+v"(arB[11]));

  if (DOSCORE){
    float sa = 0.f, sb = 0.f;
    #pragma unroll
    for (int ks = 0; ks < 12; ks++){
      const float* wp = W1 + ks*32 + kg*8;
      f32x4 w0 = *(const f32x4*)wp;
      f32x4 w1v = *(const f32x4*)(wp + 4);
      #pragma unroll
      for (int j = 0; j < 4; j++){
        sa += bf2f((unsigned short)arA[ks][j])   * w0[j];
        sa += bf2f((unsigned short)arA[ks][4+j]) * w1v[j];
        sb += bf2f((unsigned short)arB[ks][j])   * w0[j];
        sb += bf2f((unsigned short)arB[ks][4+j]) * w1v[j];
      }
    }
    sa += __shfl_xor(sa, 16); sa += __shfl_xor(sa, 32);
    sb += __shfl_xor(sb, 16); sb += __shfl_xor(sb, 32);
    if (lane < 16){ sp[edgeA] = sa; sp[edgeB] = sb; }
    float sv = (lane < 16) ? (sa + sb) : 0.f;
    float qv = (lane < 16) ? (sa*sa + sb*sb) : 0.f;
    #pragma unroll
    for (int o = 8; o; o >>= 1){ sv += __shfl_xor(sv, o); qv += __shfl_xor(qv, o); }
    if (lane == 0){ s1s[w] = sv; s1q[w] = qv; }
    __syncthreads();
    if (t == 0){
      atomicAdd(&stats[ST_SUM1], s1s[0]+s1s[1]+s1s[2]+s1s[3]);
      atomicAdd(&stats[ST_SQ1],  s1q[0]+s1q[1]+s1q[2]+s1q[3]);
    }
  }

  #pragma unroll 1
  for (int pp = 0; pp < NP; pp++){
    const int p = p0 + pp;
    if (t < 128){ ssum[t] = 0.f; ssq[t] = 0.f; }
    __syncthreads();

    const unsigned short* wb = Wcat + (size_t)(p*128 + lc)*D3 + kg*8;
    unsigned short* hp = h + (size_t)pp*NE*DD;
    const int rl = lane >> 5, cg = lane & 31;

    #pragma unroll
    for (int g = 0; g < 2; g++){
      f32x4 acc[8];
      #pragma unroll
      for (int nf = 0; nf < 8; nf++){ acc[nf][0]=0.f; acc[nf][1]=0.f; acc[nf][2]=0.f; acc[nf][3]=0.f; }
      #pragma unroll
      for (int ks = 0; ks < 12; ks++){
        s16x8 a = g ? arB[ks] : arA[ks];
        #pragma unroll
        for (int nf = 0; nf < 8; nf++){
          s16x8 b = *(const s16x8*)(wb + nf*16*D3 + ks*32);
          acc[nf] = __builtin_amdgcn_mfma_f32_16x16x32_bf16(a, b, acc[nf], 0, 0, 0);
        }
      }

      // col stats from acc via shfl (f32 exact; col=nf*16+lc, rows kg*4+r)
      #pragma unroll
      for (int nf = 0; nf < 8; nf++){
        float ps = acc[nf][0]+acc[nf][1]+acc[nf][2]+acc[nf][3];
        float pq = acc[nf][0]*acc[nf][0]+acc[nf][1]*acc[nf][1]
                 + acc[nf][2]*acc[nf][2]+acc[nf][3]*acc[nf][3];
        ps += __shfl_xor(ps, 16); ps += __shfl_xor(ps, 32);
        pq += __shfl_xor(pq, 16); pq += __shfl_xor(pq, 32);
        if (lane < 16){
          atomicAdd(&ssum[nf*16 + lc], ps);
          atomicAdd(&ssq [nf*16 + lc], pq);
        }
      }

      // u16 repack (wave-local), nontemporal h stores
      #pragma unroll
      for (int nf = 0; nf < 8; nf++)
        #pragma unroll
        for (int r = 0; r < 4; r++)
          ltu[w][kg*4 + r][nf*16 + lc] = f2bf(acc[nf][r]);

      const int rowBase = eBase + g*64 + w*16;
      #pragma unroll
      for (int it = 0; it < 8; it++){
        const int row = it*2 + rl;
        u16x4 o = *(const u16x4*)&ltu[w][row][cg*4];
        __builtin_nontemporal_store(o, (u16x4*)(hp + (size_t)(rowBase + row)*DD + cg*4));
      }
    }

    __syncthreads();
    if (t < 128){
      atomicAdd(&stats[ST_SUM + p*128 + t], ssum[t]);
      atomicAdd(&stats[ST_SQ  + p*128 + t], ssq[t]);
    }
  }
}

// ---------------- BN finalize ----------------
__global__ void sfin_score(const float* g1, const float* be1, float* __restrict__ stats){
  if (threadIdx.x == 0){
    float mu = stats[ST_SUM1] / (float)NE;
    float var = stats[ST_SQ1] / (float)NE - mu*mu;
    float sc = g1[0] * rsqrtf(var + EPSBN);
    stats[ST_SCALE1] = sc;
    stats[ST_SHIFT1] = be1[0] - mu*sc;
  }
}

__global__ void sfin_cols(const float* g, const float* be, float* __restrict__ stats, int part){
  int t = threadIdx.x;
  if (t < 128){
    int idx = part*128 + t;
    float mu = stats[ST_SUM + idx] / (float)NE;
    float var = stats[ST_SQ + idx] / (float)NE - mu*mu;
    float sc = g[t] * rsqrtf(var + EPSBN);
    stats[ST_SCALE + idx] = sc;
    stats[ST_SHIFT + idx] = be[t] - mu*sc;
  }
}

__global__ void sfin_all(const float* gT, const float* beT, const float* gM, const float* beM,
                         const float* gB, const float* beB, const float* g1, const float* be1,
                         float* __restrict__ stats){
  int t = threadIdx.x;
  if (t < 384){
    float mu = stats[ST_SUM + t] / (float)NE;
    float var = stats[ST_SQ + t] / (float)NE - mu*mu;
    float g, be;
    if (t < 128)      { g = gT[t];     be = beT[t]; }
    else if (t < 256) { g = gM[t-128]; be = beM[t-128]; }
    else              { g = gB[t-256]; be = beB[t-256]; }
    float sc = g * rsqrtf(var + EPSBN);
    stats[ST_SCALE + t] = sc;
    stats[ST_SHIFT + t] = be - mu*sc;
  } else if (t == 384){
    float mu = stats[ST_SUM1] / (float)NE;
    float var = stats[ST_SQ1] / (float)NE - mu*mu;
    float sc = g1[0] * rsqrtf(var + EPSBN);
    stats[ST_SCALE1] = sc;
    stats[ST_SHIFT1] = be1[0] - mu*sc;
  }
}

// ---------------- softmax: max, sum, att in place ----------------
__global__ void sm_max(float* __restrict__ sp, float* __restrict__ stats){
  const float sc = stats[ST_SCALE1], sh = stats[ST_SHIFT1];
  float lmax = 0.f;
  int stride = gridDim.x*blockDim.x;
  for (int i = blockIdx.x*blockDim.x + threadIdx.x; i < NE; i += stride){
    float s = fmaxf(sp[i]*sc + sh, 0.f);
    sp[i] = s;
    lmax = fmaxf(lmax, s);
  }
  #pragma unroll
  for (int o = 32; o; o >>= 1) lmax = fmaxf(lmax, __shfl_xor(lmax, o));
  __shared__ float red[4];
  if ((threadIdx.x & 63) == 0) red[threadIdx.x >> 6] = lmax;
  __syncthreads();
  if (threadIdx.x == 0){
    float m = fmaxf(fmaxf(red[0], red[1]), fmaxf(red[2], red[3]));
    atomicMax((unsigned int*)&stats[ST_MAX], __float_as_uint(m));
  }
}

__global__ void sm_sum(const float* __restrict__ sp, float* __restrict__ stats){
  const float mx = __uint_as_float(((const unsigned int*)stats)[ST_MAX]);
  float ls = 0.f;
  int stride = gridDim.x*blockDim.x;
  for (int i = blockIdx.x*blockDim.x + threadIdx.x; i < NE; i += stride)
    ls += __expf(sp[i] - mx);
  #pragma unroll
  for (int o = 32; o; o >>= 1) ls += __shfl_xor(ls, o);
  __shared__ float red[4];
  if ((threadIdx.x & 63) == 0) red[threadIdx.x >> 6] = ls;
  __syncthreads();
  if (threadIdx.x == 0)
    atomicAdd(&stats[ST_SEXP], red[0] + red[1] + red[2] + red[3]);
}

__global__ void sm_att(float* __restrict__ sp, const float* __restrict__ stats){
  const float mx = __uint_as_float(((const unsigned int*)stats)[ST_MAX]);
  const float invZ = 1.0f / stats[ST_SEXP];
  int stride = gridDim.x*blockDim.x;
  for (int i = blockIdx.x*blockDim.x + threadIdx.x; i < NE; i += stride)
    sp[i] = __expf(sp[i] - mx) * invZ;
}

// -------- node-centric scatter-mean, NP parts per call, f32 macc += --------
template<int NP>
__launch_bounds__(256)
__global__ void scat(const unsigned short* __restrict__ h,
                     const float* __restrict__ att,
                     const int* __restrict__ cnt, const int* __restrict__ start,
                     const int* __restrict__ lists,
                     const float* __restrict__ stats,
                     float* __restrict__ macc, int p0){
  const int w = threadIdx.x >> 6, lane = threadIdx.x & 63;
  const int n = blockIdx.x*4 + w;
  if (n >= NN) return;
  float a0 = 0.f, a1 = 0.f;
  for (int q = 0; q < NP; q++){
    const int p = p0 + q;
    const unsigned short* hq = h + (size_t)q*NE*DD;
    const float sc0 = stats[ST_SCALE + p*128 + lane];
    const float sh0 = stats[ST_SHIFT + p*128 + lane];
    const float sc1 = stats[ST_SCALE + p*128 + 64 + lane];
    const float sh1 = stats[ST_SHIFT + p*128 + 64 + lane];
    const int cs = start[p*NN + n];
    const int c  = cnt[p*NN + n];
    float p0a = 0.f, p1a = 0.f;
    for (int j = 0; j < c; j++){
      const int e = lists[(size_t)p*NE + cs + j];
      const float av = att[e];
      const float v0 = bf2f(__builtin_nontemporal_load(hq + (size_t)e*DD + lane));
      const float v1 = bf2f(__builtin_nontemporal_load(hq + (size_t)e*DD + 64 + lane));
      p0a += av * fmaxf(v0*sc0 + sh0, 0.f);
      p1a += av * fmaxf(v1*sc1 + sh1, 0.f);
    }
    if (c > 0){ float ic = 1.f / (float)c; a0 += p0a*ic; a1 += p1a*ic; }
  }
  macc[(size_t)n*DD + lane]      += a0;
  macc[(size_t)n*DD + 64 + lane] += a1;
}

// ---------------- zb = bf16(macc @ Wtw^T), fused col stats ----------------
__launch_bounds__(256)
__global__ void g2_gemm(const float* __restrict__ A,
                        const unsigned short* __restrict__ Wtwb,
                        unsigned short* __restrict__ zb,
                        float* __restrict__ stats){
  __shared__ float ssum[128], ssq[128];
  const int t = threadIdx.x;
  const int w = t >> 6, lane = t & 63;
  const int lc = lane & 15, kg = lane >> 4;
  if (t < 128){ ssum[t] = 0.f; ssq[t] = 0.f; }
  const int m0 = blockIdx.x*64 + w*16;
  const int arow = m0 + lc;
  f32x4 acc[8];
  #pragma unroll
  for (int nf = 0; nf < 8; nf++){ acc[nf][0]=0.f; acc[nf][1]=0.f; acc[nf][2]=0.f; acc[nf][3]=0.f; }
  #pragma unroll
  for (int ks = 0; ks < 128; ks += 32){
    s16x8 a;
    if (arow < NN){
      f32x4 a0 = *(const f32x4*)(A + (size_t)arow*DD + ks + kg*8);
      f32x4 a1 = *(const f32x4*)(A + (size_t)arow*DD + ks + kg*8 + 4);
      a[0]=(short)f2bf(a0[0]); a[1]=(short)f2bf(a0[1]); a[2]=(short)f2bf(a0[2]); a[3]=(short)f2bf(a0[3]);
      a[4]=(short)f2bf(a1[0]); a[5]=(short)f2bf(a1[1]); a[6]=(short)f2bf(a1[2]); a[7]=(short)f2bf(a1[3]);
    } else {
      a[0]=0;a[1]=0;a[2]=0;a[3]=0;a[4]=0;a[5]=0;a[6]=0;a[7]=0;
    }
    #pragma unroll
    for (int nf = 0; nf < 8; nf++){
      s16x8 b = *(const s16x8*)(Wtwb + (nf*16 + lc)*DD + ks + kg*8);
      acc[nf] = __builtin_amdgcn_mfma_f32_16x16x32_bf16(a, b, acc[nf], 0, 0, 0);
    }
  }
  float ps[8], pq[8];
  #pragma unroll
  for (int nf = 0; nf < 8; nf++){
    ps[nf] = 0.f; pq[nf] = 0.f;
    const int col = nf*16 + lc;
    #pragma unroll
    for (int r = 0; r < 4; r++){
      int row = m0 + kg*4 + r;
      if (row < NN){
        float v = acc[nf][r];
        zb[(size_t)row*DD + col] = f2bf(v);
        ps[nf] += v; pq[nf] += v*v;
      }
    }
  }
  __syncthreads();
  #pragma unroll
  for (int nf = 0; nf < 8; nf++){
    atomicAdd(&ssum[nf*16 + lc], ps[nf]);
    atomicAdd(&ssq [nf*16 + lc], pq[nf]);
  }
  __syncthreads();
  if (t < 128){
    atomicAdd(&stats[ST_SUM2 + t], ssum[t]);
    atomicAdd(&stats[ST_SQ2  + t], ssq[t]);
  }
}

__global__ void sfin2(const float* gtw, const float* betw, float* __restrict__ stats){
  int c = threadIdx.x;
  if (c < 128){
    float mu = stats[ST_SUM2 + c] / (float)NN;
    float var = stats[ST_SQ2 + c] / (float)NN - mu*mu;
    float sc = gtw[c] * rsqrtf(var + EPSBN);
    stats[ST_SCALE2 + c] = sc;
    stats[ST_SHIFT2 + c] = betw[c] - mu*sc;
  }
}

// ---------------- x += relu(BN(zb)); refresh bf16 copy (vectorized) ----------------
__global__ void fuse_update(const unsigned short* __restrict__ zb,
                            const float* __restrict__ stats,
                            float* __restrict__ xcur, unsigned short* __restrict__ xb){
  const int tot = NN*DD/4;
  int stride = gridDim.x*blockDim.x;
  for (int i = blockIdx.x*blockDim.x + threadIdx.x; i < tot; i += stride){
    u16x4 z4 = ((const u16x4*)zb)[i];
    f32x4 x4 = ((const f32x4*)xcur)[i];
    const int c = (i*4) & 127;
    f32x4 o; u16x4 ob;
    #pragma unroll
    for (int j = 0; j < 4; j++){
      float hv = fmaxf(bf2f(z4[j])*stats[ST_SCALE2 + c + j] + stats[ST_SHIFT2 + c + j], 0.f);
      o[j] = x4[j] + hv;
      ob[j] = f2bf(o[j]);
    }
    ((f32x4*)xcur)[i] = o;
    ((u16x4*)xb)[i] = ob;
  }
}

extern "C" void kernel_launch(void* const* d_in, const int* in_sizes, int n_in,
                              void* d_out, int out_size, void* d_ws, size_t ws_size,
                              hipStream_t stream){
  const float* x    = (const float*)d_in[0];
  const int*   twi  = (const int*)d_in[1];
  const float* W_T  = (const float*)d_in[2];
  const float* W_M  = (const float*)d_in[3];
  const float* W_B  = (const float*)d_in[4];
  const float* W_1  = (const float*)d_in[5];
  const float* W_tw = (const float*)d_in[6];
  const float* g_T  = (const float*)d_in[8];
  const float* be_T = (const float*)d_in[9];
  const float* g_M  = (const float*)d_in[11];
  const float* be_M = (const float*)d_in[12];
  const float* g_B  = (const float*)d_in[14];
  const float* be_B = (const float*)d_in[15];
  const float* g_1  = (const float*)d_in[17];
  const float* be_1 = (const float*)d_in[18];
  const float* g_tw = (const float*)d_in[20];
  const float* be_tw= (const float*)d_in[21];
  float* xcur = (float*)d_out;

  char* ws = (char*)d_ws;
  size_t off = 0;
  auto take = [&](size_t b){ size_t o = off; off += (b + 255) & ~(size_t)255; return o; };
  float* stats = (float*)(ws + take(ST_TOTAL*4));
  unsigned short* Wcat = (unsigned short*)(ws + take(384*384*2));
  unsigned short* Wtwb = (unsigned short*)(ws + take(128*128*2));
  int* bsums  = (int*)(ws + take((size_t)3*SCB*4));
  int* cnt    = (int*)(ws + take((size_t)3*NN*4));
  int* startA = (int*)(ws + take((size_t)3*NN*4));
  int* cursor = (int*)(ws + take((size_t)3*NN*4));
  int* lists  = (int*)(ws + take((size_t)3*NE*4));
  float* sp   = (float*)(ws + take((size_t)NE*4));
  unsigned short* xb = (unsigned short*)(ws + take((size_t)NN*DD*2));
  float* macc = (float*)(ws + take((size_t)NN*DD*4));
  size_t hoff = off;
  unsigned short* h = (unsigned short*)(ws + hoff);
  unsigned short* zb = h;   // alias: zb written only after h fully consumed each layer
  const size_t plane = (size_t)NE*DD*2;
  int P = 0;
  if (ws_size > hoff)
    P = (int)((ws_size - hoff) / plane);
  if (P > 3) P = 3;
  if (P < 1) return;  // cannot run; avoid faulting

  hipMemsetAsync(cnt, 0, (size_t)3*NN*4, stream);
  hipMemsetAsync(cursor, 0, (size_t)3*NN*4, stream);
  init_x<<<1024, 256, 0, stream>>>(x, xcur, xb);
  csr_cnt<<<(NE+255)/256, 256, 0, stream>>>(twi, cnt);
  scan_bs<<<dim3(SCB, 3), 256, 0, stream>>>(cnt, bsums);
  scan_top<<<1, 64, 0, stream>>>(bsums);
  scan_fin<<<dim3(SCB, 3), 256, 0, stream>>>(cnt, bsums, startA);
  csr_fill<<<(NE+255)/256, 256, 0, stream>>>(twi, startA, cursor, lists);

  for (int l = 0; l < KL; l++){
    hipMemsetAsync(stats, 0, ST_TOTAL*4, stream);
    hipMemsetAsync(macc, 0, (size_t)NN*DD*4, stream);
    wprep<<<640, 256, 0, stream>>>(W_T + (size_t)l*DD*D3, W_M + (size_t)l*DD*D3,
                                   W_B + (size_t)l*DD*D3, W_tw + (size_t)l*DD*DD,
                                   Wcat, Wtwb);
    const float* gs[3]  = {g_T  + (size_t)l*DD, g_M  + (size_t)l*DD, g_B  + (size_t)l*DD};
    const float* bes[3] = {be_T + (size_t)l*DD, be_M + (size_t)l*DD, be_B + (size_t)l*DD};
    const float* W1l = W_1 + (size_t)l*D3;

    if (P >= 3){
      g1k<3,1><<<EB2, 256, 0, stream>>>(xb, Wcat, W1l, twi, h, sp, stats, 0);
      sfin_all<<<1, 512, 0, stream>>>(gs[0], bes[0], gs[1], bes[1], gs[2], bes[2],
                                      g_1 + l, be_1 + l, stats);
      sm_max<<<1024, 256, 0, stream>>>(sp, stats);
      sm_sum<<<1024, 256, 0, stream>>>(sp, stats);
      sm_att<<<1024, 256, 0, stream>>>(sp, stats);
      scat<3><<<(NN+3)/4, 256, 0, stream>>>(h, sp, cnt, startA, lists, stats, macc, 0);
    } else if (P == 2){
      g1k<2,1><<<EB2, 256, 0, stream>>>(xb, Wcat, W1l, twi, h, sp, stats, 0);
      sfin_score<<<1, 64, 0, stream>>>(g_1 + l, be_1 + l, stats);
      sm_max<<<1024, 256, 0, stream>>>(sp, stats);
      sm_sum<<<1024, 256, 0, stream>>>(sp, stats);
      sm_att<<<1024, 256, 0, stream>>>(sp, stats);
      sfin_cols<<<1, 128, 0, stream>>>(gs[0], bes[0], stats, 0);
      sfin_cols<<<1, 128, 0, stream>>>(gs[1], bes[1], stats, 1);
      scat<2><<<(NN+3)/4, 256, 0, stream>>>(h, sp, cnt, startA, lists, stats, macc, 0);
      g1k<1,0><<<EB2, 256, 0, stream>>>(xb, Wcat, W1l, twi, h, sp, stats, 2);
      sfin_cols<<<1, 128, 0, stream>>>(gs[2], bes[2], stats, 2);
      scat<1><<<(NN+3)/4, 256, 0, stream>>>(h, sp, cnt, startA, lists, stats, macc, 2);
    } else {
      g1k<1,1><<<EB2, 256, 0, stream>>>(xb, Wcat, W1l, twi, h, sp, stats, 0);
      sfin_score<<<1, 64, 0, stream>>>(g_1 + l, be_1 + l, stats);
      sm_max<<<1024, 256, 0, stream>>>(sp, stats);
      sm_sum<<<1024, 256, 0, stream>>>(sp, stats);
      sm_att<<<1024, 256, 0, stream>>>(sp, stats);
      sfin_cols<<<1, 128, 0, stream>>>(gs[0], bes[0], stats, 0);
      scat<1><<<(NN+3)/4, 256, 0, stream>>>(h, sp, cnt, startA, lists, stats, macc, 0);
      for (int p = 1; p < 3; p++){
        g1k<1,0><<<EB2, 256, 0, stream>>>(xb, Wcat, W1l, twi, h, sp, stats, p);
        sfin_cols<<<1, 128, 0, stream>>>(gs[p], bes[p], stats, p);
        scat<1><<<(NN+3)/4, 256, 0, stream>>>(h, sp, cnt, startA, lists, stats, macc, p);
      }
    }

    g2_gemm<<<(NN+63)/64, 256, 0, stream>>>(macc, Wtwb, zb, stats);
    sfin2<<<1, 128, 0, stream>>>(g_tw + (size_t)l*DD, be_tw + (size_t)l*DD, stats);
    fuse_update<<<1024, 256, 0, stream>>>(zb, stats, xcur, xb);
  }
}

// Round 10
// 2378.620 us; speedup vs baseline: 1.6489x; 1.6489x over previous
//
#include <hip/hip_runtime.h>

#define NN 100000
#define NE 400000
#define DD 128
#define D3 384
#define KL 2
#define EPSBN 1e-5f
#define SCB ((NN + 1023) / 1024)

typedef __attribute__((ext_vector_type(8))) short s16x8;
typedef __attribute__((ext_vector_type(4))) float f32x4;
typedef __attribute__((ext_vector_type(4))) unsigned short u16x4;
typedef __attribute__((ext_vector_type(2))) unsigned short u16x2;

#define ST_SUM    0      // [384]
#define ST_SQ     384    // [384]
#define ST_SCALE  768    // [384]
#define ST_SHIFT  1152   // [384]
#define ST_SUM1   1536
#define ST_SQ1    1537
#define ST_MAX    1538
#define ST_SEXP   1539
#define ST_SCALE1 1540
#define ST_SHIFT1 1541
#define ST_SUM2   1542   // [128]
#define ST_SQ2    1670   // [128]
#define ST_SCALE2 1798   // [128]
#define ST_SHIFT2 1926   // [128]
#define ST_TOTAL  2054

__device__ __forceinline__ float bf2f(unsigned short u){
  return __uint_as_float(((unsigned int)u) << 16);
}
__device__ __forceinline__ unsigned short f2bf(float f){
  unsigned int x = __float_as_uint(f);
  x = x + 0x7FFFu + ((x >> 16) & 1u);
  return (unsigned short)(x >> 16);
}

// ---------------- init: x -> xcur (f32) + xb (bf16), vectorized ----------------
__global__ void init_x(const float* __restrict__ x, float* __restrict__ xcur,
                       unsigned short* __restrict__ xb){
  const int tot = NN*DD/4;
  int stride = gridDim.x * blockDim.x;
  for (int i = blockIdx.x*blockDim.x + threadIdx.x; i < tot; i += stride){
    f32x4 v = ((const f32x4*)x)[i];
    ((f32x4*)xcur)[i] = v;
    u16x4 o; o[0]=f2bf(v[0]); o[1]=f2bf(v[1]); o[2]=f2bf(v[2]); o[3]=f2bf(v[3]);
    ((u16x4*)xb)[i] = o;
  }
}

// --------- weight prep: Wjcat[j][s*128+o][c] = Wj[o][s*128+c]  (bf16) ---------
__global__ void wprep(const float* __restrict__ WT, const float* __restrict__ WM,
                      const float* __restrict__ WB, const float* __restrict__ Wtw,
                      unsigned short* __restrict__ Wjcat, unsigned short* __restrict__ Wtwb){
  int stride = gridDim.x * blockDim.x;
  int tid = blockIdx.x*blockDim.x + threadIdx.x;
  for (int i = tid; i < 3*D3*DD; i += stride){
    int j = i / (D3*DD);
    int rem = i - j*(D3*DD);
    int scol = rem >> 7;      // output col 0..383
    int c = rem & 127;        // input col
    int s = scol >> 7;        // slot
    int o = scol & 127;       // output feature within slot
    const float* Wj = (j==0) ? WT : ((j==1) ? WM : WB);
    Wjcat[i] = f2bf(Wj[o*D3 + s*128 + c]);
  }
  for (int i = tid; i < 128*128; i += stride) Wtwb[i] = f2bf(Wtw[i]);
}

// ---------------- CSR build ----------------
__global__ void csr_cnt(const int* __restrict__ twi, int* __restrict__ cnt){
  int e = blockIdx.x*blockDim.x + threadIdx.x;
  if (e < NE){
    atomicAdd(&cnt[0*NN + twi[0*NE + e]], 1);
    atomicAdd(&cnt[1*NN + twi[1*NE + e]], 1);
    atomicAdd(&cnt[2*NN + twi[2*NE + e]], 1);
  }
}

__global__ void scan_bs(const int* __restrict__ cnt, int* __restrict__ bsums){
  const int p = blockIdx.y, b = blockIdx.x, t = threadIdx.x;
  const int base = b * 1024;
  int s = 0;
  #pragma unroll
  for (int j = 0; j < 4; j++){
    int i = base + t + j*256;
    if (i < NN) s += cnt[p*NN + i];
  }
  __shared__ int red[256];
  red[t] = s; __syncthreads();
  #pragma unroll
  for (int o = 128; o; o >>= 1){
    if (t < o) red[t] += red[t+o];
    __syncthreads();
  }
  if (t == 0) bsums[p*SCB + b] = red[0];
}

__global__ void scan_top(int* __restrict__ bsums){
  const int p = threadIdx.x;
  if (p < 3){
    int run = 0;
    for (int i = 0; i < SCB; i++){ int v = bsums[p*SCB + i]; bsums[p*SCB + i] = run; run += v; }
  }
}

__global__ void scan_fin(const int* __restrict__ cnt, const int* __restrict__ bsums,
                         int* __restrict__ start){
  const int p = blockIdx.y, b = blockIdx.x, t = threadIdx.x;
  const int base = b * 1024;
  int v[4]; int s = 0;
  #pragma unroll
  for (int j = 0; j < 4; j++){
    int i = base + t*4 + j;
    v[j] = (i < NN) ? cnt[p*NN + i] : 0;
    s += v[j];
  }
  __shared__ int red[256];
  red[t] = s; __syncthreads();
  #pragma unroll
  for (int o = 1; o < 256; o <<= 1){
    int other = (t >= o) ? red[t - o] : 0;
    __syncthreads();
    red[t] += other;
    __syncthreads();
  }
  int ex = red[t] - s + bsums[p*SCB + b];
  #pragma unroll
  for (int j = 0; j < 4; j++){
    int i = base + t*4 + j;
    if (i < NN) start[p*NN + i] = ex;
    ex += v[j];
  }
}

// einfo[p][slot] = {e, n_{(p+1)%3}, n_{(p+2)%3}, 0}
__global__ void csr_fill(const int* __restrict__ twi, const int* __restrict__ start,
                         int* __restrict__ cursor, int4* __restrict__ einfo){
  int e = blockIdx.x*blockDim.x + threadIdx.x;
  if (e < NE){
    int nd0 = twi[e], nd1 = twi[NE+e], nd2 = twi[2*NE+e];
    int nd[3] = {nd0, nd1, nd2};
    #pragma unroll
    for (int p = 0; p < 3; p++){
      int n = nd[p];
      int pos = atomicAdd(&cursor[p*NN + n], 1);
      int4 v;
      v.x = e; v.y = nd[(p+1)%3]; v.z = nd[(p+2)%3]; v.w = 0;
      einfo[(size_t)p*NE + start[p*NN + n] + pos] = v;
    }
  }
}

// ---------------- node scores: S[s][n] = x[n] . w1[s*128: s*128+128] ----------------
__global__ void nscore(const unsigned short* __restrict__ xb,
                       const float* __restrict__ W1, float* __restrict__ S){
  __shared__ float w1s[384];
  const int t = threadIdx.x;
  for (int i = t; i < 384; i += 256) w1s[i] = W1[i];
  __syncthreads();
  const int n = blockIdx.x*256 + t;
  if (n >= NN) return;
  float s0 = 0.f, s1 = 0.f, s2 = 0.f;
  for (int k = 0; k < 128; k += 8){
    s16x8 v = *(const s16x8*)(xb + (size_t)n*DD + k);
    #pragma unroll
    for (int u = 0; u < 8; u++){
      float xv = bf2f((unsigned short)v[u]);
      s0 += xv * w1s[k+u];
      s1 += xv * w1s[128+k+u];
      s2 += xv * w1s[256+k+u];
    }
  }
  S[n] = s0; S[NN+n] = s1; S[2*NN+n] = s2;
}

// ---------------- edge scores: sp[e] = S0[i0]+S1[i1]+S2[i2], + sum/sumsq ----------------
__global__ void escore(const int* __restrict__ twi, const float* __restrict__ S,
                       float* __restrict__ sp, float* __restrict__ stats){
  const int e = blockIdx.x*blockDim.x + threadIdx.x;
  float s = 0.f;
  if (e < NE){
    s = S[twi[e]] + S[NN + twi[NE+e]] + S[2*NN + twi[2*NE+e]];
    sp[e] = s;
  }
  float sv = (e < NE) ? s : 0.f;
  float qv = sv*sv;
  #pragma unroll
  for (int o = 32; o; o >>= 1){ sv += __shfl_xor(sv, o); qv += __shfl_xor(qv, o); }
  if ((threadIdx.x & 63) == 0){
    atomicAdd(&stats[ST_SUM1], sv);
    atomicAdd(&stats[ST_SQ1],  qv);
  }
}

// ------------- dense node GEMM: Y[n, 0:384] = xb[n] @ Wjcat_j^T (bf16 out) -------------
__launch_bounds__(256)
__global__ void ngemm(const unsigned short* __restrict__ xb,
                      const unsigned short* __restrict__ Wj,   // pre-offset to part j
                      unsigned short* __restrict__ Y){
  const int t = threadIdx.x;
  const int w = t >> 6, lane = t & 63;
  const int lc = lane & 15, kg = lane >> 4;
  const int m0 = blockIdx.x*64 + w*16;
  const int arow = m0 + lc;
  f32x4 acc[24];
  #pragma unroll
  for (int nf = 0; nf < 24; nf++){ acc[nf][0]=0.f; acc[nf][1]=0.f; acc[nf][2]=0.f; acc[nf][3]=0.f; }
  #pragma unroll
  for (int ks = 0; ks < 4; ks++){
    s16x8 a;
    if (arow < NN) a = *(const s16x8*)(xb + (size_t)arow*DD + ks*32 + kg*8);
    else { a[0]=0;a[1]=0;a[2]=0;a[3]=0;a[4]=0;a[5]=0;a[6]=0;a[7]=0; }
    #pragma unroll
    for (int nf = 0; nf < 24; nf++){
      s16x8 b = *(const s16x8*)(Wj + (nf*16 + lc)*DD + ks*32 + kg*8);
      acc[nf] = __builtin_amdgcn_mfma_f32_16x16x32_bf16(a, b, acc[nf], 0, 0, 0);
    }
  }
  #pragma unroll
  for (int nf = 0; nf < 24; nf++){
    const int col = nf*16 + lc;
    #pragma unroll
    for (int r = 0; r < 4; r++){
      const int row = m0 + kg*4 + r;
      if (row < NN) Y[(size_t)row*D3 + col] = f2bf(acc[nf][r]);
    }
  }
}

// ------------- edge stats for part j: col sum/sumsq of h_j over all edges -------------
__launch_bounds__(256)
__global__ void estat(const unsigned short* __restrict__ Y,
                      const int* __restrict__ twi,
                      float* __restrict__ stats, int j){
  __shared__ float bs[4][128], bq[4][128];
  const int t = threadIdx.x, w = t >> 6, lane = t & 63;
  const int c0 = lane*2;
  float s0=0.f, s1=0.f, q0=0.f, q1=0.f;
  const int gw = blockIdx.x*4 + w;
  const int nw = gridDim.x*4;
  for (int e = gw; e < NE; e += nw){
    const int n0 = twi[e], n1 = twi[NE+e], n2 = twi[2*NE+e];
    u16x2 va = *(const u16x2*)(Y + (size_t)n0*D3 + c0);
    u16x2 vb = *(const u16x2*)(Y + (size_t)n1*D3 + 128 + c0);
    u16x2 vc = *(const u16x2*)(Y + (size_t)n2*D3 + 256 + c0);
    float h0 = bf2f(va[0]) + bf2f(vb[0]) + bf2f(vc[0]);
    float h1 = bf2f(va[1]) + bf2f(vb[1]) + bf2f(vc[1]);
    s0 += h0; s1 += h1; q0 += h0*h0; q1 += h1*h1;
  }
  bs[w][c0] = s0; bs[w][c0+1] = s1;
  bq[w][c0] = q0; bq[w][c0+1] = q1;
  __syncthreads();
  if (t < 128){
    atomicAdd(&stats[ST_SUM + j*128 + t], bs[0][t]+bs[1][t]+bs[2][t]+bs[3][t]);
    atomicAdd(&stats[ST_SQ  + j*128 + t], bq[0][t]+bq[1][t]+bq[2][t]+bq[3][t]);
  }
}

// ------ node-centric scatter for part j: macc[n] += mean_e att*relu(BN(h_j[e])) ------
__launch_bounds__(256)
__global__ void escat(const unsigned short* __restrict__ Y,
                      const int4* __restrict__ einfo,
                      const float* __restrict__ att,
                      const int* __restrict__ cnt, const int* __restrict__ start,
                      const float* __restrict__ stats,
                      float* __restrict__ macc, int j, int a, int b){
  const int w = threadIdx.x >> 6, lane = threadIdx.x & 63;
  const int n = blockIdx.x*4 + w;
  if (n >= NN) return;
  const int c = cnt[j*NN + n];
  if (c == 0) return;
  const int cs = start[j*NN + n];
  const int c0 = lane*2;
  u16x2 lv = *(const u16x2*)(Y + (size_t)n*D3 + j*128 + c0);
  const float l0 = bf2f(lv[0]), l1 = bf2f(lv[1]);
  const float sc0 = stats[ST_SCALE + j*128 + c0],   sh0 = stats[ST_SHIFT + j*128 + c0];
  const float sc1 = stats[ST_SCALE + j*128 + c0+1], sh1 = stats[ST_SHIFT + j*128 + c0+1];
  float a0 = 0.f, a1 = 0.f;
  for (int k = 0; k < c; k++){
    const int4 ei = einfo[(size_t)j*NE + cs + k];
    const float av = att[ei.x];
    u16x2 ga = *(const u16x2*)(Y + (size_t)ei.y*D3 + a*128 + c0);
    u16x2 gb = *(const u16x2*)(Y + (size_t)ei.z*D3 + b*128 + c0);
    float h0 = l0 + bf2f(ga[0]) + bf2f(gb[0]);
    float h1 = l1 + bf2f(ga[1]) + bf2f(gb[1]);
    a0 += av * fmaxf(h0*sc0 + sh0, 0.f);
    a1 += av * fmaxf(h1*sc1 + sh1, 0.f);
  }
  const float ic = 1.f / (float)c;
  float* mp = macc + (size_t)n*DD + c0;
  mp[0] += a0*ic;
  mp[1] += a1*ic;
}

// ---------------- BN finalize ----------------
__global__ void sfin_score(const float* g1, const float* be1, float* __restrict__ stats){
  if (threadIdx.x == 0){
    float mu = stats[ST_SUM1] / (float)NE;
    float var = stats[ST_SQ1] / (float)NE - mu*mu;
    float sc = g1[0] * rsqrtf(var + EPSBN);
    stats[ST_SCALE1] = sc;
    stats[ST_SHIFT1] = be1[0] - mu*sc;
  }
}

__global__ void sfin_cols(const float* g, const float* be, float* __restrict__ stats, int part){
  int t = threadIdx.x;
  if (t < 128){
    int idx = part*128 + t;
    float mu = stats[ST_SUM + idx] / (float)NE;
    float var = stats[ST_SQ + idx] / (float)NE - mu*mu;
    float sc = g[t] * rsqrtf(var + EPSBN);
    stats[ST_SCALE + idx] = sc;
    stats[ST_SHIFT + idx] = be[t] - mu*sc;
  }
}

// ---------------- softmax: max, sum, att in place ----------------
__global__ void sm_max(float* __restrict__ sp, float* __restrict__ stats){
  const float sc = stats[ST_SCALE1], sh = stats[ST_SHIFT1];
  float lmax = 0.f;
  int stride = gridDim.x*blockDim.x;
  for (int i = blockIdx.x*blockDim.x + threadIdx.x; i < NE; i += stride){
    float s = fmaxf(sp[i]*sc + sh, 0.f);
    sp[i] = s;
    lmax = fmaxf(lmax, s);
  }
  #pragma unroll
  for (int o = 32; o; o >>= 1) lmax = fmaxf(lmax, __shfl_xor(lmax, o));
  __shared__ float red[4];
  if ((threadIdx.x & 63) == 0) red[threadIdx.x >> 6] = lmax;
  __syncthreads();
  if (threadIdx.x == 0){
    float m = fmaxf(fmaxf(red[0], red[1]), fmaxf(red[2], red[3]));
    atomicMax((unsigned int*)&stats[ST_MAX], __float_as_uint(m));
  }
}

__global__ void sm_sum(const float* __restrict__ sp, float* __restrict__ stats){
  const float mx = __uint_as_float(((const unsigned int*)stats)[ST_MAX]);
  float ls = 0.f;
  int stride = gridDim.x*blockDim.x;
  for (int i = blockIdx.x*blockDim.x + threadIdx.x; i < NE; i += stride)
    ls += __expf(sp[i] - mx);
  #pragma unroll
  for (int o = 32; o; o >>= 1) ls += __shfl_xor(ls, o);
  __shared__ float red[4];
  if ((threadIdx.x & 63) == 0) red[threadIdx.x >> 6] = ls;
  __syncthreads();
  if (threadIdx.x == 0)
    atomicAdd(&stats[ST_SEXP], red[0] + red[1] + red[2] + red[3]);
}

__global__ void sm_att(float* __restrict__ sp, const float* __restrict__ stats){
  const float mx = __uint_as_float(((const unsigned int*)stats)[ST_MAX]);
  const float invZ = 1.0f / stats[ST_SEXP];
  int stride = gridDim.x*blockDim.x;
  for (int i = blockIdx.x*blockDim.x + threadIdx.x; i < NE; i += stride)
    sp[i] = __expf(sp[i] - mx) * invZ;
}

// ---------------- zb = bf16(macc @ Wtw^T), fused col stats ----------------
__launch_bounds__(256)
__global__ void g2_gemm(const float* __restrict__ A,
                        const unsigned short* __restrict__ Wtwb,
                        unsigned short* __restrict__ zb,
                        float* __restrict__ stats){
  __shared__ float ssum[128], ssq[128];
  const int t = threadIdx.x;
  const int w = t >> 6, lane = t & 63;
  const int lc = lane & 15, kg = lane >> 4;
  if (t < 128){ ssum[t] = 0.f; ssq[t] = 0.f; }
  const int m0 = blockIdx.x*64 + w*16;
  const int arow = m0 + lc;
  f32x4 acc[8];
  #pragma unroll
  for (int nf = 0; nf < 8; nf++){ acc[nf][0]=0.f; acc[nf][1]=0.f; acc[nf][2]=0.f; acc[nf][3]=0.f; }
  #pragma unroll
  for (int ks = 0; ks < 128; ks += 32){
    s16x8 a;
    if (arow < NN){
      f32x4 a0 = *(const f32x4*)(A + (size_t)arow*DD + ks + kg*8);
      f32x4 a1 = *(const f32x4*)(A + (size_t)arow*DD + ks + kg*8 + 4);
      a[0]=(short)f2bf(a0[0]); a[1]=(short)f2bf(a0[1]); a[2]=(short)f2bf(a0[2]); a[3]=(short)f2bf(a0[3]);
      a[4]=(short)f2bf(a1[0]); a[5]=(short)f2bf(a1[1]); a[6]=(short)f2bf(a1[2]); a[7]=(short)f2bf(a1[3]);
    } else {
      a[0]=0;a[1]=0;a[2]=0;a[3]=0;a[4]=0;a[5]=0;a[6]=0;a[7]=0;
    }
    #pragma unroll
    for (int nf = 0; nf < 8; nf++){
      s16x8 b = *(const s16x8*)(Wtwb + (nf*16 + lc)*DD + ks + kg*8);
      acc[nf] = __builtin_amdgcn_mfma_f32_16x16x32_bf16(a, b, acc[nf], 0, 0, 0);
    }
  }
  float ps[8], pq[8];
  #pragma unroll
  for (int nf = 0; nf < 8; nf++){
    ps[nf] = 0.f; pq[nf] = 0.f;
    const int col = nf*16 + lc;
    #pragma unroll
    for (int r = 0; r < 4; r++){
      int row = m0 + kg*4 + r;
      if (row < NN){
        float v = acc[nf][r];
        zb[(size_t)row*DD + col] = f2bf(v);
        ps[nf] += v; pq[nf] += v*v;
      }
    }
  }
  __syncthreads();
  #pragma unroll
  for (int nf = 0; nf < 8; nf++){
    atomicAdd(&ssum[nf*16 + lc], ps[nf]);
    atomicAdd(&ssq [nf*16 + lc], pq[nf]);
  }
  __syncthreads();
  if (t < 128){
    atomicAdd(&stats[ST_SUM2 + t], ssum[t]);
    atomicAdd(&stats[ST_SQ2  + t], ssq[t]);
  }
}

__global__ void sfin2(const float* gtw, const float* betw, float* __restrict__ stats){
  int c = threadIdx.x;
  if (c < 128){
    float mu = stats[ST_SUM2 + c] / (float)NN;
    float var = stats[ST_SQ2 + c] / (float)NN - mu*mu;
    float sc = gtw[c] * rsqrtf(var + EPSBN);
    stats[ST_SCALE2 + c] = sc;
    stats[ST_SHIFT2 + c] = betw[c] - mu*sc;
  }
}

// ---------------- x += relu(BN(zb)); refresh bf16 copy (vectorized) ----------------
__global__ void fuse_update(const unsigned short* __restrict__ zb,
                            const float* __restrict__ stats,
                            float* __restrict__ xcur, unsigned short* __restrict__ xb){
  const int tot = NN*DD/4;
  int stride = gridDim.x*blockDim.x;
  for (int i = blockIdx.x*blockDim.x + threadIdx.x; i < tot; i += stride){
    u16x4 z4 = ((const u16x4*)zb)[i];
    f32x4 x4 = ((const f32x4*)xcur)[i];
    const int c = (i*4) & 127;
    f32x4 o; u16x4 ob;
    #pragma unroll
    for (int j = 0; j < 4; j++){
      float hv = fmaxf(bf2f(z4[j])*stats[ST_SCALE2 + c + j] + stats[ST_SHIFT2 + c + j], 0.f);
      o[j] = x4[j] + hv;
      ob[j] = f2bf(o[j]);
    }
    ((f32x4*)xcur)[i] = o;
    ((u16x4*)xb)[i] = ob;
  }
}

extern "C" void kernel_launch(void* const* d_in, const int* in_sizes, int n_in,
                              void* d_out, int out_size, void* d_ws, size_t ws_size,
                              hipStream_t stream){
  const float* x    = (const float*)d_in[0];
  const int*   twi  = (const int*)d_in[1];
  const float* W_T  = (const float*)d_in[2];
  const float* W_M  = (const float*)d_in[3];
  const float* W_B  = (const float*)d_in[4];
  const float* W_1  = (const float*)d_in[5];
  const float* W_tw = (const float*)d_in[6];
  const float* g_T  = (const float*)d_in[8];
  const float* be_T = (const float*)d_in[9];
  const float* g_M  = (const float*)d_in[11];
  const float* be_M = (const float*)d_in[12];
  const float* g_B  = (const float*)d_in[14];
  const float* be_B = (const float*)d_in[15];
  const float* g_1  = (const float*)d_in[17];
  const float* be_1 = (const float*)d_in[18];
  const float* g_tw = (const float*)d_in[20];
  const float* be_tw= (const float*)d_in[21];
  float* xcur = (float*)d_out;

  char* ws = (char*)d_ws;
  size_t off = 0;
  auto take = [&](size_t b){ size_t o = off; off += (b + 255) & ~(size_t)255; return o; };
  float* stats = (float*)(ws + take(ST_TOTAL*4));
  unsigned short* Wjcat = (unsigned short*)(ws + take((size_t)3*D3*DD*2));
  unsigned short* Wtwb  = (unsigned short*)(ws + take(128*128*2));
  int* bsums  = (int*)(ws + take((size_t)3*SCB*4));
  int* cnt    = (int*)(ws + take((size_t)3*NN*4));
  int* startA = (int*)(ws + take((size_t)3*NN*4));
  int* cursor = (int*)(ws + take((size_t)3*NN*4));
  int4* einfo = (int4*)(ws + take((size_t)3*NE*16));
  float* sp   = (float*)(ws + take((size_t)NE*4));
  float* S    = (float*)(ws + take((size_t)3*NN*4));
  unsigned short* xb = (unsigned short*)(ws + take((size_t)NN*DD*2));
  float* macc = (float*)(ws + take((size_t)NN*DD*4));
  unsigned short* Y = (unsigned short*)(ws + take((size_t)NN*D3*2));
  unsigned short* zb = Y;   // alias: zb written by g2 only after last escat consumed Y
  if (ws_size < off) return;  // avoid faulting

  hipMemsetAsync(cnt, 0, (size_t)3*NN*4, stream);
  hipMemsetAsync(cursor, 0, (size_t)3*NN*4, stream);
  init_x<<<1024, 256, 0, stream>>>(x, xcur, xb);
  csr_cnt<<<(NE+255)/256, 256, 0, stream>>>(twi, cnt);
  scan_bs<<<dim3(SCB, 3), 256, 0, stream>>>(cnt, bsums);
  scan_top<<<1, 64, 0, stream>>>(bsums);
  scan_fin<<<dim3(SCB, 3), 256, 0, stream>>>(cnt, bsums, startA);
  csr_fill<<<(NE+255)/256, 256, 0, stream>>>(twi, startA, cursor, einfo);

  const int NGB = (NN + 63)/64;     // ngemm/g2 blocks
  const int NDB = (NN + 3)/4;       // node-wave blocks

  for (int l = 0; l < KL; l++){
    hipMemsetAsync(stats, 0, ST_TOTAL*4, stream);
    hipMemsetAsync(macc, 0, (size_t)NN*DD*4, stream);
    wprep<<<640, 256, 0, stream>>>(W_T + (size_t)l*DD*D3, W_M + (size_t)l*DD*D3,
                                   W_B + (size_t)l*DD*D3, W_tw + (size_t)l*DD*DD,
                                   Wjcat, Wtwb);
    const float* gs[3]  = {g_T  + (size_t)l*DD, g_M  + (size_t)l*DD, g_B  + (size_t)l*DD};
    const float* bes[3] = {be_T + (size_t)l*DD, be_M + (size_t)l*DD, be_B + (size_t)l*DD};

    // score path (node-decomposed)
    nscore<<<(NN+255)/256, 256, 0, stream>>>(xb, W_1 + (size_t)l*D3, S);
    escore<<<(NE+255)/256, 256, 0, stream>>>(twi, S, sp, stats);
    sfin_score<<<1, 64, 0, stream>>>(g_1 + l, be_1 + l, stats);
    sm_max<<<1024, 256, 0, stream>>>(sp, stats);
    sm_sum<<<1024, 256, 0, stream>>>(sp, stats);
    sm_att<<<1024, 256, 0, stream>>>(sp, stats);

    // per-part: dense node GEMM -> edge stats -> BN finalize -> node scatter
    for (int j = 0; j < 3; j++){
      ngemm<<<NGB, 256, 0, stream>>>(xb, Wjcat + (size_t)j*D3*DD, Y);
      estat<<<1024, 256, 0, stream>>>(Y, twi, stats, j);
      sfin_cols<<<1, 128, 0, stream>>>(gs[j], bes[j], stats, j);
      escat<<<NDB, 256, 0, stream>>>(Y, einfo, sp, cnt, startA, stats, macc,
                                     j, (j+1)%3, (j+2)%3);
    }

    g2_gemm<<<NGB, 256, 0, stream>>>(macc, Wtwb, zb, stats);
    sfin2<<<1, 128, 0, stream>>>(g_tw + (size_t)l*DD, be_tw + (size_t)l*DD, stats);
    fuse_update<<<1024, 256, 0, stream>>>(zb, stats, xcur, xb);
  }
}

// Round 11
// 2286.226 us; speedup vs baseline: 1.7155x; 1.0404x over previous
//
#include <hip/hip_runtime.h>

#define NN 100000
#define NE 400000
#define DD 128
#define D3 384
#define KL 2
#define EPSBN 1e-5f
#define SCB ((NN + 1023) / 1024)

typedef __attribute__((ext_vector_type(8))) short s16x8;
typedef __attribute__((ext_vector_type(4))) float f32x4;
typedef __attribute__((ext_vector_type(4))) unsigned short u16x4;
typedef __attribute__((ext_vector_type(2))) unsigned short u16x2;

#define ST_SUM    0      // [384]
#define ST_SQ     384    // [384]
#define ST_SCALE  768    // [384]
#define ST_SHIFT  1152   // [384]
#define ST_SUM1   1536
#define ST_SQ1    1537
#define ST_MAX    1538
#define ST_SEXP   1539
#define ST_SCALE1 1540
#define ST_SHIFT1 1541
#define ST_SUM2   1542   // [128]
#define ST_SQ2    1670   // [128]
#define ST_SCALE2 1798   // [128]
#define ST_SHIFT2 1926   // [128]
#define ST_TOTAL  2054

__device__ __forceinline__ float bf2f(unsigned short u){
  return __uint_as_float(((unsigned int)u) << 16);
}
__device__ __forceinline__ unsigned short f2bf(float f){
  unsigned int x = __float_as_uint(f);
  x = x + 0x7FFFu + ((x >> 16) & 1u);
  return (unsigned short)(x >> 16);
}

// ---------------- init: x -> xcur (f32) + xb (bf16), vectorized ----------------
__global__ void init_x(const float* __restrict__ x, float* __restrict__ xcur,
                       unsigned short* __restrict__ xb){
  const int tot = NN*DD/4;
  int stride = gridDim.x * blockDim.x;
  for (int i = blockIdx.x*blockDim.x + threadIdx.x; i < tot; i += stride){
    f32x4 v = ((const f32x4*)x)[i];
    ((f32x4*)xcur)[i] = v;
    u16x4 o; o[0]=f2bf(v[0]); o[1]=f2bf(v[1]); o[2]=f2bf(v[2]); o[3]=f2bf(v[3]);
    ((u16x4*)xb)[i] = o;
  }
}

// --------- weight prep: Wjcat[j][s*128+o][c] = Wj[o][s*128+c]  (bf16) ---------
__global__ void wprep(const float* __restrict__ WT, const float* __restrict__ WM,
                      const float* __restrict__ WB, const float* __restrict__ Wtw,
                      unsigned short* __restrict__ Wjcat, unsigned short* __restrict__ Wtwb){
  int stride = gridDim.x * blockDim.x;
  int tid = blockIdx.x*blockDim.x + threadIdx.x;
  for (int i = tid; i < 3*D3*DD; i += stride){
    int j = i / (D3*DD);
    int rem = i - j*(D3*DD);
    int scol = rem >> 7;      // output col 0..383
    int c = rem & 127;        // input col
    int s = scol >> 7;        // slot
    int o = scol & 127;       // output feature within slot
    const float* Wj = (j==0) ? WT : ((j==1) ? WM : WB);
    Wjcat[i] = f2bf(Wj[o*D3 + s*128 + c]);
  }
  for (int i = tid; i < 128*128; i += stride) Wtwb[i] = f2bf(Wtw[i]);
}

// ---------------- CSR build ----------------
__global__ void csr_cnt(const int* __restrict__ twi, int* __restrict__ cnt){
  int e = blockIdx.x*blockDim.x + threadIdx.x;
  if (e < NE){
    atomicAdd(&cnt[0*NN + twi[0*NE + e]], 1);
    atomicAdd(&cnt[1*NN + twi[1*NE + e]], 1);
    atomicAdd(&cnt[2*NN + twi[2*NE + e]], 1);
  }
}

__global__ void scan_bs(const int* __restrict__ cnt, int* __restrict__ bsums){
  const int p = blockIdx.y, b = blockIdx.x, t = threadIdx.x;
  const int base = b * 1024;
  int s = 0;
  #pragma unroll
  for (int j = 0; j < 4; j++){
    int i = base + t + j*256;
    if (i < NN) s += cnt[p*NN + i];
  }
  __shared__ int red[256];
  red[t] = s; __syncthreads();
  #pragma unroll
  for (int o = 128; o; o >>= 1){
    if (t < o) red[t] += red[t+o];
    __syncthreads();
  }
  if (t == 0) bsums[p*SCB + b] = red[0];
}

__global__ void scan_top(int* __restrict__ bsums){
  const int p = threadIdx.x;
  if (p < 3){
    int run = 0;
    for (int i = 0; i < SCB; i++){ int v = bsums[p*SCB + i]; bsums[p*SCB + i] = run; run += v; }
  }
}

__global__ void scan_fin(const int* __restrict__ cnt, const int* __restrict__ bsums,
                         int* __restrict__ start){
  const int p = blockIdx.y, b = blockIdx.x, t = threadIdx.x;
  const int base = b * 1024;
  int v[4]; int s = 0;
  #pragma unroll
  for (int j = 0; j < 4; j++){
    int i = base + t*4 + j;
    v[j] = (i < NN) ? cnt[p*NN + i] : 0;
    s += v[j];
  }
  __shared__ int red[256];
  red[t] = s; __syncthreads();
  #pragma unroll
  for (int o = 1; o < 256; o <<= 1){
    int other = (t >= o) ? red[t - o] : 0;
    __syncthreads();
    red[t] += other;
    __syncthreads();
  }
  int ex = red[t] - s + bsums[p*SCB + b];
  #pragma unroll
  for (int j = 0; j < 4; j++){
    int i = base + t*4 + j;
    if (i < NN) start[p*NN + i] = ex;
    ex += v[j];
  }
}

// einfo[p][slot] = {e, n_{(p+1)%3}, n_{(p+2)%3}, 0}
__global__ void csr_fill(const int* __restrict__ twi, const int* __restrict__ start,
                         int* __restrict__ cursor, int4* __restrict__ einfo){
  int e = blockIdx.x*blockDim.x + threadIdx.x;
  if (e < NE){
    int nd0 = twi[e], nd1 = twi[NE+e], nd2 = twi[2*NE+e];
    int nd[3] = {nd0, nd1, nd2};
    #pragma unroll
    for (int p = 0; p < 3; p++){
      int n = nd[p];
      int pos = atomicAdd(&cursor[p*NN + n], 1);
      int4 v;
      v.x = e; v.y = nd[(p+1)%3]; v.z = nd[(p+2)%3]; v.w = 0;
      einfo[(size_t)p*NE + start[p*NN + n] + pos] = v;
    }
  }
}

// ---------------- node scores: S[s][n] = x[n] . w1[s*128: s*128+128] ----------------
__global__ void nscore(const unsigned short* __restrict__ xb,
                       const float* __restrict__ W1, float* __restrict__ S){
  __shared__ float w1s[384];
  const int t = threadIdx.x;
  for (int i = t; i < 384; i += 256) w1s[i] = W1[i];
  __syncthreads();
  const int n = blockIdx.x*256 + t;
  if (n >= NN) return;
  float s0 = 0.f, s1 = 0.f, s2 = 0.f;
  for (int k = 0; k < 128; k += 8){
    s16x8 v = *(const s16x8*)(xb + (size_t)n*DD + k);
    #pragma unroll
    for (int u = 0; u < 8; u++){
      float xv = bf2f((unsigned short)v[u]);
      s0 += xv * w1s[k+u];
      s1 += xv * w1s[128+k+u];
      s2 += xv * w1s[256+k+u];
    }
  }
  S[n] = s0; S[NN+n] = s1; S[2*NN+n] = s2;
}

// ------- edge scores: sp[e] = S0[i0]+S1[i1]+S2[i2]; block-reduced sum/sumsq -------
__global__ void escore(const int* __restrict__ twi, const float* __restrict__ S,
                       float* __restrict__ sp, float* __restrict__ stats){
  float lsum = 0.f, lsq = 0.f;
  const int stride = gridDim.x*blockDim.x;
  for (int e = blockIdx.x*blockDim.x + threadIdx.x; e < NE; e += stride){
    float s = S[twi[e]] + S[NN + twi[NE+e]] + S[2*NN + twi[2*NE+e]];
    sp[e] = s;
    lsum += s; lsq += s*s;
  }
  #pragma unroll
  for (int o = 32; o; o >>= 1){ lsum += __shfl_xor(lsum, o); lsq += __shfl_xor(lsq, o); }
  __shared__ float rs[4], rq[4];
  if ((threadIdx.x & 63) == 0){ rs[threadIdx.x >> 6] = lsum; rq[threadIdx.x >> 6] = lsq; }
  __syncthreads();
  if (threadIdx.x == 0){
    atomicAdd(&stats[ST_SUM1], rs[0]+rs[1]+rs[2]+rs[3]);
    atomicAdd(&stats[ST_SQ1],  rq[0]+rq[1]+rq[2]+rq[3]);
  }
}

// ------------- dense node GEMM: Y[n, 0:384] = xb[n] @ Wjcat_j^T (bf16 out) -------------
__launch_bounds__(256)
__global__ void ngemm(const unsigned short* __restrict__ xb,
                      const unsigned short* __restrict__ Wj,   // pre-offset to part j
                      unsigned short* __restrict__ Y){
  const int t = threadIdx.x;
  const int w = t >> 6, lane = t & 63;
  const int lc = lane & 15, kg = lane >> 4;
  const int m0 = blockIdx.x*64 + w*16;
  const int arow = m0 + lc;
  f32x4 acc[24];
  #pragma unroll
  for (int nf = 0; nf < 24; nf++){ acc[nf][0]=0.f; acc[nf][1]=0.f; acc[nf][2]=0.f; acc[nf][3]=0.f; }
  #pragma unroll
  for (int ks = 0; ks < 4; ks++){
    s16x8 a;
    if (arow < NN) a = *(const s16x8*)(xb + (size_t)arow*DD + ks*32 + kg*8);
    else { a[0]=0;a[1]=0;a[2]=0;a[3]=0;a[4]=0;a[5]=0;a[6]=0;a[7]=0; }
    #pragma unroll
    for (int nf = 0; nf < 24; nf++){
      s16x8 b = *(const s16x8*)(Wj + (nf*16 + lc)*DD + ks*32 + kg*8);
      acc[nf] = __builtin_amdgcn_mfma_f32_16x16x32_bf16(a, b, acc[nf], 0, 0, 0);
    }
  }
  #pragma unroll
  for (int nf = 0; nf < 24; nf++){
    const int col = nf*16 + lc;
    #pragma unroll
    for (int r = 0; r < 4; r++){
      const int row = m0 + kg*4 + r;
      if (row < NN) Y[(size_t)row*D3 + col] = f2bf(acc[nf][r]);
    }
  }
}

// ------------- edge stats for part j: col sum/sumsq of h_j over all edges -------------
__launch_bounds__(256)
__global__ void estat(const unsigned short* __restrict__ Y,
                      const int* __restrict__ twi,
                      float* __restrict__ stats, int j){
  __shared__ float bs[4][128], bq[4][128];
  const int t = threadIdx.x, w = t >> 6, lane = t & 63;
  const int c0 = lane*2;
  float s0=0.f, s1=0.f, q0=0.f, q1=0.f;
  const int gw = blockIdx.x*4 + w;
  const int nw = gridDim.x*4;
  for (int e = gw; e < NE; e += nw){
    const int n0 = twi[e], n1 = twi[NE+e], n2 = twi[2*NE+e];
    u16x2 va = *(const u16x2*)(Y + (size_t)n0*D3 + c0);
    u16x2 vb = *(const u16x2*)(Y + (size_t)n1*D3 + 128 + c0);
    u16x2 vc = *(const u16x2*)(Y + (size_t)n2*D3 + 256 + c0);
    float h0 = bf2f(va[0]) + bf2f(vb[0]) + bf2f(vc[0]);
    float h1 = bf2f(va[1]) + bf2f(vb[1]) + bf2f(vc[1]);
    s0 += h0; s1 += h1; q0 += h0*h0; q1 += h1*h1;
  }
  bs[w][c0] = s0; bs[w][c0+1] = s1;
  bq[w][c0] = q0; bq[w][c0+1] = q1;
  __syncthreads();
  if (t < 128){
    atomicAdd(&stats[ST_SUM + j*128 + t], bs[0][t]+bs[1][t]+bs[2][t]+bs[3][t]);
    atomicAdd(&stats[ST_SQ  + j*128 + t], bq[0][t]+bq[1][t]+bq[2][t]+bq[3][t]);
  }
}

// ------ node-centric scatter for part j: macc[n] += mean_e att*relu(BN(h_j[e])) ------
__launch_bounds__(256)
__global__ void escat(const unsigned short* __restrict__ Y,
                      const int4* __restrict__ einfo,
                      const float* __restrict__ att,
                      const int* __restrict__ cnt, const int* __restrict__ start,
                      const float* __restrict__ stats,
                      float* __restrict__ macc, int j, int a, int b){
  const int w = threadIdx.x >> 6, lane = threadIdx.x & 63;
  const int n = blockIdx.x*4 + w;
  if (n >= NN) return;
  const int c = cnt[j*NN + n];
  if (c == 0) return;
  const int cs = start[j*NN + n];
  const int c0 = lane*2;
  u16x2 lv = *(const u16x2*)(Y + (size_t)n*D3 + j*128 + c0);
  const float l0 = bf2f(lv[0]), l1 = bf2f(lv[1]);
  const float sc0 = stats[ST_SCALE + j*128 + c0],   sh0 = stats[ST_SHIFT + j*128 + c0];
  const float sc1 = stats[ST_SCALE + j*128 + c0+1], sh1 = stats[ST_SHIFT + j*128 + c0+1];
  float a0 = 0.f, a1 = 0.f;
  for (int k = 0; k < c; k++){
    const int4 ei = einfo[(size_t)j*NE + cs + k];
    const float av = att[ei.x];
    u16x2 ga = *(const u16x2*)(Y + (size_t)ei.y*D3 + a*128 + c0);
    u16x2 gb = *(const u16x2*)(Y + (size_t)ei.z*D3 + b*128 + c0);
    float h0 = l0 + bf2f(ga[0]) + bf2f(gb[0]);
    float h1 = l1 + bf2f(ga[1]) + bf2f(gb[1]);
    a0 += av * fmaxf(h0*sc0 + sh0, 0.f);
    a1 += av * fmaxf(h1*sc1 + sh1, 0.f);
  }
  const float ic = 1.f / (float)c;
  float* mp = macc + (size_t)n*DD + c0;
  mp[0] += a0*ic;
  mp[1] += a1*ic;
}

// ---------------- BN finalize ----------------
__global__ void sfin_score(const float* g1, const float* be1, float* __restrict__ stats){
  if (threadIdx.x == 0){
    float mu = stats[ST_SUM1] / (float)NE;
    float var = stats[ST_SQ1] / (float)NE - mu*mu;
    float sc = g1[0] * rsqrtf(var + EPSBN);
    stats[ST_SCALE1] = sc;
    stats[ST_SHIFT1] = be1[0] - mu*sc;
  }
}

__global__ void sfin_cols(const float* g, const float* be, float* __restrict__ stats, int part){
  int t = threadIdx.x;
  if (t < 128){
    int idx = part*128 + t;
    float mu = stats[ST_SUM + idx] / (float)NE;
    float var = stats[ST_SQ + idx] / (float)NE - mu*mu;
    float sc = g[t] * rsqrtf(var + EPSBN);
    stats[ST_SCALE + idx] = sc;
    stats[ST_SHIFT + idx] = be[t] - mu*sc;
  }
}

// ---------------- softmax: max, sum(+store exp), scale ----------------
__global__ void sm_max(float* __restrict__ sp, float* __restrict__ stats){
  const float sc = stats[ST_SCALE1], sh = stats[ST_SHIFT1];
  float lmax = 0.f;
  int stride = gridDim.x*blockDim.x;
  for (int i = blockIdx.x*blockDim.x + threadIdx.x; i < NE; i += stride){
    float s = fmaxf(sp[i]*sc + sh, 0.f);
    sp[i] = s;
    lmax = fmaxf(lmax, s);
  }
  #pragma unroll
  for (int o = 32; o; o >>= 1) lmax = fmaxf(lmax, __shfl_xor(lmax, o));
  __shared__ float red[4];
  if ((threadIdx.x & 63) == 0) red[threadIdx.x >> 6] = lmax;
  __syncthreads();
  if (threadIdx.x == 0){
    float m = fmaxf(fmaxf(red[0], red[1]), fmaxf(red[2], red[3]));
    atomicMax((unsigned int*)&stats[ST_MAX], __float_as_uint(m));
  }
}

__global__ void sm_sum(float* __restrict__ sp, float* __restrict__ stats){
  const float mx = __uint_as_float(((const unsigned int*)stats)[ST_MAX]);
  float ls = 0.f;
  int stride = gridDim.x*blockDim.x;
  for (int i = blockIdx.x*blockDim.x + threadIdx.x; i < NE; i += stride){
    float ex = __expf(sp[i] - mx);
    sp[i] = ex;
    ls += ex;
  }
  #pragma unroll
  for (int o = 32; o; o >>= 1) ls += __shfl_xor(ls, o);
  __shared__ float red[4];
  if ((threadIdx.x & 63) == 0) red[threadIdx.x >> 6] = ls;
  __syncthreads();
  if (threadIdx.x == 0)
    atomicAdd(&stats[ST_SEXP], red[0] + red[1] + red[2] + red[3]);
}

__global__ void sm_att(float* __restrict__ sp, const float* __restrict__ stats){
  const float invZ = 1.0f / stats[ST_SEXP];
  int stride = gridDim.x*blockDim.x;
  for (int i = blockIdx.x*blockDim.x + threadIdx.x; i < NE; i += stride)
    sp[i] *= invZ;
}

// ---------------- zb = bf16(macc @ Wtw^T), fused col stats ----------------
__launch_bounds__(256)
__global__ void g2_gemm(const float* __restrict__ A,
                        const unsigned short* __restrict__ Wtwb,
                        unsigned short* __restrict__ zb,
                        float* __restrict__ stats){
  __shared__ float ssum[128], ssq[128];
  const int t = threadIdx.x;
  const int w = t >> 6, lane = t & 63;
  const int lc = lane & 15, kg = lane >> 4;
  if (t < 128){ ssum[t] = 0.f; ssq[t] = 0.f; }
  const int m0 = blockIdx.x*64 + w*16;
  const int arow = m0 + lc;
  f32x4 acc[8];
  #pragma unroll
  for (int nf = 0; nf < 8; nf++){ acc[nf][0]=0.f; acc[nf][1]=0.f; acc[nf][2]=0.f; acc[nf][3]=0.f; }
  #pragma unroll
  for (int ks = 0; ks < 128; ks += 32){
    s16x8 a;
    if (arow < NN){
      f32x4 a0 = *(const f32x4*)(A + (size_t)arow*DD + ks + kg*8);
      f32x4 a1 = *(const f32x4*)(A + (size_t)arow*DD + ks + kg*8 + 4);
      a[0]=(short)f2bf(a0[0]); a[1]=(short)f2bf(a0[1]); a[2]=(short)f2bf(a0[2]); a[3]=(short)f2bf(a0[3]);
      a[4]=(short)f2bf(a1[0]); a[5]=(short)f2bf(a1[1]); a[6]=(short)f2bf(a1[2]); a[7]=(short)f2bf(a1[3]);
    } else {
      a[0]=0;a[1]=0;a[2]=0;a[3]=0;a[4]=0;a[5]=0;a[6]=0;a[7]=0;
    }
    #pragma unroll
    for (int nf = 0; nf < 8; nf++){
      s16x8 b = *(const s16x8*)(Wtwb + (nf*16 + lc)*DD + ks + kg*8);
      acc[nf] = __builtin_amdgcn_mfma_f32_16x16x32_bf16(a, b, acc[nf], 0, 0, 0);
    }
  }
  float ps[8], pq[8];
  #pragma unroll
  for (int nf = 0; nf < 8; nf++){
    ps[nf] = 0.f; pq[nf] = 0.f;
    const int col = nf*16 + lc;
    #pragma unroll
    for (int r = 0; r < 4; r++){
      int row = m0 + kg*4 + r;
      if (row < NN){
        float v = acc[nf][r];
        zb[(size_t)row*DD + col] = f2bf(v);
        ps[nf] += v; pq[nf] += v*v;
      }
    }
  }
  __syncthreads();
  #pragma unroll
  for (int nf = 0; nf < 8; nf++){
    atomicAdd(&ssum[nf*16 + lc], ps[nf]);
    atomicAdd(&ssq [nf*16 + lc], pq[nf]);
  }
  __syncthreads();
  if (t < 128){
    atomicAdd(&stats[ST_SUM2 + t], ssum[t]);
    atomicAdd(&stats[ST_SQ2  + t], ssq[t]);
  }
}

__global__ void sfin2(const float* gtw, const float* betw, float* __restrict__ stats){
  int c = threadIdx.x;
  if (c < 128){
    float mu = stats[ST_SUM2 + c] / (float)NN;
    float var = stats[ST_SQ2 + c] / (float)NN - mu*mu;
    float sc = gtw[c] * rsqrtf(var + EPSBN);
    stats[ST_SCALE2 + c] = sc;
    stats[ST_SHIFT2 + c] = betw[c] - mu*sc;
  }
}

// ---------------- x += relu(BN(zb)); refresh bf16 copy (vectorized) ----------------
__global__ void fuse_update(const unsigned short* __restrict__ zb,
                            const float* __restrict__ stats,
                            float* __restrict__ xcur, unsigned short* __restrict__ xb){
  const int tot = NN*DD/4;
  int stride = gridDim.x*blockDim.x;
  for (int i = blockIdx.x*blockDim.x + threadIdx.x; i < tot; i += stride){
    u16x4 z4 = ((const u16x4*)zb)[i];
    f32x4 x4 = ((const f32x4*)xcur)[i];
    const int c = (i*4) & 127;
    f32x4 o; u16x4 ob;
    #pragma unroll
    for (int j = 0; j < 4; j++){
      float hv = fmaxf(bf2f(z4[j])*stats[ST_SCALE2 + c + j] + stats[ST_SHIFT2 + c + j], 0.f);
      o[j] = x4[j] + hv;
      ob[j] = f2bf(o[j]);
    }
    ((f32x4*)xcur)[i] = o;
    ((u16x4*)xb)[i] = ob;
  }
}

extern "C" void kernel_launch(void* const* d_in, const int* in_sizes, int n_in,
                              void* d_out, int out_size, void* d_ws, size_t ws_size,
                              hipStream_t stream){
  const float* x    = (const float*)d_in[0];
  const int*   twi  = (const int*)d_in[1];
  const float* W_T  = (const float*)d_in[2];
  const float* W_M  = (const float*)d_in[3];
  const float* W_B  = (const float*)d_in[4];
  const float* W_1  = (const float*)d_in[5];
  const float* W_tw = (const float*)d_in[6];
  const float* g_T  = (const float*)d_in[8];
  const float* be_T = (const float*)d_in[9];
  const float* g_M  = (const float*)d_in[11];
  const float* be_M = (const float*)d_in[12];
  const float* g_B  = (const float*)d_in[14];
  const float* be_B = (const float*)d_in[15];
  const float* g_1  = (const float*)d_in[17];
  const float* be_1 = (const float*)d_in[18];
  const float* g_tw = (const float*)d_in[20];
  const float* be_tw= (const float*)d_in[21];
  float* xcur = (float*)d_out;

  char* ws = (char*)d_ws;
  size_t off = 0;
  auto take = [&](size_t b){ size_t o = off; off += (b + 255) & ~(size_t)255; return o; };
  float* stats = (float*)(ws + take(ST_TOTAL*4));
  unsigned short* Wjcat = (unsigned short*)(ws + take((size_t)3*D3*DD*2));
  unsigned short* Wtwb  = (unsigned short*)(ws + take(128*128*2));
  int* bsums  = (int*)(ws + take((size_t)3*SCB*4));
  int* cnt    = (int*)(ws + take((size_t)3*NN*4));
  int* startA = (int*)(ws + take((size_t)3*NN*4));
  int* cursor = (int*)(ws + take((size_t)3*NN*4));
  int4* einfo = (int4*)(ws + take((size_t)3*NE*16));
  float* sp   = (float*)(ws + take((size_t)NE*4));
  float* S    = (float*)(ws + take((size_t)3*NN*4));
  unsigned short* xb = (unsigned short*)(ws + take((size_t)NN*DD*2));
  float* macc = (float*)(ws + take((size_t)NN*DD*4));
  unsigned short* Y = (unsigned short*)(ws + take((size_t)NN*D3*2));
  unsigned short* zb = Y;   // alias: zb written by g2 only after last escat consumed Y
  if (ws_size < off) return;  // avoid faulting

  hipMemsetAsync(cnt, 0, (size_t)3*NN*4, stream);
  hipMemsetAsync(cursor, 0, (size_t)3*NN*4, stream);
  init_x<<<1024, 256, 0, stream>>>(x, xcur, xb);
  csr_cnt<<<(NE+255)/256, 256, 0, stream>>>(twi, cnt);
  scan_bs<<<dim3(SCB, 3), 256, 0, stream>>>(cnt, bsums);
  scan_top<<<1, 64, 0, stream>>>(bsums);
  scan_fin<<<dim3(SCB, 3), 256, 0, stream>>>(cnt, bsums, startA);
  csr_fill<<<(NE+255)/256, 256, 0, stream>>>(twi, startA, cursor, einfo);

  const int NGB = (NN + 63)/64;     // ngemm/g2 blocks
  const int NDB = (NN + 3)/4;       // node-wave blocks

  for (int l = 0; l < KL; l++){
    hipMemsetAsync(stats, 0, ST_TOTAL*4, stream);
    hipMemsetAsync(macc, 0, (size_t)NN*DD*4, stream);
    wprep<<<640, 256, 0, stream>>>(W_T + (size_t)l*DD*D3, W_M + (size_t)l*DD*D3,
                                   W_B + (size_t)l*DD*D3, W_tw + (size_t)l*DD*DD,
                                   Wjcat, Wtwb);
    const float* gs[3]  = {g_T  + (size_t)l*DD, g_M  + (size_t)l*DD, g_B  + (size_t)l*DD};
    const float* bes[3] = {be_T + (size_t)l*DD, be_M + (size_t)l*DD, be_B + (size_t)l*DD};

    // score path (node-decomposed)
    nscore<<<(NN+255)/256, 256, 0, stream>>>(xb, W_1 + (size_t)l*D3, S);
    escore<<<256, 256, 0, stream>>>(twi, S, sp, stats);
    sfin_score<<<1, 64, 0, stream>>>(g_1 + l, be_1 + l, stats);
    sm_max<<<256, 256, 0, stream>>>(sp, stats);
    sm_sum<<<256, 256, 0, stream>>>(sp, stats);
    sm_att<<<256, 256, 0, stream>>>(sp, stats);

    // per-part: dense node GEMM -> edge stats -> BN finalize -> node scatter
    for (int j = 0; j < 3; j++){
      ngemm<<<NGB, 256, 0, stream>>>(xb, Wjcat + (size_t)j*D3*DD, Y);
      estat<<<512, 256, 0, stream>>>(Y, twi, stats, j);
      sfin_cols<<<1, 128, 0, stream>>>(gs[j], bes[j], stats, j);
      escat<<<NDB, 256, 0, stream>>>(Y, einfo, sp, cnt, startA, stats, macc,
                                     j, (j+1)%3, (j+2)%3);
    }

    g2_gemm<<<NGB, 256, 0, stream>>>(macc, Wtwb, zb, stats);
    sfin2<<<1, 128, 0, stream>>>(g_tw + (size_t)l*DD, be_tw + (size_t)l*DD, stats);
    fuse_update<<<1024, 256, 0, stream>>>(zb, stats, xcur, xb);
  }
}

// Round 12
// 2132.116 us; speedup vs baseline: 1.8395x; 1.0723x over previous
//
#include <hip/hip_runtime.h>

#define NN 100000
#define NE 400000
#define DD 128
#define D3 384
#define KL 2
#define EPSBN 1e-5f
#define SCB ((NN + 1023) / 1024)

typedef __attribute__((ext_vector_type(8))) short s16x8;
typedef __attribute__((ext_vector_type(4))) float f32x4;
typedef __attribute__((ext_vector_type(4))) unsigned short u16x4;
typedef __attribute__((ext_vector_type(2))) unsigned short u16x2;

#define ST_SUM    0      // [384]
#define ST_SQ     384    // [384]
#define ST_SCALE  768    // [384]
#define ST_SHIFT  1152   // [384]
#define ST_SUM1   1536
#define ST_SQ1    1537
#define ST_MAX    1538
#define ST_SEXP   1539
#define ST_SCALE1 1540
#define ST_SHIFT1 1541
#define ST_SUM2   1542   // [128]
#define ST_SQ2    1670   // [128]
#define ST_SCALE2 1798   // [128]
#define ST_SHIFT2 1926   // [128]
#define ST_TOTAL  2054

__device__ __forceinline__ float bf2f(unsigned short u){
  return __uint_as_float(((unsigned int)u) << 16);
}
__device__ __forceinline__ unsigned short f2bf(float f){
  unsigned int x = __float_as_uint(f);
  x = x + 0x7FFFu + ((x >> 16) & 1u);
  return (unsigned short)(x >> 16);
}

// ---------------- init: x -> xcur (f32) + xb (bf16), vectorized ----------------
__global__ void init_x(const float* __restrict__ x, float* __restrict__ xcur,
                       unsigned short* __restrict__ xb){
  const int tot = NN*DD/4;
  int stride = gridDim.x * blockDim.x;
  for (int i = blockIdx.x*blockDim.x + threadIdx.x; i < tot; i += stride){
    f32x4 v = ((const f32x4*)x)[i];
    ((f32x4*)xcur)[i] = v;
    u16x4 o; o[0]=f2bf(v[0]); o[1]=f2bf(v[1]); o[2]=f2bf(v[2]); o[3]=f2bf(v[3]);
    ((u16x4*)xb)[i] = o;
  }
}

// --------- weight prep: Wjcat[j][s*128+o][c] = Wj[o][s*128+c]  (bf16) ---------
__global__ void wprep(const float* __restrict__ WT, const float* __restrict__ WM,
                      const float* __restrict__ WB, const float* __restrict__ Wtw,
                      unsigned short* __restrict__ Wjcat, unsigned short* __restrict__ Wtwb){
  int stride = gridDim.x * blockDim.x;
  int tid = blockIdx.x*blockDim.x + threadIdx.x;
  for (int i = tid; i < 3*D3*DD; i += stride){
    int j = i / (D3*DD);
    int rem = i - j*(D3*DD);
    int scol = rem >> 7;      // output col 0..383
    int c = rem & 127;        // input col
    int s = scol >> 7;        // slot
    int o = scol & 127;       // output feature within slot
    const float* Wj = (j==0) ? WT : ((j==1) ? WM : WB);
    Wjcat[i] = f2bf(Wj[o*D3 + s*128 + c]);
  }
  for (int i = tid; i < 128*128; i += stride) Wtwb[i] = f2bf(Wtw[i]);
}

// ---------------- CSR build ----------------
__global__ void csr_cnt(const int* __restrict__ twi, int* __restrict__ cnt){
  int e = blockIdx.x*blockDim.x + threadIdx.x;
  if (e < NE){
    atomicAdd(&cnt[0*NN + twi[0*NE + e]], 1);
    atomicAdd(&cnt[1*NN + twi[1*NE + e]], 1);
    atomicAdd(&cnt[2*NN + twi[2*NE + e]], 1);
  }
}

__global__ void scan_bs(const int* __restrict__ cnt, int* __restrict__ bsums){
  const int p = blockIdx.y, b = blockIdx.x, t = threadIdx.x;
  const int base = b * 1024;
  int s = 0;
  #pragma unroll
  for (int j = 0; j < 4; j++){
    int i = base + t + j*256;
    if (i < NN) s += cnt[p*NN + i];
  }
  __shared__ int red[256];
  red[t] = s; __syncthreads();
  #pragma unroll
  for (int o = 128; o; o >>= 1){
    if (t < o) red[t] += red[t+o];
    __syncthreads();
  }
  if (t == 0) bsums[p*SCB + b] = red[0];
}

__global__ void scan_top(int* __restrict__ bsums){
  const int p = threadIdx.x;
  if (p < 3){
    int run = 0;
    for (int i = 0; i < SCB; i++){ int v = bsums[p*SCB + i]; bsums[p*SCB + i] = run; run += v; }
  }
}

__global__ void scan_fin(const int* __restrict__ cnt, const int* __restrict__ bsums,
                         int* __restrict__ start){
  const int p = blockIdx.y, b = blockIdx.x, t = threadIdx.x;
  const int base = b * 1024;
  int v[4]; int s = 0;
  #pragma unroll
  for (int j = 0; j < 4; j++){
    int i = base + t*4 + j;
    v[j] = (i < NN) ? cnt[p*NN + i] : 0;
    s += v[j];
  }
  __shared__ int red[256];
  red[t] = s; __syncthreads();
  #pragma unroll
  for (int o = 1; o < 256; o <<= 1){
    int other = (t >= o) ? red[t - o] : 0;
    __syncthreads();
    red[t] += other;
    __syncthreads();
  }
  int ex = red[t] - s + bsums[p*SCB + b];
  #pragma unroll
  for (int j = 0; j < 4; j++){
    int i = base + t*4 + j;
    if (i < NN) start[p*NN + i] = ex;
    ex += v[j];
  }
}

// einfo[p][slot] = {e, n_{(p+1)%3}, n_{(p+2)%3}, n_p}
__global__ void csr_fill(const int* __restrict__ twi, const int* __restrict__ start,
                         int* __restrict__ cursor, int4* __restrict__ einfo){
  int e = blockIdx.x*blockDim.x + threadIdx.x;
  if (e < NE){
    int nd0 = twi[e], nd1 = twi[NE+e], nd2 = twi[2*NE+e];
    int nd[3] = {nd0, nd1, nd2};
    #pragma unroll
    for (int p = 0; p < 3; p++){
      int n = nd[p];
      int pos = atomicAdd(&cursor[p*NN + n], 1);
      int4 v;
      v.x = e; v.y = nd[(p+1)%3]; v.z = nd[(p+2)%3]; v.w = n;
      einfo[(size_t)p*NE + start[p*NN + n] + pos] = v;
    }
  }
}

// ---------------- node scores: S[s][n] = x[n] . w1[s*128: s*128+128] ----------------
__global__ void nscore(const unsigned short* __restrict__ xb,
                       const float* __restrict__ W1, float* __restrict__ S){
  __shared__ float w1s[384];
  const int t = threadIdx.x;
  for (int i = t; i < 384; i += 256) w1s[i] = W1[i];
  __syncthreads();
  const int n = blockIdx.x*256 + t;
  if (n >= NN) return;
  float s0 = 0.f, s1 = 0.f, s2 = 0.f;
  for (int k = 0; k < 128; k += 8){
    s16x8 v = *(const s16x8*)(xb + (size_t)n*DD + k);
    #pragma unroll
    for (int u = 0; u < 8; u++){
      float xv = bf2f((unsigned short)v[u]);
      s0 += xv * w1s[k+u];
      s1 += xv * w1s[128+k+u];
      s2 += xv * w1s[256+k+u];
    }
  }
  S[n] = s0; S[NN+n] = s1; S[2*NN+n] = s2;
}

// ------- edge scores: sp[e] = S0[i0]+S1[i1]+S2[i2]; block-reduced sum/sumsq -------
__global__ void escore(const int* __restrict__ twi, const float* __restrict__ S,
                       float* __restrict__ sp, float* __restrict__ stats){
  float lsum = 0.f, lsq = 0.f;
  const int stride = gridDim.x*blockDim.x;
  for (int e = blockIdx.x*blockDim.x + threadIdx.x; e < NE; e += stride){
    float s = S[twi[e]] + S[NN + twi[NE+e]] + S[2*NN + twi[2*NE+e]];
    sp[e] = s;
    lsum += s; lsq += s*s;
  }
  #pragma unroll
  for (int o = 32; o; o >>= 1){ lsum += __shfl_xor(lsum, o); lsq += __shfl_xor(lsq, o); }
  __shared__ float rs[4], rq[4];
  if ((threadIdx.x & 63) == 0){ rs[threadIdx.x >> 6] = lsum; rq[threadIdx.x >> 6] = lsq; }
  __syncthreads();
  if (threadIdx.x == 0){
    atomicAdd(&stats[ST_SUM1], rs[0]+rs[1]+rs[2]+rs[3]);
    atomicAdd(&stats[ST_SQ1],  rq[0]+rq[1]+rq[2]+rq[3]);
  }
}

// ------------- dense node GEMM: Y[n, 0:384] = xb[n] @ Wjcat_j^T (bf16 out) -------------
__launch_bounds__(256)
__global__ void ngemm(const unsigned short* __restrict__ xb,
                      const unsigned short* __restrict__ Wj,   // pre-offset to part j
                      unsigned short* __restrict__ Y){
  const int t = threadIdx.x;
  const int w = t >> 6, lane = t & 63;
  const int lc = lane & 15, kg = lane >> 4;
  const int m0 = blockIdx.x*64 + w*16;
  const int arow = m0 + lc;
  f32x4 acc[24];
  #pragma unroll
  for (int nf = 0; nf < 24; nf++){ acc[nf][0]=0.f; acc[nf][1]=0.f; acc[nf][2]=0.f; acc[nf][3]=0.f; }
  #pragma unroll
  for (int ks = 0; ks < 4; ks++){
    s16x8 a;
    if (arow < NN) a = *(const s16x8*)(xb + (size_t)arow*DD + ks*32 + kg*8);
    else { a[0]=0;a[1]=0;a[2]=0;a[3]=0;a[4]=0;a[5]=0;a[6]=0;a[7]=0; }
    #pragma unroll
    for (int nf = 0; nf < 24; nf++){
      s16x8 b = *(const s16x8*)(Wj + (nf*16 + lc)*DD + ks*32 + kg*8);
      acc[nf] = __builtin_amdgcn_mfma_f32_16x16x32_bf16(a, b, acc[nf], 0, 0, 0);
    }
  }
  #pragma unroll
  for (int nf = 0; nf < 24; nf++){
    const int col = nf*16 + lc;
    #pragma unroll
    for (int r = 0; r < 4; r++){
      const int row = m0 + kg*4 + r;
      if (row < NN) Y[(size_t)row*D3 + col] = f2bf(acc[nf][r]);
    }
  }
}

// ----- edge stats for part j (node-centric CSR walk): col sum/sumsq of h_j -----
__launch_bounds__(256)
__global__ void estat(const unsigned short* __restrict__ Y,
                      const int4* __restrict__ einfo,
                      const int* __restrict__ cnt, const int* __restrict__ start,
                      float* __restrict__ stats, int j, int a, int b){
  __shared__ float bs[4][128], bq[4][128];
  const int t = threadIdx.x, w = t >> 6, lane = t & 63;
  const int c0 = lane*2;
  float s0=0.f, s1=0.f, q0=0.f, q1=0.f;
  const int gw = blockIdx.x*4 + w;
  const int nw = gridDim.x*4;
  for (int n = gw; n < NN; n += nw){
    const int c = cnt[j*NN + n];
    if (c == 0) continue;
    const int cs = start[j*NN + n];
    u16x2 lv = *(const u16x2*)(Y + (size_t)n*D3 + j*128 + c0);
    const float l0 = bf2f(lv[0]), l1 = bf2f(lv[1]);
    for (int k = 0; k < c; k++){
      const int4 ei = einfo[(size_t)j*NE + cs + k];
      u16x2 ga = *(const u16x2*)(Y + (size_t)ei.y*D3 + a*128 + c0);
      u16x2 gb = *(const u16x2*)(Y + (size_t)ei.z*D3 + b*128 + c0);
      float h0 = l0 + bf2f(ga[0]) + bf2f(gb[0]);
      float h1 = l1 + bf2f(ga[1]) + bf2f(gb[1]);
      s0 += h0; s1 += h1; q0 += h0*h0; q1 += h1*h1;
    }
  }
  bs[w][c0] = s0; bs[w][c0+1] = s1;
  bq[w][c0] = q0; bq[w][c0+1] = q1;
  __syncthreads();
  if (t < 128){
    atomicAdd(&stats[ST_SUM + j*128 + t], bs[0][t]+bs[1][t]+bs[2][t]+bs[3][t]);
    atomicAdd(&stats[ST_SQ  + j*128 + t], bq[0][t]+bq[1][t]+bq[2][t]+bq[3][t]);
  }
}

// ------ node-centric scatter for part j: macc[n] += mean_e att*relu(BN(h_j[e])) ------
__launch_bounds__(256)
__global__ void escat(const unsigned short* __restrict__ Y,
                      const int4* __restrict__ einfo,
                      const float* __restrict__ att,
                      const int* __restrict__ cnt, const int* __restrict__ start,
                      const float* __restrict__ stats,
                      float* __restrict__ macc, int j, int a, int b){
  const int w = threadIdx.x >> 6, lane = threadIdx.x & 63;
  const int n = blockIdx.x*4 + w;
  if (n >= NN) return;
  const int c = cnt[j*NN + n];
  if (c == 0) return;
  const float invZ = 1.0f / stats[ST_SEXP];
  const int cs = start[j*NN + n];
  const int c0 = lane*2;
  u16x2 lv = *(const u16x2*)(Y + (size_t)n*D3 + j*128 + c0);
  const float l0 = bf2f(lv[0]), l1 = bf2f(lv[1]);
  const float sc0 = stats[ST_SCALE + j*128 + c0],   sh0 = stats[ST_SHIFT + j*128 + c0];
  const float sc1 = stats[ST_SCALE + j*128 + c0+1], sh1 = stats[ST_SHIFT + j*128 + c0+1];
  float a0 = 0.f, a1 = 0.f;
  for (int k = 0; k < c; k++){
    const int4 ei = einfo[(size_t)j*NE + cs + k];
    const float av = att[ei.x] * invZ;
    u16x2 ga = *(const u16x2*)(Y + (size_t)ei.y*D3 + a*128 + c0);
    u16x2 gb = *(const u16x2*)(Y + (size_t)ei.z*D3 + b*128 + c0);
    float h0 = l0 + bf2f(ga[0]) + bf2f(gb[0]);
    float h1 = l1 + bf2f(ga[1]) + bf2f(gb[1]);
    a0 += av * fmaxf(h0*sc0 + sh0, 0.f);
    a1 += av * fmaxf(h1*sc1 + sh1, 0.f);
  }
  const float ic = 1.f / (float)c;
  float* mp = macc + (size_t)n*DD + c0;
  mp[0] += a0*ic;
  mp[1] += a1*ic;
}

// ---------------- BN finalize ----------------
__global__ void sfin_score(const float* g1, const float* be1, float* __restrict__ stats){
  if (threadIdx.x == 0){
    float mu = stats[ST_SUM1] / (float)NE;
    float var = stats[ST_SQ1] / (float)NE - mu*mu;
    float sc = g1[0] * rsqrtf(var + EPSBN);
    stats[ST_SCALE1] = sc;
    stats[ST_SHIFT1] = be1[0] - mu*sc;
  }
}

__global__ void sfin_cols(const float* g, const float* be, float* __restrict__ stats, int part){
  int t = threadIdx.x;
  if (t < 128){
    int idx = part*128 + t;
    float mu = stats[ST_SUM + idx] / (float)NE;
    float var = stats[ST_SQ + idx] / (float)NE - mu*mu;
    float sc = g[t] * rsqrtf(var + EPSBN);
    stats[ST_SCALE + idx] = sc;
    stats[ST_SHIFT + idx] = be[t] - mu*sc;
  }
}

// ---------------- softmax: max, then sum (stores exp in place) ----------------
__global__ void sm_max(float* __restrict__ sp, float* __restrict__ stats){
  const float sc = stats[ST_SCALE1], sh = stats[ST_SHIFT1];
  float lmax = 0.f;
  int stride = gridDim.x*blockDim.x;
  for (int i = blockIdx.x*blockDim.x + threadIdx.x; i < NE; i += stride){
    float s = fmaxf(sp[i]*sc + sh, 0.f);
    sp[i] = s;
    lmax = fmaxf(lmax, s);
  }
  #pragma unroll
  for (int o = 32; o; o >>= 1) lmax = fmaxf(lmax, __shfl_xor(lmax, o));
  __shared__ float red[4];
  if ((threadIdx.x & 63) == 0) red[threadIdx.x >> 6] = lmax;
  __syncthreads();
  if (threadIdx.x == 0){
    float m = fmaxf(fmaxf(red[0], red[1]), fmaxf(red[2], red[3]));
    atomicMax((unsigned int*)&stats[ST_MAX], __float_as_uint(m));
  }
}

__global__ void sm_sum(float* __restrict__ sp, float* __restrict__ stats){
  const float mx = __uint_as_float(((const unsigned int*)stats)[ST_MAX]);
  float ls = 0.f;
  int stride = gridDim.x*blockDim.x;
  for (int i = blockIdx.x*blockDim.x + threadIdx.x; i < NE; i += stride){
    float ex = __expf(sp[i] - mx);
    sp[i] = ex;
    ls += ex;
  }
  #pragma unroll
  for (int o = 32; o; o >>= 1) ls += __shfl_xor(ls, o);
  __shared__ float red[4];
  if ((threadIdx.x & 63) == 0) red[threadIdx.x >> 6] = ls;
  __syncthreads();
  if (threadIdx.x == 0)
    atomicAdd(&stats[ST_SEXP], red[0] + red[1] + red[2] + red[3]);
}

// ---------------- zb = bf16(macc @ Wtw^T), fused col stats ----------------
__launch_bounds__(256)
__global__ void g2_gemm(const float* __restrict__ A,
                        const unsigned short* __restrict__ Wtwb,
                        unsigned short* __restrict__ zb,
                        float* __restrict__ stats){
  __shared__ float ssum[128], ssq[128];
  const int t = threadIdx.x;
  const int w = t >> 6, lane = t & 63;
  const int lc = lane & 15, kg = lane >> 4;
  if (t < 128){ ssum[t] = 0.f; ssq[t] = 0.f; }
  const int m0 = blockIdx.x*64 + w*16;
  const int arow = m0 + lc;
  f32x4 acc[8];
  #pragma unroll
  for (int nf = 0; nf < 8; nf++){ acc[nf][0]=0.f; acc[nf][1]=0.f; acc[nf][2]=0.f; acc[nf][3]=0.f; }
  #pragma unroll
  for (int ks = 0; ks < 128; ks += 32){
    s16x8 a;
    if (arow < NN){
      f32x4 a0 = *(const f32x4*)(A + (size_t)arow*DD + ks + kg*8);
      f32x4 a1 = *(const f32x4*)(A + (size_t)arow*DD + ks + kg*8 + 4);
      a[0]=(short)f2bf(a0[0]); a[1]=(short)f2bf(a0[1]); a[2]=(short)f2bf(a0[2]); a[3]=(short)f2bf(a0[3]);
      a[4]=(short)f2bf(a1[0]); a[5]=(short)f2bf(a1[1]); a[6]=(short)f2bf(a1[2]); a[7]=(short)f2bf(a1[3]);
    } else {
      a[0]=0;a[1]=0;a[2]=0;a[3]=0;a[4]=0;a[5]=0;a[6]=0;a[7]=0;
    }
    #pragma unroll
    for (int nf = 0; nf < 8; nf++){
      s16x8 b = *(const s16x8*)(Wtwb + (nf*16 + lc)*DD + ks + kg*8);
      acc[nf] = __builtin_amdgcn_mfma_f32_16x16x32_bf16(a, b, acc[nf], 0, 0, 0);
    }
  }
  float ps[8], pq[8];
  #pragma unroll
  for (int nf = 0; nf < 8; nf++){
    ps[nf] = 0.f; pq[nf] = 0.f;
    const int col = nf*16 + lc;
    #pragma unroll
    for (int r = 0; r < 4; r++){
      int row = m0 + kg*4 + r;
      if (row < NN){
        float v = acc[nf][r];
        zb[(size_t)row*DD + col] = f2bf(v);
        ps[nf] += v; pq[nf] += v*v;
      }
    }
  }
  __syncthreads();
  #pragma unroll
  for (int nf = 0; nf < 8; nf++){
    atomicAdd(&ssum[nf*16 + lc], ps[nf]);
    atomicAdd(&ssq [nf*16 + lc], pq[nf]);
  }
  __syncthreads();
  if (t < 128){
    atomicAdd(&stats[ST_SUM2 + t], ssum[t]);
    atomicAdd(&stats[ST_SQ2  + t], ssq[t]);
  }
}

__global__ void sfin2(const float* gtw, const float* betw, float* __restrict__ stats){
  int c = threadIdx.x;
  if (c < 128){
    float mu = stats[ST_SUM2 + c] / (float)NN;
    float var = stats[ST_SQ2 + c] / (float)NN - mu*mu;
    float sc = gtw[c] * rsqrtf(var + EPSBN);
    stats[ST_SCALE2 + c] = sc;
    stats[ST_SHIFT2 + c] = betw[c] - mu*sc;
  }
}

// ---------------- x += relu(BN(zb)); refresh bf16 copy (vectorized) ----------------
__global__ void fuse_update(const unsigned short* __restrict__ zb,
                            const float* __restrict__ stats,
                            float* __restrict__ xcur, unsigned short* __restrict__ xb){
  const int tot = NN*DD/4;
  int stride = gridDim.x*blockDim.x;
  for (int i = blockIdx.x*blockDim.x + threadIdx.x; i < tot; i += stride){
    u16x4 z4 = ((const u16x4*)zb)[i];
    f32x4 x4 = ((const f32x4*)xcur)[i];
    const int c = (i*4) & 127;
    f32x4 o; u16x4 ob;
    #pragma unroll
    for (int j = 0; j < 4; j++){
      float hv = fmaxf(bf2f(z4[j])*stats[ST_SCALE2 + c + j] + stats[ST_SHIFT2 + c + j], 0.f);
      o[j] = x4[j] + hv;
      ob[j] = f2bf(o[j]);
    }
    ((f32x4*)xcur)[i] = o;
    ((u16x4*)xb)[i] = ob;
  }
}

extern "C" void kernel_launch(void* const* d_in, const int* in_sizes, int n_in,
                              void* d_out, int out_size, void* d_ws, size_t ws_size,
                              hipStream_t stream){
  const float* x    = (const float*)d_in[0];
  const int*   twi  = (const int*)d_in[1];
  const float* W_T  = (const float*)d_in[2];
  const float* W_M  = (const float*)d_in[3];
  const float* W_B  = (const float*)d_in[4];
  const float* W_1  = (const float*)d_in[5];
  const float* W_tw = (const float*)d_in[6];
  const float* g_T  = (const float*)d_in[8];
  const float* be_T = (const float*)d_in[9];
  const float* g_M  = (const float*)d_in[11];
  const float* be_M = (const float*)d_in[12];
  const float* g_B  = (const float*)d_in[14];
  const float* be_B = (const float*)d_in[15];
  const float* g_1  = (const float*)d_in[17];
  const float* be_1 = (const float*)d_in[18];
  const float* g_tw = (const float*)d_in[20];
  const float* be_tw= (const float*)d_in[21];
  float* xcur = (float*)d_out;

  char* ws = (char*)d_ws;
  size_t off = 0;
  auto take = [&](size_t b){ size_t o = off; off += (b + 255) & ~(size_t)255; return o; };
  float* stats = (float*)(ws + take(ST_TOTAL*4));
  unsigned short* Wjcat = (unsigned short*)(ws + take((size_t)3*D3*DD*2));
  unsigned short* Wtwb  = (unsigned short*)(ws + take(128*128*2));
  int* bsums  = (int*)(ws + take((size_t)3*SCB*4));
  int* cnt    = (int*)(ws + take((size_t)3*NN*4));
  int* startA = (int*)(ws + take((size_t)3*NN*4));
  int* cursor = (int*)(ws + take((size_t)3*NN*4));
  int4* einfo = (int4*)(ws + take((size_t)3*NE*16));
  float* sp   = (float*)(ws + take((size_t)NE*4));
  float* S    = (float*)(ws + take((size_t)3*NN*4));
  unsigned short* xb = (unsigned short*)(ws + take((size_t)NN*DD*2));
  float* macc = (float*)(ws + take((size_t)NN*DD*4));
  unsigned short* Y = (unsigned short*)(ws + take((size_t)NN*D3*2));
  unsigned short* zb = Y;   // alias: zb written by g2 only after last escat consumed Y
  if (ws_size < off) return;  // avoid faulting

  hipMemsetAsync(cnt, 0, (size_t)3*NN*4, stream);
  hipMemsetAsync(cursor, 0, (size_t)3*NN*4, stream);
  init_x<<<1024, 256, 0, stream>>>(x, xcur, xb);
  csr_cnt<<<(NE+255)/256, 256, 0, stream>>>(twi, cnt);
  scan_bs<<<dim3(SCB, 3), 256, 0, stream>>>(cnt, bsums);
  scan_top<<<1, 64, 0, stream>>>(bsums);
  scan_fin<<<dim3(SCB, 3), 256, 0, stream>>>(cnt, bsums, startA);
  csr_fill<<<(NE+255)/256, 256, 0, stream>>>(twi, startA, cursor, einfo);

  const int NGB = (NN + 63)/64;     // ngemm/g2 blocks
  const int NDB = (NN + 3)/4;       // node-wave blocks

  for (int l = 0; l < KL; l++){
    hipMemsetAsync(stats, 0, ST_TOTAL*4, stream);
    hipMemsetAsync(macc, 0, (size_t)NN*DD*4, stream);
    wprep<<<640, 256, 0, stream>>>(W_T + (size_t)l*DD*D3, W_M + (size_t)l*DD*D3,
                                   W_B + (size_t)l*DD*D3, W_tw + (size_t)l*DD*DD,
                                   Wjcat, Wtwb);
    const float* gs[3]  = {g_T  + (size_t)l*DD, g_M  + (size_t)l*DD, g_B  + (size_t)l*DD};
    const float* bes[3] = {be_T + (size_t)l*DD, be_M + (size_t)l*DD, be_B + (size_t)l*DD};

    // score path (node-decomposed)
    nscore<<<(NN+255)/256, 256, 0, stream>>>(xb, W_1 + (size_t)l*D3, S);
    escore<<<256, 256, 0, stream>>>(twi, S, sp, stats);
    sfin_score<<<1, 64, 0, stream>>>(g_1 + l, be_1 + l, stats);
    sm_max<<<256, 256, 0, stream>>>(sp, stats);
    sm_sum<<<256, 256, 0, stream>>>(sp, stats);

    // per-part: dense node GEMM -> edge stats -> BN finalize -> node scatter
    for (int j = 0; j < 3; j++){
      ngemm<<<NGB, 256, 0, stream>>>(xb, Wjcat + (size_t)j*D3*DD, Y);
      estat<<<1024, 256, 0, stream>>>(Y, einfo, cnt, startA, stats, j, (j+1)%3, (j+2)%3);
      sfin_cols<<<1, 128, 0, stream>>>(gs[j], bes[j], stats, j);
      escat<<<NDB, 256, 0, stream>>>(Y, einfo, sp, cnt, startA, stats, macc,
                                     j, (j+1)%3, (j+2)%3);
    }

    g2_gemm<<<NGB, 256, 0, stream>>>(macc, Wtwb, zb, stats);
    sfin2<<<1, 128, 0, stream>>>(g_tw + (size_t)l*DD, be_tw + (size_t)l*DD, stats);
    fuse_update<<<1024, 256, 0, stream>>>(zb, stats, xcur, xb);
  }
}

// Round 13
// 2089.579 us; speedup vs baseline: 1.8770x; 1.0204x over previous
//
#include <hip/hip_runtime.h>

#define NN 100000
#define NE 400000
#define DD 128
#define D3 384
#define KL 2
#define EPSBN 1e-5f
#define SCB ((NN + 1023) / 1024)

typedef __attribute__((ext_vector_type(8))) short s16x8;
typedef __attribute__((ext_vector_type(4))) float f32x4;
typedef __attribute__((ext_vector_type(4))) unsigned short u16x4;
typedef __attribute__((ext_vector_type(2))) unsigned short u16x2;

#define ST_SUM    0      // [384]
#define ST_SQ     384    // [384]
#define ST_SCALE  768    // [384]
#define ST_SHIFT  1152   // [384]
#define ST_SUM1   1536
#define ST_SQ1    1537
#define ST_MAX    1538
#define ST_SEXP   1539
#define ST_SCALE1 1540
#define ST_SHIFT1 1541
#define ST_SUM2   1542   // [128]
#define ST_SQ2    1670   // [128]
#define ST_SCALE2 1798   // [128]
#define ST_SHIFT2 1926   // [128]
#define ST_TOTAL  2054

__device__ __forceinline__ float bf2f(unsigned short u){
  return __uint_as_float(((unsigned int)u) << 16);
}
__device__ __forceinline__ unsigned short f2bf(float f){
  unsigned int x = __float_as_uint(f);
  x = x + 0x7FFFu + ((x >> 16) & 1u);
  return (unsigned short)(x >> 16);
}

// ---------------- init: x -> xcur (f32) + xb (bf16), vectorized ----------------
__global__ void init_x(const float* __restrict__ x, float* __restrict__ xcur,
                       unsigned short* __restrict__ xb){
  const int tot = NN*DD/4;
  int stride = gridDim.x * blockDim.x;
  for (int i = blockIdx.x*blockDim.x + threadIdx.x; i < tot; i += stride){
    f32x4 v = ((const f32x4*)x)[i];
    ((f32x4*)xcur)[i] = v;
    u16x4 o; o[0]=f2bf(v[0]); o[1]=f2bf(v[1]); o[2]=f2bf(v[2]); o[3]=f2bf(v[3]);
    ((u16x4*)xb)[i] = o;
  }
}

// --------- weight prep: Wjcat[j][s*128+o][c] = Wj[o][s*128+c]  (bf16) ---------
__global__ void wprep(const float* __restrict__ WT, const float* __restrict__ WM,
                      const float* __restrict__ WB, const float* __restrict__ Wtw,
                      unsigned short* __restrict__ Wjcat, unsigned short* __restrict__ Wtwb){
  int stride = gridDim.x * blockDim.x;
  int tid = blockIdx.x*blockDim.x + threadIdx.x;
  for (int i = tid; i < 3*D3*DD; i += stride){
    int j = i / (D3*DD);
    int rem = i - j*(D3*DD);
    int scol = rem >> 7;      // output col 0..383
    int c = rem & 127;        // input col
    int s = scol >> 7;        // slot
    int o = scol & 127;       // output feature within slot
    const float* Wj = (j==0) ? WT : ((j==1) ? WM : WB);
    Wjcat[i] = f2bf(Wj[o*D3 + s*128 + c]);
  }
  for (int i = tid; i < 128*128; i += stride) Wtwb[i] = f2bf(Wtw[i]);
}

// ---------------- CSR build ----------------
__global__ void csr_cnt(const int* __restrict__ twi, int* __restrict__ cnt){
  int e = blockIdx.x*blockDim.x + threadIdx.x;
  if (e < NE){
    atomicAdd(&cnt[0*NN + twi[0*NE + e]], 1);
    atomicAdd(&cnt[1*NN + twi[1*NE + e]], 1);
    atomicAdd(&cnt[2*NN + twi[2*NE + e]], 1);
  }
}

__global__ void scan_bs(const int* __restrict__ cnt, int* __restrict__ bsums){
  const int p = blockIdx.y, b = blockIdx.x, t = threadIdx.x;
  const int base = b * 1024;
  int s = 0;
  #pragma unroll
  for (int j = 0; j < 4; j++){
    int i = base + t + j*256;
    if (i < NN) s += cnt[p*NN + i];
  }
  __shared__ int red[256];
  red[t] = s; __syncthreads();
  #pragma unroll
  for (int o = 128; o; o >>= 1){
    if (t < o) red[t] += red[t+o];
    __syncthreads();
  }
  if (t == 0) bsums[p*SCB + b] = red[0];
}

__global__ void scan_top(int* __restrict__ bsums){
  const int p = threadIdx.x;
  if (p < 3){
    int run = 0;
    for (int i = 0; i < SCB; i++){ int v = bsums[p*SCB + i]; bsums[p*SCB + i] = run; run += v; }
  }
}

__global__ void scan_fin(const int* __restrict__ cnt, const int* __restrict__ bsums,
                         int* __restrict__ start){
  const int p = blockIdx.y, b = blockIdx.x, t = threadIdx.x;
  const int base = b * 1024;
  int v[4]; int s = 0;
  #pragma unroll
  for (int j = 0; j < 4; j++){
    int i = base + t*4 + j;
    v[j] = (i < NN) ? cnt[p*NN + i] : 0;
    s += v[j];
  }
  __shared__ int red[256];
  red[t] = s; __syncthreads();
  #pragma unroll
  for (int o = 1; o < 256; o <<= 1){
    int other = (t >= o) ? red[t - o] : 0;
    __syncthreads();
    red[t] += other;
    __syncthreads();
  }
  int ex = red[t] - s + bsums[p*SCB + b];
  #pragma unroll
  for (int j = 0; j < 4; j++){
    int i = base + t*4 + j;
    if (i < NN) start[p*NN + i] = ex;
    ex += v[j];
  }
}

// einfo[p][slot] = {e, n_{(p+1)%3}, n_{(p+2)%3}, n_p}
__global__ void csr_fill(const int* __restrict__ twi, const int* __restrict__ start,
                         int* __restrict__ cursor, int4* __restrict__ einfo){
  int e = blockIdx.x*blockDim.x + threadIdx.x;
  if (e < NE){
    int nd0 = twi[e], nd1 = twi[NE+e], nd2 = twi[2*NE+e];
    int nd[3] = {nd0, nd1, nd2};
    #pragma unroll
    for (int p = 0; p < 3; p++){
      int n = nd[p];
      int pos = atomicAdd(&cursor[p*NN + n], 1);
      int4 v;
      v.x = e; v.y = nd[(p+1)%3]; v.z = nd[(p+2)%3]; v.w = n;
      einfo[(size_t)p*NE + start[p*NN + n] + pos] = v;
    }
  }
}

// ---------------- node scores: S[s][n] = x[n] . w1[s*128: s*128+128] ----------------
__global__ void nscore(const unsigned short* __restrict__ xb,
                       const float* __restrict__ W1, float* __restrict__ S){
  __shared__ float w1s[384];
  const int t = threadIdx.x;
  for (int i = t; i < 384; i += 256) w1s[i] = W1[i];
  __syncthreads();
  const int n = blockIdx.x*256 + t;
  if (n >= NN) return;
  float s0 = 0.f, s1 = 0.f, s2 = 0.f;
  for (int k = 0; k < 128; k += 8){
    s16x8 v = *(const s16x8*)(xb + (size_t)n*DD + k);
    #pragma unroll
    for (int u = 0; u < 8; u++){
      float xv = bf2f((unsigned short)v[u]);
      s0 += xv * w1s[k+u];
      s1 += xv * w1s[128+k+u];
      s2 += xv * w1s[256+k+u];
    }
  }
  S[n] = s0; S[NN+n] = s1; S[2*NN+n] = s2;
}

// ------- edge scores: sp[e] = S0[i0]+S1[i1]+S2[i2]; block-reduced sum/sumsq -------
__global__ void escore(const int* __restrict__ twi, const float* __restrict__ S,
                       float* __restrict__ sp, float* __restrict__ stats){
  float lsum = 0.f, lsq = 0.f;
  const int stride = gridDim.x*blockDim.x;
  for (int e = blockIdx.x*blockDim.x + threadIdx.x; e < NE; e += stride){
    float s = S[twi[e]] + S[NN + twi[NE+e]] + S[2*NN + twi[2*NE+e]];
    sp[e] = s;
    lsum += s; lsq += s*s;
  }
  #pragma unroll
  for (int o = 32; o; o >>= 1){ lsum += __shfl_xor(lsum, o); lsq += __shfl_xor(lsq, o); }
  __shared__ float rs[4], rq[4];
  if ((threadIdx.x & 63) == 0){ rs[threadIdx.x >> 6] = lsum; rq[threadIdx.x >> 6] = lsq; }
  __syncthreads();
  if (threadIdx.x == 0){
    atomicAdd(&stats[ST_SUM1], rs[0]+rs[1]+rs[2]+rs[3]);
    atomicAdd(&stats[ST_SQ1],  rq[0]+rq[1]+rq[2]+rq[3]);
  }
}

// ------ dense node GEMM: Y[n, 0:384] = xb[n] @ Wjcat_j^T, coalesced LDS-repack ------
__launch_bounds__(256)
__global__ void ngemm(const unsigned short* __restrict__ xb,
                      const unsigned short* __restrict__ Wj,   // pre-offset to part j
                      unsigned short* __restrict__ Y){
  __shared__ unsigned short ltu[4][16][128];   // 16 KB wave-local repack
  const int t = threadIdx.x;
  const int w = t >> 6, lane = t & 63;
  const int lc = lane & 15, kg = lane >> 4;
  const int m0 = blockIdx.x*64 + w*16;
  const int arow = m0 + lc;
  f32x4 acc[24];
  #pragma unroll
  for (int nf = 0; nf < 24; nf++){ acc[nf][0]=0.f; acc[nf][1]=0.f; acc[nf][2]=0.f; acc[nf][3]=0.f; }
  #pragma unroll
  for (int ks = 0; ks < 4; ks++){
    s16x8 a;
    if (arow < NN) a = *(const s16x8*)(xb + (size_t)arow*DD + ks*32 + kg*8);
    else { a[0]=0;a[1]=0;a[2]=0;a[3]=0;a[4]=0;a[5]=0;a[6]=0;a[7]=0; }
    #pragma unroll
    for (int nf = 0; nf < 24; nf++){
      s16x8 b = *(const s16x8*)(Wj + (nf*16 + lc)*DD + ks*32 + kg*8);
      acc[nf] = __builtin_amdgcn_mfma_f32_16x16x32_bf16(a, b, acc[nf], 0, 0, 0);
    }
  }
  // 3 chunks of 128 cols: wave-local u16 repack -> coalesced u16x4 stores
  const int rl = lane >> 5, cg = lane & 31;
  #pragma unroll
  for (int ch = 0; ch < 3; ch++){
    #pragma unroll
    for (int f = 0; f < 8; f++){
      const int nf = ch*8 + f;
      #pragma unroll
      for (int r = 0; r < 4; r++)
        ltu[w][kg*4 + r][f*16 + lc] = f2bf(acc[nf][r]);
    }
    #pragma unroll
    for (int it = 0; it < 8; it++){
      const int row = it*2 + rl;
      const int grow = m0 + row;
      if (grow < NN){
        u16x4 o = *(const u16x4*)&ltu[w][row][cg*4];
        *(u16x4*)(Y + (size_t)grow*D3 + ch*128 + cg*4) = o;
      }
    }
  }
}

// ----- edge stats for part j (node-centric CSR walk): col sum/sumsq of h_j -----
__launch_bounds__(256)
__global__ void estat(const unsigned short* __restrict__ Y,
                      const int4* __restrict__ einfo,
                      const int* __restrict__ cnt, const int* __restrict__ start,
                      float* __restrict__ stats, int j, int a, int b){
  __shared__ float bs[4][128], bq[4][128];
  const int t = threadIdx.x, w = t >> 6, lane = t & 63;
  const int c0 = lane*2;
  float s0=0.f, s1=0.f, q0=0.f, q1=0.f;
  const int gw = blockIdx.x*4 + w;
  const int nw = gridDim.x*4;
  for (int n = gw; n < NN; n += nw){
    const int c = cnt[j*NN + n];
    if (c == 0) continue;
    const int cs = start[j*NN + n];
    u16x2 lv = *(const u16x2*)(Y + (size_t)n*D3 + j*128 + c0);
    const float l0 = bf2f(lv[0]), l1 = bf2f(lv[1]);
    for (int k = 0; k < c; k++){
      const int4 ei = einfo[(size_t)j*NE + cs + k];
      u16x2 ga = *(const u16x2*)(Y + (size_t)ei.y*D3 + a*128 + c0);
      u16x2 gb = *(const u16x2*)(Y + (size_t)ei.z*D3 + b*128 + c0);
      float h0 = l0 + bf2f(ga[0]) + bf2f(gb[0]);
      float h1 = l1 + bf2f(ga[1]) + bf2f(gb[1]);
      s0 += h0; s1 += h1; q0 += h0*h0; q1 += h1*h1;
    }
  }
  bs[w][c0] = s0; bs[w][c0+1] = s1;
  bq[w][c0] = q0; bq[w][c0+1] = q1;
  __syncthreads();
  if (t < 128){
    atomicAdd(&stats[ST_SUM + j*128 + t], bs[0][t]+bs[1][t]+bs[2][t]+bs[3][t]);
    atomicAdd(&stats[ST_SQ  + j*128 + t], bq[0][t]+bq[1][t]+bq[2][t]+bq[3][t]);
  }
}

// ------ node-centric scatter for part j: macc[n] += mean_e att*relu(BN(h_j[e])) ------
__launch_bounds__(256)
__global__ void escat(const unsigned short* __restrict__ Y,
                      const int4* __restrict__ einfo,
                      const float* __restrict__ att,
                      const int* __restrict__ cnt, const int* __restrict__ start,
                      const float* __restrict__ stats,
                      float* __restrict__ macc, int j, int a, int b){
  const int w = threadIdx.x >> 6, lane = threadIdx.x & 63;
  const int n = blockIdx.x*4 + w;
  if (n >= NN) return;
  const int c = cnt[j*NN + n];
  if (c == 0) return;
  const float invZ = 1.0f / stats[ST_SEXP];
  const int cs = start[j*NN + n];
  const int c0 = lane*2;
  u16x2 lv = *(const u16x2*)(Y + (size_t)n*D3 + j*128 + c0);
  const float l0 = bf2f(lv[0]), l1 = bf2f(lv[1]);
  const float sc0 = stats[ST_SCALE + j*128 + c0],   sh0 = stats[ST_SHIFT + j*128 + c0];
  const float sc1 = stats[ST_SCALE + j*128 + c0+1], sh1 = stats[ST_SHIFT + j*128 + c0+1];
  float a0 = 0.f, a1 = 0.f;
  for (int k = 0; k < c; k++){
    const int4 ei = einfo[(size_t)j*NE + cs + k];
    const float av = att[ei.x] * invZ;
    u16x2 ga = *(const u16x2*)(Y + (size_t)ei.y*D3 + a*128 + c0);
    u16x2 gb = *(const u16x2*)(Y + (size_t)ei.z*D3 + b*128 + c0);
    float h0 = l0 + bf2f(ga[0]) + bf2f(gb[0]);
    float h1 = l1 + bf2f(ga[1]) + bf2f(gb[1]);
    a0 += av * fmaxf(h0*sc0 + sh0, 0.f);
    a1 += av * fmaxf(h1*sc1 + sh1, 0.f);
  }
  const float ic = 1.f / (float)c;
  float* mp = macc + (size_t)n*DD + c0;
  mp[0] += a0*ic;
  mp[1] += a1*ic;
}

// ---------------- BN finalize ----------------
__global__ void sfin_score(const float* g1, const float* be1, float* __restrict__ stats){
  if (threadIdx.x == 0){
    float mu = stats[ST_SUM1] / (float)NE;
    float var = stats[ST_SQ1] / (float)NE - mu*mu;
    float sc = g1[0] * rsqrtf(var + EPSBN);
    stats[ST_SCALE1] = sc;
    stats[ST_SHIFT1] = be1[0] - mu*sc;
  }
}

__global__ void sfin_cols(const float* g, const float* be, float* __restrict__ stats, int part){
  int t = threadIdx.x;
  if (t < 128){
    int idx = part*128 + t;
    float mu = stats[ST_SUM + idx] / (float)NE;
    float var = stats[ST_SQ + idx] / (float)NE - mu*mu;
    float sc = g[t] * rsqrtf(var + EPSBN);
    stats[ST_SCALE + idx] = sc;
    stats[ST_SHIFT + idx] = be[t] - mu*sc;
  }
}

// ---------------- softmax: max, then sum (stores exp in place) ----------------
__global__ void sm_max(float* __restrict__ sp, float* __restrict__ stats){
  const float sc = stats[ST_SCALE1], sh = stats[ST_SHIFT1];
  float lmax = 0.f;
  int stride = gridDim.x*blockDim.x;
  for (int i = blockIdx.x*blockDim.x + threadIdx.x; i < NE; i += stride){
    float s = fmaxf(sp[i]*sc + sh, 0.f);
    sp[i] = s;
    lmax = fmaxf(lmax, s);
  }
  #pragma unroll
  for (int o = 32; o; o >>= 1) lmax = fmaxf(lmax, __shfl_xor(lmax, o));
  __shared__ float red[4];
  if ((threadIdx.x & 63) == 0) red[threadIdx.x >> 6] = lmax;
  __syncthreads();
  if (threadIdx.x == 0){
    float m = fmaxf(fmaxf(red[0], red[1]), fmaxf(red[2], red[3]));
    atomicMax((unsigned int*)&stats[ST_MAX], __float_as_uint(m));
  }
}

__global__ void sm_sum(float* __restrict__ sp, float* __restrict__ stats){
  const float mx = __uint_as_float(((const unsigned int*)stats)[ST_MAX]);
  float ls = 0.f;
  int stride = gridDim.x*blockDim.x;
  for (int i = blockIdx.x*blockDim.x + threadIdx.x; i < NE; i += stride){
    float ex = __expf(sp[i] - mx);
    sp[i] = ex;
    ls += ex;
  }
  #pragma unroll
  for (int o = 32; o; o >>= 1) ls += __shfl_xor(ls, o);
  __shared__ float red[4];
  if ((threadIdx.x & 63) == 0) red[threadIdx.x >> 6] = ls;
  __syncthreads();
  if (threadIdx.x == 0)
    atomicAdd(&stats[ST_SEXP], red[0] + red[1] + red[2] + red[3]);
}

// ---------------- zb = bf16(macc @ Wtw^T), fused col stats ----------------
__launch_bounds__(256)
__global__ void g2_gemm(const float* __restrict__ A,
                        const unsigned short* __restrict__ Wtwb,
                        unsigned short* __restrict__ zb,
                        float* __restrict__ stats){
  __shared__ float ssum[128], ssq[128];
  const int t = threadIdx.x;
  const int w = t >> 6, lane = t & 63;
  const int lc = lane & 15, kg = lane >> 4;
  if (t < 128){ ssum[t] = 0.f; ssq[t] = 0.f; }
  const int m0 = blockIdx.x*64 + w*16;
  const int arow = m0 + lc;
  f32x4 acc[8];
  #pragma unroll
  for (int nf = 0; nf < 8; nf++){ acc[nf][0]=0.f; acc[nf][1]=0.f; acc[nf][2]=0.f; acc[nf][3]=0.f; }
  #pragma unroll
  for (int ks = 0; ks < 128; ks += 32){
    s16x8 a;
    if (arow < NN){
      f32x4 a0 = *(const f32x4*)(A + (size_t)arow*DD + ks + kg*8);
      f32x4 a1 = *(const f32x4*)(A + (size_t)arow*DD + ks + kg*8 + 4);
      a[0]=(short)f2bf(a0[0]); a[1]=(short)f2bf(a0[1]); a[2]=(short)f2bf(a0[2]); a[3]=(short)f2bf(a0[3]);
      a[4]=(short)f2bf(a1[0]); a[5]=(short)f2bf(a1[1]); a[6]=(short)f2bf(a1[2]); a[7]=(short)f2bf(a1[3]);
    } else {
      a[0]=0;a[1]=0;a[2]=0;a[3]=0;a[4]=0;a[5]=0;a[6]=0;a[7]=0;
    }
    #pragma unroll
    for (int nf = 0; nf < 8; nf++){
      s16x8 b = *(const s16x8*)(Wtwb + (nf*16 + lc)*DD + ks + kg*8);
      acc[nf] = __builtin_amdgcn_mfma_f32_16x16x32_bf16(a, b, acc[nf], 0, 0, 0);
    }
  }
  float ps[8], pq[8];
  #pragma unroll
  for (int nf = 0; nf < 8; nf++){
    ps[nf] = 0.f; pq[nf] = 0.f;
    const int col = nf*16 + lc;
    #pragma unroll
    for (int r = 0; r < 4; r++){
      int row = m0 + kg*4 + r;
      if (row < NN){
        float v = acc[nf][r];
        zb[(size_t)row*DD + col] = f2bf(v);
        ps[nf] += v; pq[nf] += v*v;
      }
    }
  }
  __syncthreads();
  #pragma unroll
  for (int nf = 0; nf < 8; nf++){
    atomicAdd(&ssum[nf*16 + lc], ps[nf]);
    atomicAdd(&ssq [nf*16 + lc], pq[nf]);
  }
  __syncthreads();
  if (t < 128){
    atomicAdd(&stats[ST_SUM2 + t], ssum[t]);
    atomicAdd(&stats[ST_SQ2  + t], ssq[t]);
  }
}

__global__ void sfin2(const float* gtw, const float* betw, float* __restrict__ stats){
  int c = threadIdx.x;
  if (c < 128){
    float mu = stats[ST_SUM2 + c] / (float)NN;
    float var = stats[ST_SQ2 + c] / (float)NN - mu*mu;
    float sc = gtw[c] * rsqrtf(var + EPSBN);
    stats[ST_SCALE2 + c] = sc;
    stats[ST_SHIFT2 + c] = betw[c] - mu*sc;
  }
}

// ---------------- x += relu(BN(zb)); refresh bf16 copy (vectorized) ----------------
__global__ void fuse_update(const unsigned short* __restrict__ zb,
                            const float* __restrict__ stats,
                            float* __restrict__ xcur, unsigned short* __restrict__ xb){
  const int tot = NN*DD/4;
  int stride = gridDim.x*blockDim.x;
  for (int i = blockIdx.x*blockDim.x + threadIdx.x; i < tot; i += stride){
    u16x4 z4 = ((const u16x4*)zb)[i];
    f32x4 x4 = ((const f32x4*)xcur)[i];
    const int c = (i*4) & 127;
    f32x4 o; u16x4 ob;
    #pragma unroll
    for (int j = 0; j < 4; j++){
      float hv = fmaxf(bf2f(z4[j])*stats[ST_SCALE2 + c + j] + stats[ST_SHIFT2 + c + j], 0.f);
      o[j] = x4[j] + hv;
      ob[j] = f2bf(o[j]);
    }
    ((f32x4*)xcur)[i] = o;
    ((u16x4*)xb)[i] = ob;
  }
}

extern "C" void kernel_launch(void* const* d_in, const int* in_sizes, int n_in,
                              void* d_out, int out_size, void* d_ws, size_t ws_size,
                              hipStream_t stream){
  const float* x    = (const float*)d_in[0];
  const int*   twi  = (const int*)d_in[1];
  const float* W_T  = (const float*)d_in[2];
  const float* W_M  = (const float*)d_in[3];
  const float* W_B  = (const float*)d_in[4];
  const float* W_1  = (const float*)d_in[5];
  const float* W_tw = (const float*)d_in[6];
  const float* g_T  = (const float*)d_in[8];
  const float* be_T = (const float*)d_in[9];
  const float* g_M  = (const float*)d_in[11];
  const float* be_M = (const float*)d_in[12];
  const float* g_B  = (const float*)d_in[14];
  const float* be_B = (const float*)d_in[15];
  const float* g_1  = (const float*)d_in[17];
  const float* be_1 = (const float*)d_in[18];
  const float* g_tw = (const float*)d_in[20];
  const float* be_tw= (const float*)d_in[21];
  float* xcur = (float*)d_out;

  char* ws = (char*)d_ws;
  size_t off = 0;
  auto take = [&](size_t b){ size_t o = off; off += (b + 255) & ~(size_t)255; return o; };
  float* stats = (float*)(ws + take(ST_TOTAL*4));
  unsigned short* Wjcat = (unsigned short*)(ws + take((size_t)3*D3*DD*2));
  unsigned short* Wtwb  = (unsigned short*)(ws + take(128*128*2));
  int* bsums  = (int*)(ws + take((size_t)3*SCB*4));
  int* cnt    = (int*)(ws + take((size_t)3*NN*4));
  int* startA = (int*)(ws + take((size_t)3*NN*4));
  int* cursor = (int*)(ws + take((size_t)3*NN*4));
  int4* einfo = (int4*)(ws + take((size_t)3*NE*16));
  float* sp   = (float*)(ws + take((size_t)NE*4));
  float* S    = (float*)(ws + take((size_t)3*NN*4));
  unsigned short* xb = (unsigned short*)(ws + take((size_t)NN*DD*2));
  float* macc = (float*)(ws + take((size_t)NN*DD*4));
  unsigned short* Y = (unsigned short*)(ws + take((size_t)NN*D3*2));
  unsigned short* zb = Y;   // alias: zb written by g2 only after last escat consumed Y
  if (ws_size < off) return;  // avoid faulting

  hipMemsetAsync(cnt, 0, (size_t)3*NN*4, stream);
  hipMemsetAsync(cursor, 0, (size_t)3*NN*4, stream);
  init_x<<<1024, 256, 0, stream>>>(x, xcur, xb);
  csr_cnt<<<(NE+255)/256, 256, 0, stream>>>(twi, cnt);
  scan_bs<<<dim3(SCB, 3), 256, 0, stream>>>(cnt, bsums);
  scan_top<<<1, 64, 0, stream>>>(bsums);
  scan_fin<<<dim3(SCB, 3), 256, 0, stream>>>(cnt, bsums, startA);
  csr_fill<<<(NE+255)/256, 256, 0, stream>>>(twi, startA, cursor, einfo);

  const int NGB = (NN + 63)/64;     // ngemm/g2 blocks
  const int NDB = (NN + 3)/4;       // node-wave blocks

  for (int l = 0; l < KL; l++){
    hipMemsetAsync(stats, 0, ST_TOTAL*4, stream);
    hipMemsetAsync(macc, 0, (size_t)NN*DD*4, stream);
    wprep<<<640, 256, 0, stream>>>(W_T + (size_t)l*DD*D3, W_M + (size_t)l*DD*D3,
                                   W_B + (size_t)l*DD*D3, W_tw + (size_t)l*DD*DD,
                                   Wjcat, Wtwb);
    const float* gs[3]  = {g_T  + (size_t)l*DD, g_M  + (size_t)l*DD, g_B  + (size_t)l*DD};
    const float* bes[3] = {be_T + (size_t)l*DD, be_M + (size_t)l*DD, be_B + (size_t)l*DD};

    // score path (node-decomposed)
    nscore<<<(NN+255)/256, 256, 0, stream>>>(xb, W_1 + (size_t)l*D3, S);
    escore<<<256, 256, 0, stream>>>(twi, S, sp, stats);
    sfin_score<<<1, 64, 0, stream>>>(g_1 + l, be_1 + l, stats);
    sm_max<<<256, 256, 0, stream>>>(sp, stats);
    sm_sum<<<256, 256, 0, stream>>>(sp, stats);

    // per-part: dense node GEMM -> edge stats -> BN finalize -> node scatter
    for (int j = 0; j < 3; j++){
      ngemm<<<NGB, 256, 0, stream>>>(xb, Wjcat + (size_t)j*D3*DD, Y);
      estat<<<1024, 256, 0, stream>>>(Y, einfo, cnt, startA, stats, j, (j+1)%3, (j+2)%3);
      sfin_cols<<<1, 128, 0, stream>>>(gs[j], bes[j], stats, j);
      escat<<<NDB, 256, 0, stream>>>(Y, einfo, sp, cnt, startA, stats, macc,
                                     j, (j+1)%3, (j+2)%3);
    }

    g2_gemm<<<NGB, 256, 0, stream>>>(macc, Wtwb, zb, stats);
    sfin2<<<1, 128, 0, stream>>>(g_tw + (size_t)l*DD, be_tw + (size_t)l*DD, stats);
    fuse_update<<<1024, 256, 0, stream>>>(zb, stats, xcur, xb);
  }
}

// Round 14
// 1957.484 us; speedup vs baseline: 2.0036x; 1.0675x over previous
//
#include <hip/hip_runtime.h>

#define NN 100000
#define NE 400000
#define DD 128
#define D3 384
#define KL 2
#define EPSBN 1e-5f
#define SCB ((NN + 1023) / 1024)

typedef __attribute__((ext_vector_type(8))) short s16x8;
typedef __attribute__((ext_vector_type(4))) float f32x4;
typedef __attribute__((ext_vector_type(4))) unsigned short u16x4;
typedef __attribute__((ext_vector_type(2))) unsigned short u16x2;

#define ST_SUM    0      // [384]
#define ST_SQ     384    // [384]
#define ST_SCALE  768    // [384]
#define ST_SHIFT  1152   // [384]
#define ST_SUM1   1536
#define ST_SQ1    1537
#define ST_MAX    1538
#define ST_SEXP   1539
#define ST_SCALE1 1540
#define ST_SHIFT1 1541
#define ST_SUM2   1542   // [128]
#define ST_SQ2    1670   // [128]
#define ST_SCALE2 1798   // [128]
#define ST_SHIFT2 1926   // [128]
#define ST_TOTAL  2054

__device__ __forceinline__ float bf2f(unsigned short u){
  return __uint_as_float(((unsigned int)u) << 16);
}
__device__ __forceinline__ unsigned short f2bf(float f){
  unsigned int x = __float_as_uint(f);
  x = x + 0x7FFFu + ((x >> 16) & 1u);
  return (unsigned short)(x >> 16);
}

// ---------------- init: x -> xcur (f32) + xb (bf16), vectorized ----------------
__global__ void init_x(const float* __restrict__ x, float* __restrict__ xcur,
                       unsigned short* __restrict__ xb){
  const int tot = NN*DD/4;
  int stride = gridDim.x * blockDim.x;
  for (int i = blockIdx.x*blockDim.x + threadIdx.x; i < tot; i += stride){
    f32x4 v = ((const f32x4*)x)[i];
    ((f32x4*)xcur)[i] = v;
    u16x4 o; o[0]=f2bf(v[0]); o[1]=f2bf(v[1]); o[2]=f2bf(v[2]); o[3]=f2bf(v[3]);
    ((u16x4*)xb)[i] = o;
  }
}

// --------- weight prep: Wjcat[j][s*128+o][c] = Wj[o][s*128+c]  (bf16) ---------
__global__ void wprep(const float* __restrict__ WT, const float* __restrict__ WM,
                      const float* __restrict__ WB, const float* __restrict__ Wtw,
                      unsigned short* __restrict__ Wjcat, unsigned short* __restrict__ Wtwb){
  int stride = gridDim.x * blockDim.x;
  int tid = blockIdx.x*blockDim.x + threadIdx.x;
  for (int i = tid; i < 3*D3*DD; i += stride){
    int j = i / (D3*DD);
    int rem = i - j*(D3*DD);
    int scol = rem >> 7;      // output col 0..383
    int c = rem & 127;        // input col
    int s = scol >> 7;        // slot
    int o = scol & 127;       // output feature within slot
    const float* Wj = (j==0) ? WT : ((j==1) ? WM : WB);
    Wjcat[i] = f2bf(Wj[o*D3 + s*128 + c]);
  }
  for (int i = tid; i < 128*128; i += stride) Wtwb[i] = f2bf(Wtw[i]);
}

// ---------------- CSR build ----------------
__global__ void csr_cnt(const int* __restrict__ twi, int* __restrict__ cnt){
  int e = blockIdx.x*blockDim.x + threadIdx.x;
  if (e < NE){
    atomicAdd(&cnt[0*NN + twi[0*NE + e]], 1);
    atomicAdd(&cnt[1*NN + twi[1*NE + e]], 1);
    atomicAdd(&cnt[2*NN + twi[2*NE + e]], 1);
  }
}

__global__ void scan_bs(const int* __restrict__ cnt, int* __restrict__ bsums){
  const int p = blockIdx.y, b = blockIdx.x, t = threadIdx.x;
  const int base = b * 1024;
  int s = 0;
  #pragma unroll
  for (int j = 0; j < 4; j++){
    int i = base + t + j*256;
    if (i < NN) s += cnt[p*NN + i];
  }
  __shared__ int red[256];
  red[t] = s; __syncthreads();
  #pragma unroll
  for (int o = 128; o; o >>= 1){
    if (t < o) red[t] += red[t+o];
    __syncthreads();
  }
  if (t == 0) bsums[p*SCB + b] = red[0];
}

__global__ void scan_top(int* __restrict__ bsums){
  const int p = threadIdx.x;
  if (p < 3){
    int run = 0;
    for (int i = 0; i < SCB; i++){ int v = bsums[p*SCB + i]; bsums[p*SCB + i] = run; run += v; }
  }
}

__global__ void scan_fin(const int* __restrict__ cnt, const int* __restrict__ bsums,
                         int* __restrict__ start){
  const int p = blockIdx.y, b = blockIdx.x, t = threadIdx.x;
  const int base = b * 1024;
  int v[4]; int s = 0;
  #pragma unroll
  for (int j = 0; j < 4; j++){
    int i = base + t*4 + j;
    v[j] = (i < NN) ? cnt[p*NN + i] : 0;
    s += v[j];
  }
  __shared__ int red[256];
  red[t] = s; __syncthreads();
  #pragma unroll
  for (int o = 1; o < 256; o <<= 1){
    int other = (t >= o) ? red[t - o] : 0;
    __syncthreads();
    red[t] += other;
    __syncthreads();
  }
  int ex = red[t] - s + bsums[p*SCB + b];
  #pragma unroll
  for (int j = 0; j < 4; j++){
    int i = base + t*4 + j;
    if (i < NN) start[p*NN + i] = ex;
    ex += v[j];
  }
}

// einfo[p][slot] = {e, n_{(p+1)%3}, n_{(p+2)%3}, n_p}
__global__ void csr_fill(const int* __restrict__ twi, const int* __restrict__ start,
                         int* __restrict__ cursor, int4* __restrict__ einfo){
  int e = blockIdx.x*blockDim.x + threadIdx.x;
  if (e < NE){
    int nd0 = twi[e], nd1 = twi[NE+e], nd2 = twi[2*NE+e];
    int nd[3] = {nd0, nd1, nd2};
    #pragma unroll
    for (int p = 0; p < 3; p++){
      int n = nd[p];
      int pos = atomicAdd(&cursor[p*NN + n], 1);
      int4 v;
      v.x = e; v.y = nd[(p+1)%3]; v.z = nd[(p+2)%3]; v.w = n;
      einfo[(size_t)p*NE + start[p*NN + n] + pos] = v;
    }
  }
}

// ---------------- node scores: S[s][n] = x[n] . w1[s*128: s*128+128] ----------------
__global__ void nscore(const unsigned short* __restrict__ xb,
                       const float* __restrict__ W1, float* __restrict__ S){
  __shared__ float w1s[384];
  const int t = threadIdx.x;
  for (int i = t; i < 384; i += 256) w1s[i] = W1[i];
  __syncthreads();
  const int n = blockIdx.x*256 + t;
  if (n >= NN) return;
  float s0 = 0.f, s1 = 0.f, s2 = 0.f;
  for (int k = 0; k < 128; k += 8){
    s16x8 v = *(const s16x8*)(xb + (size_t)n*DD + k);
    #pragma unroll
    for (int u = 0; u < 8; u++){
      float xv = bf2f((unsigned short)v[u]);
      s0 += xv * w1s[k+u];
      s1 += xv * w1s[128+k+u];
      s2 += xv * w1s[256+k+u];
    }
  }
  S[n] = s0; S[NN+n] = s1; S[2*NN+n] = s2;
}

// ------- edge scores: sp[e] = S0[i0]+S1[i1]+S2[i2]; block-reduced sum/sumsq -------
__global__ void escore(const int* __restrict__ twi, const float* __restrict__ S,
                       float* __restrict__ sp, float* __restrict__ stats){
  float lsum = 0.f, lsq = 0.f;
  const int stride = gridDim.x*blockDim.x;
  for (int e = blockIdx.x*blockDim.x + threadIdx.x; e < NE; e += stride){
    float s = S[twi[e]] + S[NN + twi[NE+e]] + S[2*NN + twi[2*NE+e]];
    sp[e] = s;
    lsum += s; lsq += s*s;
  }
  #pragma unroll
  for (int o = 32; o; o >>= 1){ lsum += __shfl_xor(lsum, o); lsq += __shfl_xor(lsq, o); }
  __shared__ float rs[4], rq[4];
  if ((threadIdx.x & 63) == 0){ rs[threadIdx.x >> 6] = lsum; rq[threadIdx.x >> 6] = lsq; }
  __syncthreads();
  if (threadIdx.x == 0){
    atomicAdd(&stats[ST_SUM1], rs[0]+rs[1]+rs[2]+rs[3]);
    atomicAdd(&stats[ST_SQ1],  rq[0]+rq[1]+rq[2]+rq[3]);
  }
}

// ------ dense node GEMM: Y[n, 0:384] = xb[n] @ Wjcat_j^T, coalesced LDS-repack ------
__launch_bounds__(256)
__global__ void ngemm(const unsigned short* __restrict__ xb,
                      const unsigned short* __restrict__ Wj,   // pre-offset to part j
                      unsigned short* __restrict__ Y){
  __shared__ unsigned short ltu[4][16][128];   // 16 KB wave-local repack
  const int t = threadIdx.x;
  const int w = t >> 6, lane = t & 63;
  const int lc = lane & 15, kg = lane >> 4;
  const int m0 = blockIdx.x*64 + w*16;
  const int arow = m0 + lc;
  f32x4 acc[24];
  #pragma unroll
  for (int nf = 0; nf < 24; nf++){ acc[nf][0]=0.f; acc[nf][1]=0.f; acc[nf][2]=0.f; acc[nf][3]=0.f; }
  #pragma unroll
  for (int ks = 0; ks < 4; ks++){
    s16x8 a;
    if (arow < NN) a = *(const s16x8*)(xb + (size_t)arow*DD + ks*32 + kg*8);
    else { a[0]=0;a[1]=0;a[2]=0;a[3]=0;a[4]=0;a[5]=0;a[6]=0;a[7]=0; }
    #pragma unroll
    for (int nf = 0; nf < 24; nf++){
      s16x8 b = *(const s16x8*)(Wj + (nf*16 + lc)*DD + ks*32 + kg*8);
      acc[nf] = __builtin_amdgcn_mfma_f32_16x16x32_bf16(a, b, acc[nf], 0, 0, 0);
    }
  }
  // 3 chunks of 128 cols: wave-local u16 repack -> coalesced u16x4 stores
  const int rl = lane >> 5, cg = lane & 31;
  #pragma unroll
  for (int ch = 0; ch < 3; ch++){
    #pragma unroll
    for (int f = 0; f < 8; f++){
      const int nf = ch*8 + f;
      #pragma unroll
      for (int r = 0; r < 4; r++)
        ltu[w][kg*4 + r][f*16 + lc] = f2bf(acc[nf][r]);
    }
    #pragma unroll
    for (int it = 0; it < 8; it++){
      const int row = it*2 + rl;
      const int grow = m0 + row;
      if (grow < NN){
        u16x4 o = *(const u16x4*)&ltu[w][row][cg*4];
        *(u16x4*)(Y + (size_t)grow*D3 + ch*128 + cg*4) = o;
      }
    }
  }
}

// ----- edge stats for part j (node-centric CSR walk, 2 edges/wave-iter) -----
__launch_bounds__(256)
__global__ void estat(const unsigned short* __restrict__ Y,
                      const int4* __restrict__ einfo,
                      const int* __restrict__ cnt, const int* __restrict__ start,
                      float* __restrict__ stats, int j, int a, int b){
  __shared__ float bs[4][128], bq[4][128];
  const int t = threadIdx.x, w = t >> 6, lane = t & 63;
  const int half = lane >> 5, hl = lane & 31;
  const int c0 = hl*4;
  float s0=0,s1=0,s2=0,s3=0, q0=0,q1=0,q2=0,q3=0;
  const int gw = blockIdx.x*4 + w;
  const int nw = gridDim.x*4;
  for (int n = gw; n < NN; n += nw){
    const int c = cnt[j*NN + n];
    if (c == 0) continue;
    const int cs = start[j*NN + n];
    u16x4 lv = *(const u16x4*)(Y + (size_t)n*D3 + j*128 + c0);
    const float l0 = bf2f(lv[0]), l1 = bf2f(lv[1]), l2 = bf2f(lv[2]), l3 = bf2f(lv[3]);
    for (int k = 0; k < c; k += 2){
      const int kk = k + half;
      const bool valid = kk < c;
      const int4 ei = einfo[(size_t)j*NE + cs + (valid ? kk : c-1)];
      u16x4 ga = *(const u16x4*)(Y + (size_t)ei.y*D3 + a*128 + c0);
      u16x4 gb = *(const u16x4*)(Y + (size_t)ei.z*D3 + b*128 + c0);
      if (valid){
        float h0 = l0 + bf2f(ga[0]) + bf2f(gb[0]);
        float h1 = l1 + bf2f(ga[1]) + bf2f(gb[1]);
        float h2 = l2 + bf2f(ga[2]) + bf2f(gb[2]);
        float h3 = l3 + bf2f(ga[3]) + bf2f(gb[3]);
        s0 += h0; s1 += h1; s2 += h2; s3 += h3;
        q0 += h0*h0; q1 += h1*h1; q2 += h2*h2; q3 += h3*h3;
      }
    }
  }
  s0 += __shfl_xor(s0, 32); s1 += __shfl_xor(s1, 32);
  s2 += __shfl_xor(s2, 32); s3 += __shfl_xor(s3, 32);
  q0 += __shfl_xor(q0, 32); q1 += __shfl_xor(q1, 32);
  q2 += __shfl_xor(q2, 32); q3 += __shfl_xor(q3, 32);
  if (half == 0){
    bs[w][c0] = s0; bs[w][c0+1] = s1; bs[w][c0+2] = s2; bs[w][c0+3] = s3;
    bq[w][c0] = q0; bq[w][c0+1] = q1; bq[w][c0+2] = q2; bq[w][c0+3] = q3;
  }
  __syncthreads();
  if (t < 128){
    atomicAdd(&stats[ST_SUM + j*128 + t], bs[0][t]+bs[1][t]+bs[2][t]+bs[3][t]);
    atomicAdd(&stats[ST_SQ  + j*128 + t], bq[0][t]+bq[1][t]+bq[2][t]+bq[3][t]);
  }
}

// -- node-centric scatter for part j (2 edges/wave-iter): macc[n] += mean --
__launch_bounds__(256)
__global__ void escat(const unsigned short* __restrict__ Y,
                      const int4* __restrict__ einfo,
                      const float* __restrict__ att,
                      const int* __restrict__ cnt, const int* __restrict__ start,
                      const float* __restrict__ stats,
                      float* __restrict__ macc, int j, int a, int b){
  const int w = threadIdx.x >> 6, lane = threadIdx.x & 63;
  const int half = lane >> 5, hl = lane & 31;
  const int n = blockIdx.x*4 + w;
  if (n >= NN) return;
  const int c = cnt[j*NN + n];
  if (c == 0) return;
  const float invZ = 1.0f / stats[ST_SEXP];
  const int cs = start[j*NN + n];
  const int c0 = hl*4;
  u16x4 lv = *(const u16x4*)(Y + (size_t)n*D3 + j*128 + c0);
  const float l0 = bf2f(lv[0]), l1 = bf2f(lv[1]), l2 = bf2f(lv[2]), l3 = bf2f(lv[3]);
  f32x4 sc = *(const f32x4*)(stats + ST_SCALE + j*128 + c0);
  f32x4 sh = *(const f32x4*)(stats + ST_SHIFT + j*128 + c0);
  float a0=0,a1=0,a2=0,a3=0;
  for (int k = 0; k < c; k += 2){
    const int kk = k + half;
    const bool valid = kk < c;
    const int4 ei = einfo[(size_t)j*NE + cs + (valid ? kk : c-1)];
    const float av = valid ? att[ei.x] * invZ : 0.f;
    u16x4 ga = *(const u16x4*)(Y + (size_t)ei.y*D3 + a*128 + c0);
    u16x4 gb = *(const u16x4*)(Y + (size_t)ei.z*D3 + b*128 + c0);
    float h0 = l0 + bf2f(ga[0]) + bf2f(gb[0]);
    float h1 = l1 + bf2f(ga[1]) + bf2f(gb[1]);
    float h2 = l2 + bf2f(ga[2]) + bf2f(gb[2]);
    float h3 = l3 + bf2f(ga[3]) + bf2f(gb[3]);
    a0 += av * fmaxf(h0*sc[0] + sh[0], 0.f);
    a1 += av * fmaxf(h1*sc[1] + sh[1], 0.f);
    a2 += av * fmaxf(h2*sc[2] + sh[2], 0.f);
    a3 += av * fmaxf(h3*sc[3] + sh[3], 0.f);
  }
  a0 += __shfl_xor(a0, 32); a1 += __shfl_xor(a1, 32);
  a2 += __shfl_xor(a2, 32); a3 += __shfl_xor(a3, 32);
  if (half == 0){
    const float ic = 1.f / (float)c;
    f32x4* mp = (f32x4*)(macc + (size_t)n*DD + c0);
    f32x4 old = *mp;
    old[0] += a0*ic; old[1] += a1*ic; old[2] += a2*ic; old[3] += a3*ic;
    *mp = old;
  }
}

// ---------------- BN finalize ----------------
__global__ void sfin_score(const float* g1, const float* be1, float* __restrict__ stats){
  if (threadIdx.x == 0){
    float mu = stats[ST_SUM1] / (float)NE;
    float var = stats[ST_SQ1] / (float)NE - mu*mu;
    float sc = g1[0] * rsqrtf(var + EPSBN);
    stats[ST_SCALE1] = sc;
    stats[ST_SHIFT1] = be1[0] - mu*sc;
  }
}

__global__ void sfin_cols(const float* g, const float* be, float* __restrict__ stats, int part){
  int t = threadIdx.x;
  if (t < 128){
    int idx = part*128 + t;
    float mu = stats[ST_SUM + idx] / (float)NE;
    float var = stats[ST_SQ + idx] / (float)NE - mu*mu;
    float sc = g[t] * rsqrtf(var + EPSBN);
    stats[ST_SCALE + idx] = sc;
    stats[ST_SHIFT + idx] = be[t] - mu*sc;
  }
}

// ---------------- softmax: max, then sum (stores exp in place) ----------------
__global__ void sm_max(float* __restrict__ sp, float* __restrict__ stats){
  const float sc = stats[ST_SCALE1], sh = stats[ST_SHIFT1];
  float lmax = 0.f;
  int stride = gridDim.x*blockDim.x;
  for (int i = blockIdx.x*blockDim.x + threadIdx.x; i < NE; i += stride){
    float s = fmaxf(sp[i]*sc + sh, 0.f);
    sp[i] = s;
    lmax = fmaxf(lmax, s);
  }
  #pragma unroll
  for (int o = 32; o; o >>= 1) lmax = fmaxf(lmax, __shfl_xor(lmax, o));
  __shared__ float red[4];
  if ((threadIdx.x & 63) == 0) red[threadIdx.x >> 6] = lmax;
  __syncthreads();
  if (threadIdx.x == 0){
    float m = fmaxf(fmaxf(red[0], red[1]), fmaxf(red[2], red[3]));
    atomicMax((unsigned int*)&stats[ST_MAX], __float_as_uint(m));
  }
}

__global__ void sm_sum(float* __restrict__ sp, float* __restrict__ stats){
  const float mx = __uint_as_float(((const unsigned int*)stats)[ST_MAX]);
  float ls = 0.f;
  int stride = gridDim.x*blockDim.x;
  for (int i = blockIdx.x*blockDim.x + threadIdx.x; i < NE; i += stride){
    float ex = __expf(sp[i] - mx);
    sp[i] = ex;
    ls += ex;
  }
  #pragma unroll
  for (int o = 32; o; o >>= 1) ls += __shfl_xor(ls, o);
  __shared__ float red[4];
  if ((threadIdx.x & 63) == 0) red[threadIdx.x >> 6] = ls;
  __syncthreads();
  if (threadIdx.x == 0)
    atomicAdd(&stats[ST_SEXP], red[0] + red[1] + red[2] + red[3]);
}

// ---------------- zb = bf16(macc @ Wtw^T), fused col stats ----------------
__launch_bounds__(256)
__global__ void g2_gemm(const float* __restrict__ A,
                        const unsigned short* __restrict__ Wtwb,
                        unsigned short* __restrict__ zb,
                        float* __restrict__ stats){
  __shared__ float ssum[128], ssq[128];
  const int t = threadIdx.x;
  const int w = t >> 6, lane = t & 63;
  const int lc = lane & 15, kg = lane >> 4;
  if (t < 128){ ssum[t] = 0.f; ssq[t] = 0.f; }
  const int m0 = blockIdx.x*64 + w*16;
  const int arow = m0 + lc;
  f32x4 acc[8];
  #pragma unroll
  for (int nf = 0; nf < 8; nf++){ acc[nf][0]=0.f; acc[nf][1]=0.f; acc[nf][2]=0.f; acc[nf][3]=0.f; }
  #pragma unroll
  for (int ks = 0; ks < 128; ks += 32){
    s16x8 a;
    if (arow < NN){
      f32x4 a0 = *(const f32x4*)(A + (size_t)arow*DD + ks + kg*8);
      f32x4 a1 = *(const f32x4*)(A + (size_t)arow*DD + ks + kg*8 + 4);
      a[0]=(short)f2bf(a0[0]); a[1]=(short)f2bf(a0[1]); a[2]=(short)f2bf(a0[2]); a[3]=(short)f2bf(a0[3]);
      a[4]=(short)f2bf(a1[0]); a[5]=(short)f2bf(a1[1]); a[6]=(short)f2bf(a1[2]); a[7]=(short)f2bf(a1[3]);
    } else {
      a[0]=0;a[1]=0;a[2]=0;a[3]=0;a[4]=0;a[5]=0;a[6]=0;a[7]=0;
    }
    #pragma unroll
    for (int nf = 0; nf < 8; nf++){
      s16x8 b = *(const s16x8*)(Wtwb + (nf*16 + lc)*DD + ks + kg*8);
      acc[nf] = __builtin_amdgcn_mfma_f32_16x16x32_bf16(a, b, acc[nf], 0, 0, 0);
    }
  }
  float ps[8], pq[8];
  #pragma unroll
  for (int nf = 0; nf < 8; nf++){
    ps[nf] = 0.f; pq[nf] = 0.f;
    const int col = nf*16 + lc;
    #pragma unroll
    for (int r = 0; r < 4; r++){
      int row = m0 + kg*4 + r;
      if (row < NN){
        float v = acc[nf][r];
        zb[(size_t)row*DD + col] = f2bf(v);
        ps[nf] += v; pq[nf] += v*v;
      }
    }
  }
  __syncthreads();
  #pragma unroll
  for (int nf = 0; nf < 8; nf++){
    atomicAdd(&ssum[nf*16 + lc], ps[nf]);
    atomicAdd(&ssq [nf*16 + lc], pq[nf]);
  }
  __syncthreads();
  if (t < 128){
    atomicAdd(&stats[ST_SUM2 + t], ssum[t]);
    atomicAdd(&stats[ST_SQ2  + t], ssq[t]);
  }
}

__global__ void sfin2(const float* gtw, const float* betw, float* __restrict__ stats){
  int c = threadIdx.x;
  if (c < 128){
    float mu = stats[ST_SUM2 + c] / (float)NN;
    float var = stats[ST_SQ2 + c] / (float)NN - mu*mu;
    float sc = gtw[c] * rsqrtf(var + EPSBN);
    stats[ST_SCALE2 + c] = sc;
    stats[ST_SHIFT2 + c] = betw[c] - mu*sc;
  }
}

// ---------------- x += relu(BN(zb)); refresh bf16 copy (vectorized) ----------------
__global__ void fuse_update(const unsigned short* __restrict__ zb,
                            const float* __restrict__ stats,
                            float* __restrict__ xcur, unsigned short* __restrict__ xb){
  const int tot = NN*DD/4;
  int stride = gridDim.x*blockDim.x;
  for (int i = blockIdx.x*blockDim.x + threadIdx.x; i < tot; i += stride){
    u16x4 z4 = ((const u16x4*)zb)[i];
    f32x4 x4 = ((const f32x4*)xcur)[i];
    const int c = (i*4) & 127;
    f32x4 o; u16x4 ob;
    #pragma unroll
    for (int j = 0; j < 4; j++){
      float hv = fmaxf(bf2f(z4[j])*stats[ST_SCALE2 + c + j] + stats[ST_SHIFT2 + c + j], 0.f);
      o[j] = x4[j] + hv;
      ob[j] = f2bf(o[j]);
    }
    ((f32x4*)xcur)[i] = o;
    ((u16x4*)xb)[i] = ob;
  }
}

extern "C" void kernel_launch(void* const* d_in, const int* in_sizes, int n_in,
                              void* d_out, int out_size, void* d_ws, size_t ws_size,
                              hipStream_t stream){
  const float* x    = (const float*)d_in[0];
  const int*   twi  = (const int*)d_in[1];
  const float* W_T  = (const float*)d_in[2];
  const float* W_M  = (const float*)d_in[3];
  const float* W_B  = (const float*)d_in[4];
  const float* W_1  = (const float*)d_in[5];
  const float* W_tw = (const float*)d_in[6];
  const float* g_T  = (const float*)d_in[8];
  const float* be_T = (const float*)d_in[9];
  const float* g_M  = (const float*)d_in[11];
  const float* be_M = (const float*)d_in[12];
  const float* g_B  = (const float*)d_in[14];
  const float* be_B = (const float*)d_in[15];
  const float* g_1  = (const float*)d_in[17];
  const float* be_1 = (const float*)d_in[18];
  const float* g_tw = (const float*)d_in[20];
  const float* be_tw= (const float*)d_in[21];
  float* xcur = (float*)d_out;

  char* ws = (char*)d_ws;
  size_t off = 0;
  auto take = [&](size_t b){ size_t o = off; off += (b + 255) & ~(size_t)255; return o; };
  float* stats = (float*)(ws + take(ST_TOTAL*4));
  unsigned short* Wjcat = (unsigned short*)(ws + take((size_t)3*D3*DD*2));
  unsigned short* Wtwb  = (unsigned short*)(ws + take(128*128*2));
  int* bsums  = (int*)(ws + take((size_t)3*SCB*4));
  int* cnt    = (int*)(ws + take((size_t)3*NN*4));
  int* startA = (int*)(ws + take((size_t)3*NN*4));
  int* cursor = (int*)(ws + take((size_t)3*NN*4));
  int4* einfo = (int4*)(ws + take((size_t)3*NE*16));
  float* sp   = (float*)(ws + take((size_t)NE*4));
  float* S    = (float*)(ws + take((size_t)3*NN*4));
  unsigned short* xb = (unsigned short*)(ws + take((size_t)NN*DD*2));
  float* macc = (float*)(ws + take((size_t)NN*DD*4));
  unsigned short* Y = (unsigned short*)(ws + take((size_t)NN*D3*2));
  unsigned short* zb = Y;   // alias: zb written by g2 only after last escat consumed Y
  if (ws_size < off) return;  // avoid faulting

  hipMemsetAsync(cnt, 0, (size_t)3*NN*4, stream);
  hipMemsetAsync(cursor, 0, (size_t)3*NN*4, stream);
  init_x<<<1024, 256, 0, stream>>>(x, xcur, xb);
  csr_cnt<<<(NE+255)/256, 256, 0, stream>>>(twi, cnt);
  scan_bs<<<dim3(SCB, 3), 256, 0, stream>>>(cnt, bsums);
  scan_top<<<1, 64, 0, stream>>>(bsums);
  scan_fin<<<dim3(SCB, 3), 256, 0, stream>>>(cnt, bsums, startA);
  csr_fill<<<(NE+255)/256, 256, 0, stream>>>(twi, startA, cursor, einfo);

  const int NGB = (NN + 63)/64;     // ngemm/g2 blocks
  const int NDB = (NN + 3)/4;       // node-wave blocks

  for (int l = 0; l < KL; l++){
    hipMemsetAsync(stats, 0, ST_TOTAL*4, stream);
    hipMemsetAsync(macc, 0, (size_t)NN*DD*4, stream);
    wprep<<<640, 256, 0, stream>>>(W_T + (size_t)l*DD*D3, W_M + (size_t)l*DD*D3,
                                   W_B + (size_t)l*DD*D3, W_tw + (size_t)l*DD*DD,
                                   Wjcat, Wtwb);
    const float* gs[3]  = {g_T  + (size_t)l*DD, g_M  + (size_t)l*DD, g_B  + (size_t)l*DD};
    const float* bes[3] = {be_T + (size_t)l*DD, be_M + (size_t)l*DD, be_B + (size_t)l*DD};

    // score path (node-decomposed)
    nscore<<<(NN+255)/256, 256, 0, stream>>>(xb, W_1 + (size_t)l*D3, S);
    escore<<<256, 256, 0, stream>>>(twi, S, sp, stats);
    sfin_score<<<1, 64, 0, stream>>>(g_1 + l, be_1 + l, stats);
    sm_max<<<256, 256, 0, stream>>>(sp, stats);
    sm_sum<<<256, 256, 0, stream>>>(sp, stats);

    // per-part: dense node GEMM -> edge stats -> BN finalize -> node scatter
    for (int j = 0; j < 3; j++){
      ngemm<<<NGB, 256, 0, stream>>>(xb, Wjcat + (size_t)j*D3*DD, Y);
      estat<<<1024, 256, 0, stream>>>(Y, einfo, cnt, startA, stats, j, (j+1)%3, (j+2)%3);
      sfin_cols<<<1, 128, 0, stream>>>(gs[j], bes[j], stats, j);
      escat<<<NDB, 256, 0, stream>>>(Y, einfo, sp, cnt, startA, stats, macc,
                                     j, (j+1)%3, (j+2)%3);
    }

    g2_gemm<<<NGB, 256, 0, stream>>>(macc, Wtwb, zb, stats);
    sfin2<<<1, 128, 0, stream>>>(g_tw + (size_t)l*DD, be_tw + (size_t)l*DD, stats);
    fuse_update<<<1024, 256, 0, stream>>>(zb, stats, xcur, xb);
  }
}

// Round 15
// 1950.020 us; speedup vs baseline: 2.0113x; 1.0038x over previous
//
#include <hip/hip_runtime.h>

#define NN 100000
#define NE 400000
#define DD 128
#define D3 384
#define KL 2
#define EPSBN 1e-5f
#define SCB ((NN + 1023) / 1024)

typedef __attribute__((ext_vector_type(8))) short s16x8;
typedef __attribute__((ext_vector_type(4))) float f32x4;
typedef __attribute__((ext_vector_type(4))) unsigned short u16x4;
typedef __attribute__((ext_vector_type(2))) unsigned short u16x2;

#define ST_SUM    0      // [384]
#define ST_SQ     384    // [384]
#define ST_SCALE  768    // [384]
#define ST_SHIFT  1152   // [384]
#define ST_SUM1   1536
#define ST_SQ1    1537
#define ST_MAX    1538
#define ST_SEXP   1539
#define ST_SCALE1 1540
#define ST_SHIFT1 1541
#define ST_SUM2   1542   // [128]
#define ST_SQ2    1670   // [128]
#define ST_SCALE2 1798   // [128]
#define ST_SHIFT2 1926   // [128]
#define ST_TOTAL  2054

__device__ __forceinline__ float bf2f(unsigned short u){
  return __uint_as_float(((unsigned int)u) << 16);
}
__device__ __forceinline__ unsigned short f2bf(float f){
  unsigned int x = __float_as_uint(f);
  x = x + 0x7FFFu + ((x >> 16) & 1u);
  return (unsigned short)(x >> 16);
}

// ---------------- init: x -> xcur (f32) + xb (bf16), vectorized ----------------
__global__ void init_x(const float* __restrict__ x, float* __restrict__ xcur,
                       unsigned short* __restrict__ xb){
  const int tot = NN*DD/4;
  int stride = gridDim.x * blockDim.x;
  for (int i = blockIdx.x*blockDim.x + threadIdx.x; i < tot; i += stride){
    f32x4 v = ((const f32x4*)x)[i];
    ((f32x4*)xcur)[i] = v;
    u16x4 o; o[0]=f2bf(v[0]); o[1]=f2bf(v[1]); o[2]=f2bf(v[2]); o[3]=f2bf(v[3]);
    ((u16x4*)xb)[i] = o;
  }
}

// --------- weight prep: Wjcat[j][s*128+o][c] = Wj[o][s*128+c]  (bf16) ---------
__global__ void wprep(const float* __restrict__ WT, const float* __restrict__ WM,
                      const float* __restrict__ WB, const float* __restrict__ Wtw,
                      unsigned short* __restrict__ Wjcat, unsigned short* __restrict__ Wtwb){
  int stride = gridDim.x * blockDim.x;
  int tid = blockIdx.x*blockDim.x + threadIdx.x;
  for (int i = tid; i < 3*D3*DD; i += stride){
    int j = i / (D3*DD);
    int rem = i - j*(D3*DD);
    int scol = rem >> 7;      // output col 0..383
    int c = rem & 127;        // input col
    int s = scol >> 7;        // slot
    int o = scol & 127;       // output feature within slot
    const float* Wj = (j==0) ? WT : ((j==1) ? WM : WB);
    Wjcat[i] = f2bf(Wj[o*D3 + s*128 + c]);
  }
  for (int i = tid; i < 128*128; i += stride) Wtwb[i] = f2bf(Wtw[i]);
}

// ---------------- CSR build ----------------
__global__ void csr_cnt(const int* __restrict__ twi, int* __restrict__ cnt){
  int e = blockIdx.x*blockDim.x + threadIdx.x;
  if (e < NE){
    atomicAdd(&cnt[0*NN + twi[0*NE + e]], 1);
    atomicAdd(&cnt[1*NN + twi[1*NE + e]], 1);
    atomicAdd(&cnt[2*NN + twi[2*NE + e]], 1);
  }
}

__global__ void scan_bs(const int* __restrict__ cnt, int* __restrict__ bsums){
  const int p = blockIdx.y, b = blockIdx.x, t = threadIdx.x;
  const int base = b * 1024;
  int s = 0;
  #pragma unroll
  for (int j = 0; j < 4; j++){
    int i = base + t + j*256;
    if (i < NN) s += cnt[p*NN + i];
  }
  __shared__ int red[256];
  red[t] = s; __syncthreads();
  #pragma unroll
  for (int o = 128; o; o >>= 1){
    if (t < o) red[t] += red[t+o];
    __syncthreads();
  }
  if (t == 0) bsums[p*SCB + b] = red[0];
}

__global__ void scan_top(int* __restrict__ bsums){
  const int p = threadIdx.x;
  if (p < 3){
    int run = 0;
    for (int i = 0; i < SCB; i++){ int v = bsums[p*SCB + i]; bsums[p*SCB + i] = run; run += v; }
  }
}

__global__ void scan_fin(const int* __restrict__ cnt, const int* __restrict__ bsums,
                         int* __restrict__ start){
  const int p = blockIdx.y, b = blockIdx.x, t = threadIdx.x;
  const int base = b * 1024;
  int v[4]; int s = 0;
  #pragma unroll
  for (int j = 0; j < 4; j++){
    int i = base + t*4 + j;
    v[j] = (i < NN) ? cnt[p*NN + i] : 0;
    s += v[j];
  }
  __shared__ int red[256];
  red[t] = s; __syncthreads();
  #pragma unroll
  for (int o = 1; o < 256; o <<= 1){
    int other = (t >= o) ? red[t - o] : 0;
    __syncthreads();
    red[t] += other;
    __syncthreads();
  }
  int ex = red[t] - s + bsums[p*SCB + b];
  #pragma unroll
  for (int j = 0; j < 4; j++){
    int i = base + t*4 + j;
    if (i < NN) start[p*NN + i] = ex;
    ex += v[j];
  }
}

// einfo[p][slot] = {e, n_{(p+1)%3}, n_{(p+2)%3}, n_p}
__global__ void csr_fill(const int* __restrict__ twi, const int* __restrict__ start,
                         int* __restrict__ cursor, int4* __restrict__ einfo){
  int e = blockIdx.x*blockDim.x + threadIdx.x;
  if (e < NE){
    int nd0 = twi[e], nd1 = twi[NE+e], nd2 = twi[2*NE+e];
    int nd[3] = {nd0, nd1, nd2};
    #pragma unroll
    for (int p = 0; p < 3; p++){
      int n = nd[p];
      int pos = atomicAdd(&cursor[p*NN + n], 1);
      int4 v;
      v.x = e; v.y = nd[(p+1)%3]; v.z = nd[(p+2)%3]; v.w = n;
      einfo[(size_t)p*NE + start[p*NN + n] + pos] = v;
    }
  }
}

// ---------------- node scores: S[s][n] = x[n] . w1[s*128: s*128+128] ----------------
__global__ void nscore(const unsigned short* __restrict__ xb,
                       const float* __restrict__ W1, float* __restrict__ S){
  __shared__ float w1s[384];
  const int t = threadIdx.x;
  for (int i = t; i < 384; i += 256) w1s[i] = W1[i];
  __syncthreads();
  const int n = blockIdx.x*256 + t;
  if (n >= NN) return;
  float s0 = 0.f, s1 = 0.f, s2 = 0.f;
  for (int k = 0; k < 128; k += 8){
    s16x8 v = *(const s16x8*)(xb + (size_t)n*DD + k);
    #pragma unroll
    for (int u = 0; u < 8; u++){
      float xv = bf2f((unsigned short)v[u]);
      s0 += xv * w1s[k+u];
      s1 += xv * w1s[128+k+u];
      s2 += xv * w1s[256+k+u];
    }
  }
  S[n] = s0; S[NN+n] = s1; S[2*NN+n] = s2;
}

// ------- edge scores: sp[e] = S0[i0]+S1[i1]+S2[i2]; block-reduced sum/sumsq -------
__global__ void escore(const int* __restrict__ twi, const float* __restrict__ S,
                       float* __restrict__ sp, float* __restrict__ stats){
  float lsum = 0.f, lsq = 0.f;
  const int stride = gridDim.x*blockDim.x;
  for (int e = blockIdx.x*blockDim.x + threadIdx.x; e < NE; e += stride){
    float s = S[twi[e]] + S[NN + twi[NE+e]] + S[2*NN + twi[2*NE+e]];
    sp[e] = s;
    lsum += s; lsq += s*s;
  }
  #pragma unroll
  for (int o = 32; o; o >>= 1){ lsum += __shfl_xor(lsum, o); lsq += __shfl_xor(lsq, o); }
  __shared__ float rs[4], rq[4];
  if ((threadIdx.x & 63) == 0){ rs[threadIdx.x >> 6] = lsum; rq[threadIdx.x >> 6] = lsq; }
  __syncthreads();
  if (threadIdx.x == 0){
    atomicAdd(&stats[ST_SUM1], rs[0]+rs[1]+rs[2]+rs[3]);
    atomicAdd(&stats[ST_SQ1],  rq[0]+rq[1]+rq[2]+rq[3]);
  }
}

// ------ dense node GEMM: Y[n, 0:384] = xb[n] @ Wjcat_j^T, coalesced LDS-repack ------
__launch_bounds__(256)
__global__ void ngemm(const unsigned short* __restrict__ xb,
                      const unsigned short* __restrict__ Wj,   // pre-offset to part j
                      unsigned short* __restrict__ Y){
  __shared__ unsigned short ltu[4][16][128];   // 16 KB wave-local repack
  const int t = threadIdx.x;
  const int w = t >> 6, lane = t & 63;
  const int lc = lane & 15, kg = lane >> 4;
  const int m0 = blockIdx.x*64 + w*16;
  const int arow = m0 + lc;
  f32x4 acc[24];
  #pragma unroll
  for (int nf = 0; nf < 24; nf++){ acc[nf][0]=0.f; acc[nf][1]=0.f; acc[nf][2]=0.f; acc[nf][3]=0.f; }
  #pragma unroll
  for (int ks = 0; ks < 4; ks++){
    s16x8 a;
    if (arow < NN) a = *(const s16x8*)(xb + (size_t)arow*DD + ks*32 + kg*8);
    else { a[0]=0;a[1]=0;a[2]=0;a[3]=0;a[4]=0;a[5]=0;a[6]=0;a[7]=0; }
    #pragma unroll
    for (int nf = 0; nf < 24; nf++){
      s16x8 b = *(const s16x8*)(Wj + (nf*16 + lc)*DD + ks*32 + kg*8);
      acc[nf] = __builtin_amdgcn_mfma_f32_16x16x32_bf16(a, b, acc[nf], 0, 0, 0);
    }
  }
  // 3 chunks of 128 cols: wave-local u16 repack -> coalesced u16x4 stores
  const int rl = lane >> 5, cg = lane & 31;
  #pragma unroll
  for (int ch = 0; ch < 3; ch++){
    #pragma unroll
    for (int f = 0; f < 8; f++){
      const int nf = ch*8 + f;
      #pragma unroll
      for (int r = 0; r < 4; r++)
        ltu[w][kg*4 + r][f*16 + lc] = f2bf(acc[nf][r]);
    }
    #pragma unroll
    for (int it = 0; it < 8; it++){
      const int row = it*2 + rl;
      const int grow = m0 + row;
      if (grow < NN){
        u16x4 o = *(const u16x4*)&ltu[w][row][cg*4];
        *(u16x4*)(Y + (size_t)grow*D3 + ch*128 + cg*4) = o;
      }
    }
  }
}

// ----- edge stats for part j (node-centric CSR walk, 2 edges/wave-iter) -----
__launch_bounds__(256)
__global__ void estat(const unsigned short* __restrict__ Y,
                      const int4* __restrict__ einfo,
                      const int* __restrict__ cnt, const int* __restrict__ start,
                      float* __restrict__ stats, int j, int a, int b){
  __shared__ float bs[4][128], bq[4][128];
  const int t = threadIdx.x, w = t >> 6, lane = t & 63;
  const int half = lane >> 5, hl = lane & 31;
  const int c0 = hl*4;
  float s0=0,s1=0,s2=0,s3=0, q0=0,q1=0,q2=0,q3=0;
  const int gw = blockIdx.x*4 + w;
  const int nw = gridDim.x*4;
  for (int n = gw; n < NN; n += nw){
    const int c = cnt[j*NN + n];
    if (c == 0) continue;
    const int cs = start[j*NN + n];
    u16x4 lv = *(const u16x4*)(Y + (size_t)n*D3 + j*128 + c0);
    const float l0 = bf2f(lv[0]), l1 = bf2f(lv[1]), l2 = bf2f(lv[2]), l3 = bf2f(lv[3]);
    for (int k = 0; k < c; k += 2){
      const int kk = k + half;
      const bool valid = kk < c;
      const int4 ei = einfo[(size_t)j*NE + cs + (valid ? kk : c-1)];
      u16x4 ga = *(const u16x4*)(Y + (size_t)ei.y*D3 + a*128 + c0);
      u16x4 gb = *(const u16x4*)(Y + (size_t)ei.z*D3 + b*128 + c0);
      if (valid){
        float h0 = l0 + bf2f(ga[0]) + bf2f(gb[0]);
        float h1 = l1 + bf2f(ga[1]) + bf2f(gb[1]);
        float h2 = l2 + bf2f(ga[2]) + bf2f(gb[2]);
        float h3 = l3 + bf2f(ga[3]) + bf2f(gb[3]);
        s0 += h0; s1 += h1; s2 += h2; s3 += h3;
        q0 += h0*h0; q1 += h1*h1; q2 += h2*h2; q3 += h3*h3;
      }
    }
  }
  s0 += __shfl_xor(s0, 32); s1 += __shfl_xor(s1, 32);
  s2 += __shfl_xor(s2, 32); s3 += __shfl_xor(s3, 32);
  q0 += __shfl_xor(q0, 32); q1 += __shfl_xor(q1, 32);
  q2 += __shfl_xor(q2, 32); q3 += __shfl_xor(q3, 32);
  if (half == 0){
    bs[w][c0] = s0; bs[w][c0+1] = s1; bs[w][c0+2] = s2; bs[w][c0+3] = s3;
    bq[w][c0] = q0; bq[w][c0+1] = q1; bq[w][c0+2] = q2; bq[w][c0+3] = q3;
  }
  __syncthreads();
  if (t < 128){
    atomicAdd(&stats[ST_SUM + j*128 + t], bs[0][t]+bs[1][t]+bs[2][t]+bs[3][t]);
    atomicAdd(&stats[ST_SQ  + j*128 + t], bq[0][t]+bq[1][t]+bq[2][t]+bq[3][t]);
  }
}

// -- node-centric scatter for part j (2 edges/wave-iter): macc[n] += mean --
__launch_bounds__(256)
__global__ void escat(const unsigned short* __restrict__ Y,
                      const int4* __restrict__ einfo,
                      const float* __restrict__ att,
                      const int* __restrict__ cnt, const int* __restrict__ start,
                      const float* __restrict__ stats,
                      float* __restrict__ macc, int j, int a, int b){
  const int w = threadIdx.x >> 6, lane = threadIdx.x & 63;
  const int half = lane >> 5, hl = lane & 31;
  const int n = blockIdx.x*4 + w;
  if (n >= NN) return;
  const int c = cnt[j*NN + n];
  if (c == 0) return;
  const float invZ = 1.0f / stats[ST_SEXP];
  const int cs = start[j*NN + n];
  const int c0 = hl*4;
  u16x4 lv = *(const u16x4*)(Y + (size_t)n*D3 + j*128 + c0);
  const float l0 = bf2f(lv[0]), l1 = bf2f(lv[1]), l2 = bf2f(lv[2]), l3 = bf2f(lv[3]);
  f32x4 sc = *(const f32x4*)(stats + ST_SCALE + j*128 + c0);
  f32x4 sh = *(const f32x4*)(stats + ST_SHIFT + j*128 + c0);
  float a0=0,a1=0,a2=0,a3=0;
  for (int k = 0; k < c; k += 2){
    const int kk = k + half;
    const bool valid = kk < c;
    const int4 ei = einfo[(size_t)j*NE + cs + (valid ? kk : c-1)];
    const float av = valid ? att[ei.x] * invZ : 0.f;
    u16x4 ga = *(const u16x4*)(Y + (size_t)ei.y*D3 + a*128 + c0);
    u16x4 gb = *(const u16x4*)(Y + (size_t)ei.z*D3 + b*128 + c0);
    float h0 = l0 + bf2f(ga[0]) + bf2f(gb[0]);
    float h1 = l1 + bf2f(ga[1]) + bf2f(gb[1]);
    float h2 = l2 + bf2f(ga[2]) + bf2f(gb[2]);
    float h3 = l3 + bf2f(ga[3]) + bf2f(gb[3]);
    a0 += av * fmaxf(h0*sc[0] + sh[0], 0.f);
    a1 += av * fmaxf(h1*sc[1] + sh[1], 0.f);
    a2 += av * fmaxf(h2*sc[2] + sh[2], 0.f);
    a3 += av * fmaxf(h3*sc[3] + sh[3], 0.f);
  }
  a0 += __shfl_xor(a0, 32); a1 += __shfl_xor(a1, 32);
  a2 += __shfl_xor(a2, 32); a3 += __shfl_xor(a3, 32);
  if (half == 0){
    const float ic = 1.f / (float)c;
    f32x4* mp = (f32x4*)(macc + (size_t)n*DD + c0);
    f32x4 old = *mp;
    old[0] += a0*ic; old[1] += a1*ic; old[2] += a2*ic; old[3] += a3*ic;
    *mp = old;
  }
}

// ---------------- BN finalize ----------------
__global__ void sfin_score(const float* g1, const float* be1, float* __restrict__ stats){
  if (threadIdx.x == 0){
    float mu = stats[ST_SUM1] / (float)NE;
    float var = stats[ST_SQ1] / (float)NE - mu*mu;
    float sc = g1[0] * rsqrtf(var + EPSBN);
    stats[ST_SCALE1] = sc;
    stats[ST_SHIFT1] = be1[0] - mu*sc;
  }
}

__global__ void sfin_cols(const float* g, const float* be, float* __restrict__ stats, int part){
  int t = threadIdx.x;
  if (t < 128){
    int idx = part*128 + t;
    float mu = stats[ST_SUM + idx] / (float)NE;
    float var = stats[ST_SQ + idx] / (float)NE - mu*mu;
    float sc = g[t] * rsqrtf(var + EPSBN);
    stats[ST_SCALE + idx] = sc;
    stats[ST_SHIFT + idx] = be[t] - mu*sc;
  }
}

// ---------------- softmax: max, then sum (stores exp in place) ----------------
__global__ void sm_max(float* __restrict__ sp, float* __restrict__ stats){
  const float sc = stats[ST_SCALE1], sh = stats[ST_SHIFT1];
  float lmax = 0.f;
  int stride = gridDim.x*blockDim.x;
  for (int i = blockIdx.x*blockDim.x + threadIdx.x; i < NE; i += stride){
    float s = fmaxf(sp[i]*sc + sh, 0.f);
    sp[i] = s;
    lmax = fmaxf(lmax, s);
  }
  #pragma unroll
  for (int o = 32; o; o >>= 1) lmax = fmaxf(lmax, __shfl_xor(lmax, o));
  __shared__ float red[4];
  if ((threadIdx.x & 63) == 0) red[threadIdx.x >> 6] = lmax;
  __syncthreads();
  if (threadIdx.x == 0){
    float m = fmaxf(fmaxf(red[0], red[1]), fmaxf(red[2], red[3]));
    atomicMax((unsigned int*)&stats[ST_MAX], __float_as_uint(m));
  }
}

__global__ void sm_sum(float* __restrict__ sp, float* __restrict__ stats){
  const float mx = __uint_as_float(((const unsigned int*)stats)[ST_MAX]);
  float ls = 0.f;
  int stride = gridDim.x*blockDim.x;
  for (int i = blockIdx.x*blockDim.x + threadIdx.x; i < NE; i += stride){
    float ex = __expf(sp[i] - mx);
    sp[i] = ex;
    ls += ex;
  }
  #pragma unroll
  for (int o = 32; o; o >>= 1) ls += __shfl_xor(ls, o);
  __shared__ float red[4];
  if ((threadIdx.x & 63) == 0) red[threadIdx.x >> 6] = ls;
  __syncthreads();
  if (threadIdx.x == 0)
    atomicAdd(&stats[ST_SEXP], red[0] + red[1] + red[2] + red[3]);
}

// ------- zb = bf16(macc @ Wtw^T), fused col stats, coalesced LDS-repack -------
__launch_bounds__(256)
__global__ void g2_gemm(const float* __restrict__ A,
                        const unsigned short* __restrict__ Wtwb,
                        unsigned short* __restrict__ zb,
                        float* __restrict__ stats){
  __shared__ unsigned short ltu[4][16][128];   // 16 KB wave-local repack
  __shared__ float ssum[128], ssq[128];
  const int t = threadIdx.x;
  const int w = t >> 6, lane = t & 63;
  const int lc = lane & 15, kg = lane >> 4;
  if (t < 128){ ssum[t] = 0.f; ssq[t] = 0.f; }
  const int m0 = blockIdx.x*64 + w*16;
  const int arow = m0 + lc;
  f32x4 acc[8];
  #pragma unroll
  for (int nf = 0; nf < 8; nf++){ acc[nf][0]=0.f; acc[nf][1]=0.f; acc[nf][2]=0.f; acc[nf][3]=0.f; }
  #pragma unroll
  for (int ks = 0; ks < 128; ks += 32){
    s16x8 a;
    if (arow < NN){
      f32x4 a0 = *(const f32x4*)(A + (size_t)arow*DD + ks + kg*8);
      f32x4 a1 = *(const f32x4*)(A + (size_t)arow*DD + ks + kg*8 + 4);
      a[0]=(short)f2bf(a0[0]); a[1]=(short)f2bf(a0[1]); a[2]=(short)f2bf(a0[2]); a[3]=(short)f2bf(a0[3]);
      a[4]=(short)f2bf(a1[0]); a[5]=(short)f2bf(a1[1]); a[6]=(short)f2bf(a1[2]); a[7]=(short)f2bf(a1[3]);
    } else {
      a[0]=0;a[1]=0;a[2]=0;a[3]=0;a[4]=0;a[5]=0;a[6]=0;a[7]=0;
    }
    #pragma unroll
    for (int nf = 0; nf < 8; nf++){
      s16x8 b = *(const s16x8*)(Wtwb + (nf*16 + lc)*DD + ks + kg*8);
      acc[nf] = __builtin_amdgcn_mfma_f32_16x16x32_bf16(a, b, acc[nf], 0, 0, 0);
    }
  }
  // stats from acc (f32 exact)
  float ps[8], pq[8];
  #pragma unroll
  for (int nf = 0; nf < 8; nf++){
    ps[nf] = 0.f; pq[nf] = 0.f;
    #pragma unroll
    for (int r = 0; r < 4; r++){
      int row = m0 + kg*4 + r;
      if (row < NN){
        float v = acc[nf][r];
        ps[nf] += v; pq[nf] += v*v;
      }
    }
  }
  __syncthreads();
  #pragma unroll
  for (int nf = 0; nf < 8; nf++){
    atomicAdd(&ssum[nf*16 + lc], ps[nf]);
    atomicAdd(&ssq [nf*16 + lc], pq[nf]);
  }
  // coalesced store path: wave-local u16 repack -> u16x4 stores
  #pragma unroll
  for (int nf = 0; nf < 8; nf++)
    #pragma unroll
    for (int r = 0; r < 4; r++)
      ltu[w][kg*4 + r][nf*16 + lc] = f2bf(acc[nf][r]);
  const int rl = lane >> 5, cg = lane & 31;
  #pragma unroll
  for (int it = 0; it < 8; it++){
    const int row = it*2 + rl;
    const int grow = m0 + row;
    if (grow < NN){
      u16x4 o = *(const u16x4*)&ltu[w][row][cg*4];
      *(u16x4*)(zb + (size_t)grow*DD + cg*4) = o;
    }
  }
  __syncthreads();
  if (t < 128){
    atomicAdd(&stats[ST_SUM2 + t], ssum[t]);
    atomicAdd(&stats[ST_SQ2  + t], ssq[t]);
  }
}

__global__ void sfin2(const float* gtw, const float* betw, float* __restrict__ stats){
  int c = threadIdx.x;
  if (c < 128){
    float mu = stats[ST_SUM2 + c] / (float)NN;
    float var = stats[ST_SQ2 + c] / (float)NN - mu*mu;
    float sc = gtw[c] * rsqrtf(var + EPSBN);
    stats[ST_SCALE2 + c] = sc;
    stats[ST_SHIFT2 + c] = betw[c] - mu*sc;
  }
}

// ---------------- x += relu(BN(zb)); refresh bf16 copy (vectorized) ----------------
__global__ void fuse_update(const unsigned short* __restrict__ zb,
                            const float* __restrict__ stats,
                            float* __restrict__ xcur, unsigned short* __restrict__ xb){
  const int tot = NN*DD/4;
  int stride = gridDim.x*blockDim.x;
  for (int i = blockIdx.x*blockDim.x + threadIdx.x; i < tot; i += stride){
    u16x4 z4 = ((const u16x4*)zb)[i];
    f32x4 x4 = ((const f32x4*)xcur)[i];
    const int c = (i*4) & 127;
    f32x4 o; u16x4 ob;
    #pragma unroll
    for (int j = 0; j < 4; j++){
      float hv = fmaxf(bf2f(z4[j])*stats[ST_SCALE2 + c + j] + stats[ST_SHIFT2 + c + j], 0.f);
      o[j] = x4[j] + hv;
      ob[j] = f2bf(o[j]);
    }
    ((f32x4*)xcur)[i] = o;
    ((u16x4*)xb)[i] = ob;
  }
}

extern "C" void kernel_launch(void* const* d_in, const int* in_sizes, int n_in,
                              void* d_out, int out_size, void* d_ws, size_t ws_size,
                              hipStream_t stream){
  const float* x    = (const float*)d_in[0];
  const int*   twi  = (const int*)d_in[1];
  const float* W_T  = (const float*)d_in[2];
  const float* W_M  = (const float*)d_in[3];
  const float* W_B  = (const float*)d_in[4];
  const float* W_1  = (const float*)d_in[5];
  const float* W_tw = (const float*)d_in[6];
  const float* g_T  = (const float*)d_in[8];
  const float* be_T = (const float*)d_in[9];
  const float* g_M  = (const float*)d_in[11];
  const float* be_M = (const float*)d_in[12];
  const float* g_B  = (const float*)d_in[14];
  const float* be_B = (const float*)d_in[15];
  const float* g_1  = (const float*)d_in[17];
  const float* be_1 = (const float*)d_in[18];
  const float* g_tw = (const float*)d_in[20];
  const float* be_tw= (const float*)d_in[21];
  float* xcur = (float*)d_out;

  char* ws = (char*)d_ws;
  size_t off = 0;
  auto take = [&](size_t b){ size_t o = off; off += (b + 255) & ~(size_t)255; return o; };
  float* stats = (float*)(ws + take(ST_TOTAL*4));
  unsigned short* Wjcat = (unsigned short*)(ws + take((size_t)3*D3*DD*2));
  unsigned short* Wtwb  = (unsigned short*)(ws + take(128*128*2));
  int* bsums  = (int*)(ws + take((size_t)3*SCB*4));
  int* cnt    = (int*)(ws + take((size_t)3*NN*4));
  int* startA = (int*)(ws + take((size_t)3*NN*4));
  int* cursor = (int*)(ws + take((size_t)3*NN*4));
  int4* einfo = (int4*)(ws + take((size_t)3*NE*16));
  float* sp   = (float*)(ws + take((size_t)NE*4));
  float* S    = (float*)(ws + take((size_t)3*NN*4));
  unsigned short* xb = (unsigned short*)(ws + take((size_t)NN*DD*2));
  float* macc = (float*)(ws + take((size_t)NN*DD*4));
  unsigned short* Y = (unsigned short*)(ws + take((size_t)NN*D3*2));
  unsigned short* zb = Y;   // alias: zb written by g2 only after last escat consumed Y
  if (ws_size < off) return;  // avoid faulting

  hipMemsetAsync(cnt, 0, (size_t)3*NN*4, stream);
  hipMemsetAsync(cursor, 0, (size_t)3*NN*4, stream);
  init_x<<<1024, 256, 0, stream>>>(x, xcur, xb);
  csr_cnt<<<(NE+255)/256, 256, 0, stream>>>(twi, cnt);
  scan_bs<<<dim3(SCB, 3), 256, 0, stream>>>(cnt, bsums);
  scan_top<<<1, 64, 0, stream>>>(bsums);
  scan_fin<<<dim3(SCB, 3), 256, 0, stream>>>(cnt, bsums, startA);
  csr_fill<<<(NE+255)/256, 256, 0, stream>>>(twi, startA, cursor, einfo);

  const int NGB = (NN + 63)/64;     // ngemm/g2 blocks
  const int NDB = (NN + 3)/4;       // node-wave blocks

  for (int l = 0; l < KL; l++){
    hipMemsetAsync(stats, 0, ST_TOTAL*4, stream);
    hipMemsetAsync(macc, 0, (size_t)NN*DD*4, stream);
    wprep<<<640, 256, 0, stream>>>(W_T + (size_t)l*DD*D3, W_M + (size_t)l*DD*D3,
                                   W_B + (size_t)l*DD*D3, W_tw + (size_t)l*DD*DD,
                                   Wjcat, Wtwb);
    const float* gs[3]  = {g_T  + (size_t)l*DD, g_M  + (size_t)l*DD, g_B  + (size_t)l*DD};
    const float* bes[3] = {be_T + (size_t)l*DD, be_M + (size_t)l*DD, be_B + (size_t)l*DD};

    // score path (node-decomposed)
    nscore<<<(NN+255)/256, 256, 0, stream>>>(xb, W_1 + (size_t)l*D3, S);
    escore<<<256, 256, 0, stream>>>(twi, S, sp, stats);
    sfin_score<<<1, 64, 0, stream>>>(g_1 + l, be_1 + l, stats);
    sm_max<<<256, 256, 0, stream>>>(sp, stats);
    sm_sum<<<256, 256, 0, stream>>>(sp, stats);

    // per-part: dense node GEMM -> edge stats -> BN finalize -> node scatter
    for (int j = 0; j < 3; j++){
      ngemm<<<NGB, 256, 0, stream>>>(xb, Wjcat + (size_t)j*D3*DD, Y);
      estat<<<1024, 256, 0, stream>>>(Y, einfo, cnt, startA, stats, j, (j+1)%3, (j+2)%3);
      sfin_cols<<<1, 128, 0, stream>>>(gs[j], bes[j], stats, j);
      escat<<<NDB, 256, 0, stream>>>(Y, einfo, sp, cnt, startA, stats, macc,
                                     j, (j+1)%3, (j+2)%3);
    }

    g2_gemm<<<NGB, 256, 0, stream>>>(macc, Wtwb, zb, stats);
    sfin2<<<1, 128, 0, stream>>>(g_tw + (size_t)l*DD, be_tw + (size_t)l*DD, stats);
    fuse_update<<<1024, 256, 0, stream>>>(zb, stats, xcur, xb);
  }
}

// Round 16
// 1589.026 us; speedup vs baseline: 2.4682x; 1.2272x over previous
//
#include <hip/hip_runtime.h>

#define NN 100000
#define NE 400000
#define DD 128
#define D3 384
#define KL 2
#define EPSBN 1e-5f
#define SCB ((NN + 1023) / 1024)
#define BPAD 132   // padded u16 row stride for LDS B panel

typedef __attribute__((ext_vector_type(8))) short s16x8;
typedef __attribute__((ext_vector_type(4))) float f32x4;
typedef __attribute__((ext_vector_type(4))) unsigned short u16x4;
typedef __attribute__((ext_vector_type(2))) unsigned short u16x2;

#define ST_SUM    0      // [384]
#define ST_SQ     384    // [384]
#define ST_SCALE  768    // [384]
#define ST_SHIFT  1152   // [384]
#define ST_SUM1   1536
#define ST_SQ1    1537
#define ST_MAX    1538
#define ST_SEXP   1539
#define ST_SCALE1 1540
#define ST_SHIFT1 1541
#define ST_SUM2   1542   // [128]
#define ST_SQ2    1670   // [128]
#define ST_SCALE2 1798   // [128]
#define ST_SHIFT2 1926   // [128]
#define ST_TOTAL  2054

__device__ __forceinline__ float bf2f(unsigned short u){
  return __uint_as_float(((unsigned int)u) << 16);
}
__device__ __forceinline__ unsigned short f2bf(float f){
  unsigned int x = __float_as_uint(f);
  x = x + 0x7FFFu + ((x >> 16) & 1u);
  return (unsigned short)(x >> 16);
}

// ---------------- init: x -> xcur (f32) + xb (bf16), vectorized ----------------
__global__ void init_x(const float* __restrict__ x, float* __restrict__ xcur,
                       unsigned short* __restrict__ xb){
  const int tot = NN*DD/4;
  int stride = gridDim.x * blockDim.x;
  for (int i = blockIdx.x*blockDim.x + threadIdx.x; i < tot; i += stride){
    f32x4 v = ((const f32x4*)x)[i];
    ((f32x4*)xcur)[i] = v;
    u16x4 o; o[0]=f2bf(v[0]); o[1]=f2bf(v[1]); o[2]=f2bf(v[2]); o[3]=f2bf(v[3]);
    ((u16x4*)xb)[i] = o;
  }
}

// --------- weight prep: Wjcat[j][s*128+o][c] = Wj[o][s*128+c]  (bf16) ---------
__global__ void wprep(const float* __restrict__ WT, const float* __restrict__ WM,
                      const float* __restrict__ WB, const float* __restrict__ Wtw,
                      unsigned short* __restrict__ Wjcat, unsigned short* __restrict__ Wtwb){
  int stride = gridDim.x * blockDim.x;
  int tid = blockIdx.x*blockDim.x + threadIdx.x;
  for (int i = tid; i < 3*D3*DD; i += stride){
    int j = i / (D3*DD);
    int rem = i - j*(D3*DD);
    int scol = rem >> 7;      // output col 0..383
    int c = rem & 127;        // input col
    int s = scol >> 7;        // slot
    int o = scol & 127;       // output feature within slot
    const float* Wj = (j==0) ? WT : ((j==1) ? WM : WB);
    Wjcat[i] = f2bf(Wj[o*D3 + s*128 + c]);
  }
  for (int i = tid; i < 128*128; i += stride) Wtwb[i] = f2bf(Wtw[i]);
}

// ---------------- CSR build ----------------
__global__ void csr_cnt(const int* __restrict__ twi, int* __restrict__ cnt){
  int e = blockIdx.x*blockDim.x + threadIdx.x;
  if (e < NE){
    atomicAdd(&cnt[0*NN + twi[0*NE + e]], 1);
    atomicAdd(&cnt[1*NN + twi[1*NE + e]], 1);
    atomicAdd(&cnt[2*NN + twi[2*NE + e]], 1);
  }
}

__global__ void scan_bs(const int* __restrict__ cnt, int* __restrict__ bsums){
  const int p = blockIdx.y, b = blockIdx.x, t = threadIdx.x;
  const int base = b * 1024;
  int s = 0;
  #pragma unroll
  for (int j = 0; j < 4; j++){
    int i = base + t + j*256;
    if (i < NN) s += cnt[p*NN + i];
  }
  __shared__ int red[256];
  red[t] = s; __syncthreads();
  #pragma unroll
  for (int o = 128; o; o >>= 1){
    if (t < o) red[t] += red[t+o];
    __syncthreads();
  }
  if (t == 0) bsums[p*SCB + b] = red[0];
}

__global__ void scan_top(int* __restrict__ bsums){
  const int p = threadIdx.x;
  if (p < 3){
    int run = 0;
    for (int i = 0; i < SCB; i++){ int v = bsums[p*SCB + i]; bsums[p*SCB + i] = run; run += v; }
  }
}

__global__ void scan_fin(const int* __restrict__ cnt, const int* __restrict__ bsums,
                         int* __restrict__ start){
  const int p = blockIdx.y, b = blockIdx.x, t = threadIdx.x;
  const int base = b * 1024;
  int v[4]; int s = 0;
  #pragma unroll
  for (int j = 0; j < 4; j++){
    int i = base + t*4 + j;
    v[j] = (i < NN) ? cnt[p*NN + i] : 0;
    s += v[j];
  }
  __shared__ int red[256];
  red[t] = s; __syncthreads();
  #pragma unroll
  for (int o = 1; o < 256; o <<= 1){
    int other = (t >= o) ? red[t - o] : 0;
    __syncthreads();
    red[t] += other;
    __syncthreads();
  }
  int ex = red[t] - s + bsums[p*SCB + b];
  #pragma unroll
  for (int j = 0; j < 4; j++){
    int i = base + t*4 + j;
    if (i < NN) start[p*NN + i] = ex;
    ex += v[j];
  }
}

// einfo[p][slot] = {e, n_{(p+1)%3}, n_{(p+2)%3}, n_p}
__global__ void csr_fill(const int* __restrict__ twi, const int* __restrict__ start,
                         int* __restrict__ cursor, int4* __restrict__ einfo){
  int e = blockIdx.x*blockDim.x + threadIdx.x;
  if (e < NE){
    int nd0 = twi[e], nd1 = twi[NE+e], nd2 = twi[2*NE+e];
    int nd[3] = {nd0, nd1, nd2};
    #pragma unroll
    for (int p = 0; p < 3; p++){
      int n = nd[p];
      int pos = atomicAdd(&cursor[p*NN + n], 1);
      int4 v;
      v.x = e; v.y = nd[(p+1)%3]; v.z = nd[(p+2)%3]; v.w = n;
      einfo[(size_t)p*NE + start[p*NN + n] + pos] = v;
    }
  }
}

// ---------------- node scores: S[s][n] = x[n] . w1[s*128: s*128+128] ----------------
__global__ void nscore(const unsigned short* __restrict__ xb,
                       const float* __restrict__ W1, float* __restrict__ S){
  __shared__ float w1s[384];
  const int t = threadIdx.x;
  for (int i = t; i < 384; i += 256) w1s[i] = W1[i];
  __syncthreads();
  const int n = blockIdx.x*256 + t;
  if (n >= NN) return;
  float s0 = 0.f, s1 = 0.f, s2 = 0.f;
  for (int k = 0; k < 128; k += 8){
    s16x8 v = *(const s16x8*)(xb + (size_t)n*DD + k);
    #pragma unroll
    for (int u = 0; u < 8; u++){
      float xv = bf2f((unsigned short)v[u]);
      s0 += xv * w1s[k+u];
      s1 += xv * w1s[128+k+u];
      s2 += xv * w1s[256+k+u];
    }
  }
  S[n] = s0; S[NN+n] = s1; S[2*NN+n] = s2;
}

// ------- edge scores: sp[e] = S0[i0]+S1[i1]+S2[i2]; block-reduced sum/sumsq -------
__global__ void escore(const int* __restrict__ twi, const float* __restrict__ S,
                       float* __restrict__ sp, float* __restrict__ stats){
  float lsum = 0.f, lsq = 0.f;
  const int stride = gridDim.x*blockDim.x;
  for (int e = blockIdx.x*blockDim.x + threadIdx.x; e < NE; e += stride){
    float s = S[twi[e]] + S[NN + twi[NE+e]] + S[2*NN + twi[2*NE+e]];
    sp[e] = s;
    lsum += s; lsq += s*s;
  }
  #pragma unroll
  for (int o = 32; o; o >>= 1){ lsum += __shfl_xor(lsum, o); lsq += __shfl_xor(lsq, o); }
  __shared__ float rs[4], rq[4];
  if ((threadIdx.x & 63) == 0){ rs[threadIdx.x >> 6] = lsum; rq[threadIdx.x >> 6] = lsq; }
  __syncthreads();
  if (threadIdx.x == 0){
    atomicAdd(&stats[ST_SUM1], rs[0]+rs[1]+rs[2]+rs[3]);
    atomicAdd(&stats[ST_SQ1],  rq[0]+rq[1]+rq[2]+rq[3]);
  }
}

// --- dense node GEMM, col-tiled: Y[n, ch*128:+128] = xb[n] @ Wj_ch^T, B in LDS ---
__launch_bounds__(256)
__global__ void ngemm(const unsigned short* __restrict__ xb,
                      const unsigned short* __restrict__ Wj,   // pre-offset to part j
                      unsigned short* __restrict__ Y){
  __shared__ unsigned short bsh[128*BPAD];   // 33 KB: B panel, reused as repack buf
  const int t = threadIdx.x;
  const int w = t >> 6, lane = t & 63;
  const int lc = lane & 15, kg = lane >> 4;
  const int ch = blockIdx.y;                 // 128-col chunk of the 384 outputs
  const int m0 = blockIdx.x*64 + w*16;
  const int arow = m0 + lc;

  // stage B panel: rows = output cols ch*128..+127, each 128 k (256B), padded stride
  for (int i = t; i < 128*16; i += 256){
    const int r = i >> 4, cc = (i & 15) * 8;
    *(s16x8*)(bsh + r*BPAD + cc) = *(const s16x8*)(Wj + (size_t)(ch*128 + r)*DD + cc);
  }
  __syncthreads();

  f32x4 acc[8];
  #pragma unroll
  for (int nf = 0; nf < 8; nf++){ acc[nf][0]=0.f; acc[nf][1]=0.f; acc[nf][2]=0.f; acc[nf][3]=0.f; }
  #pragma unroll
  for (int ks = 0; ks < 4; ks++){
    s16x8 a;
    if (arow < NN) a = *(const s16x8*)(xb + (size_t)arow*DD + ks*32 + kg*8);
    else { a[0]=0;a[1]=0;a[2]=0;a[3]=0;a[4]=0;a[5]=0;a[6]=0;a[7]=0; }
    #pragma unroll
    for (int nf = 0; nf < 8; nf++){
      s16x8 b = *(const s16x8*)(bsh + (nf*16 + lc)*BPAD + ks*32 + kg*8);
      acc[nf] = __builtin_amdgcn_mfma_f32_16x16x32_bf16(a, b, acc[nf], 0, 0, 0);
    }
  }
  __syncthreads();   // all waves done reading B panel; reuse bsh for repack

  unsigned short* ltu = bsh + w*16*BPAD;     // wave-local [16][BPAD]
  #pragma unroll
  for (int nf = 0; nf < 8; nf++)
    #pragma unroll
    for (int r = 0; r < 4; r++)
      ltu[(kg*4 + r)*BPAD + nf*16 + lc] = f2bf(acc[nf][r]);
  const int rl = lane >> 5, cg = lane & 31;
  #pragma unroll
  for (int it = 0; it < 8; it++){
    const int row = it*2 + rl;
    const int grow = m0 + row;
    if (grow < NN){
      u16x4 o = *(const u16x4*)&ltu[row*BPAD + cg*4];
      *(u16x4*)(Y + (size_t)grow*D3 + ch*128 + cg*4) = o;
    }
  }
}

// ----- edge stats for part j (node-centric CSR walk, 2 edges/wave-iter) -----
__launch_bounds__(256)
__global__ void estat(const unsigned short* __restrict__ Y,
                      const int4* __restrict__ einfo,
                      const int* __restrict__ cnt, const int* __restrict__ start,
                      float* __restrict__ stats, int j, int a, int b){
  __shared__ float bs[4][128], bq[4][128];
  const int t = threadIdx.x, w = t >> 6, lane = t & 63;
  const int half = lane >> 5, hl = lane & 31;
  const int c0 = hl*4;
  float s0=0,s1=0,s2=0,s3=0, q0=0,q1=0,q2=0,q3=0;
  const int gw = blockIdx.x*4 + w;
  const int nw = gridDim.x*4;
  for (int n = gw; n < NN; n += nw){
    const int c = cnt[j*NN + n];
    if (c == 0) continue;
    const int cs = start[j*NN + n];
    u16x4 lv = *(const u16x4*)(Y + (size_t)n*D3 + j*128 + c0);
    const float l0 = bf2f(lv[0]), l1 = bf2f(lv[1]), l2 = bf2f(lv[2]), l3 = bf2f(lv[3]);
    for (int k = 0; k < c; k += 2){
      const int kk = k + half;
      const bool valid = kk < c;
      const int4 ei = einfo[(size_t)j*NE + cs + (valid ? kk : c-1)];
      u16x4 ga = *(const u16x4*)(Y + (size_t)ei.y*D3 + a*128 + c0);
      u16x4 gb = *(const u16x4*)(Y + (size_t)ei.z*D3 + b*128 + c0);
      if (valid){
        float h0 = l0 + bf2f(ga[0]) + bf2f(gb[0]);
        float h1 = l1 + bf2f(ga[1]) + bf2f(gb[1]);
        float h2 = l2 + bf2f(ga[2]) + bf2f(gb[2]);
        float h3 = l3 + bf2f(ga[3]) + bf2f(gb[3]);
        s0 += h0; s1 += h1; s2 += h2; s3 += h3;
        q0 += h0*h0; q1 += h1*h1; q2 += h2*h2; q3 += h3*h3;
      }
    }
  }
  s0 += __shfl_xor(s0, 32); s1 += __shfl_xor(s1, 32);
  s2 += __shfl_xor(s2, 32); s3 += __shfl_xor(s3, 32);
  q0 += __shfl_xor(q0, 32); q1 += __shfl_xor(q1, 32);
  q2 += __shfl_xor(q2, 32); q3 += __shfl_xor(q3, 32);
  if (half == 0){
    bs[w][c0] = s0; bs[w][c0+1] = s1; bs[w][c0+2] = s2; bs[w][c0+3] = s3;
    bq[w][c0] = q0; bq[w][c0+1] = q1; bq[w][c0+2] = q2; bq[w][c0+3] = q3;
  }
  __syncthreads();
  if (t < 128){
    atomicAdd(&stats[ST_SUM + j*128 + t], bs[0][t]+bs[1][t]+bs[2][t]+bs[3][t]);
    atomicAdd(&stats[ST_SQ  + j*128 + t], bq[0][t]+bq[1][t]+bq[2][t]+bq[3][t]);
  }
}

// -- node-centric scatter for part j (2 edges/wave-iter): macc[n] += mean --
__launch_bounds__(256)
__global__ void escat(const unsigned short* __restrict__ Y,
                      const int4* __restrict__ einfo,
                      const float* __restrict__ att,
                      const int* __restrict__ cnt, const int* __restrict__ start,
                      const float* __restrict__ stats,
                      float* __restrict__ macc, int j, int a, int b){
  const int w = threadIdx.x >> 6, lane = threadIdx.x & 63;
  const int half = lane >> 5, hl = lane & 31;
  const int n = blockIdx.x*4 + w;
  if (n >= NN) return;
  const int c = cnt[j*NN + n];
  if (c == 0) return;
  const float invZ = 1.0f / stats[ST_SEXP];
  const int cs = start[j*NN + n];
  const int c0 = hl*4;
  u16x4 lv = *(const u16x4*)(Y + (size_t)n*D3 + j*128 + c0);
  const float l0 = bf2f(lv[0]), l1 = bf2f(lv[1]), l2 = bf2f(lv[2]), l3 = bf2f(lv[3]);
  f32x4 sc = *(const f32x4*)(stats + ST_SCALE + j*128 + c0);
  f32x4 sh = *(const f32x4*)(stats + ST_SHIFT + j*128 + c0);
  float a0=0,a1=0,a2=0,a3=0;
  for (int k = 0; k < c; k += 2){
    const int kk = k + half;
    const bool valid = kk < c;
    const int4 ei = einfo[(size_t)j*NE + cs + (valid ? kk : c-1)];
    const float av = valid ? att[ei.x] * invZ : 0.f;
    u16x4 ga = *(const u16x4*)(Y + (size_t)ei.y*D3 + a*128 + c0);
    u16x4 gb = *(const u16x4*)(Y + (size_t)ei.z*D3 + b*128 + c0);
    float h0 = l0 + bf2f(ga[0]) + bf2f(gb[0]);
    float h1 = l1 + bf2f(ga[1]) + bf2f(gb[1]);
    float h2 = l2 + bf2f(ga[2]) + bf2f(gb[2]);
    float h3 = l3 + bf2f(ga[3]) + bf2f(gb[3]);
    a0 += av * fmaxf(h0*sc[0] + sh[0], 0.f);
    a1 += av * fmaxf(h1*sc[1] + sh[1], 0.f);
    a2 += av * fmaxf(h2*sc[2] + sh[2], 0.f);
    a3 += av * fmaxf(h3*sc[3] + sh[3], 0.f);
  }
  a0 += __shfl_xor(a0, 32); a1 += __shfl_xor(a1, 32);
  a2 += __shfl_xor(a2, 32); a3 += __shfl_xor(a3, 32);
  if (half == 0){
    const float ic = 1.f / (float)c;
    f32x4* mp = (f32x4*)(macc + (size_t)n*DD + c0);
    f32x4 old = *mp;
    old[0] += a0*ic; old[1] += a1*ic; old[2] += a2*ic; old[3] += a3*ic;
    *mp = old;
  }
}

// ---------------- BN finalize ----------------
__global__ void sfin_score(const float* g1, const float* be1, float* __restrict__ stats){
  if (threadIdx.x == 0){
    float mu = stats[ST_SUM1] / (float)NE;
    float var = stats[ST_SQ1] / (float)NE - mu*mu;
    float sc = g1[0] * rsqrtf(var + EPSBN);
    stats[ST_SCALE1] = sc;
    stats[ST_SHIFT1] = be1[0] - mu*sc;
  }
}

__global__ void sfin_cols(const float* g, const float* be, float* __restrict__ stats, int part){
  int t = threadIdx.x;
  if (t < 128){
    int idx = part*128 + t;
    float mu = stats[ST_SUM + idx] / (float)NE;
    float var = stats[ST_SQ + idx] / (float)NE - mu*mu;
    float sc = g[t] * rsqrtf(var + EPSBN);
    stats[ST_SCALE + idx] = sc;
    stats[ST_SHIFT + idx] = be[t] - mu*sc;
  }
}

// ---------------- softmax: max, then sum (stores exp in place) ----------------
__global__ void sm_max(float* __restrict__ sp, float* __restrict__ stats){
  const float sc = stats[ST_SCALE1], sh = stats[ST_SHIFT1];
  float lmax = 0.f;
  int stride = gridDim.x*blockDim.x;
  for (int i = blockIdx.x*blockDim.x + threadIdx.x; i < NE; i += stride){
    float s = fmaxf(sp[i]*sc + sh, 0.f);
    sp[i] = s;
    lmax = fmaxf(lmax, s);
  }
  #pragma unroll
  for (int o = 32; o; o >>= 1) lmax = fmaxf(lmax, __shfl_xor(lmax, o));
  __shared__ float red[4];
  if ((threadIdx.x & 63) == 0) red[threadIdx.x >> 6] = lmax;
  __syncthreads();
  if (threadIdx.x == 0){
    float m = fmaxf(fmaxf(red[0], red[1]), fmaxf(red[2], red[3]));
    atomicMax((unsigned int*)&stats[ST_MAX], __float_as_uint(m));
  }
}

__global__ void sm_sum(float* __restrict__ sp, float* __restrict__ stats){
  const float mx = __uint_as_float(((const unsigned int*)stats)[ST_MAX]);
  float ls = 0.f;
  int stride = gridDim.x*blockDim.x;
  for (int i = blockIdx.x*blockDim.x + threadIdx.x; i < NE; i += stride){
    float ex = __expf(sp[i] - mx);
    sp[i] = ex;
    ls += ex;
  }
  #pragma unroll
  for (int o = 32; o; o >>= 1) ls += __shfl_xor(ls, o);
  __shared__ float red[4];
  if ((threadIdx.x & 63) == 0) red[threadIdx.x >> 6] = ls;
  __syncthreads();
  if (threadIdx.x == 0)
    atomicAdd(&stats[ST_SEXP], red[0] + red[1] + red[2] + red[3]);
}

// ------- zb = bf16(macc @ Wtw^T), fused col stats, coalesced LDS-repack -------
__launch_bounds__(256)
__global__ void g2_gemm(const float* __restrict__ A,
                        const unsigned short* __restrict__ Wtwb,
                        unsigned short* __restrict__ zb,
                        float* __restrict__ stats){
  __shared__ unsigned short ltu[4][16][128];   // 16 KB wave-local repack
  __shared__ float ssum[128], ssq[128];
  const int t = threadIdx.x;
  const int w = t >> 6, lane = t & 63;
  const int lc = lane & 15, kg = lane >> 4;
  if (t < 128){ ssum[t] = 0.f; ssq[t] = 0.f; }
  const int m0 = blockIdx.x*64 + w*16;
  const int arow = m0 + lc;
  f32x4 acc[8];
  #pragma unroll
  for (int nf = 0; nf < 8; nf++){ acc[nf][0]=0.f; acc[nf][1]=0.f; acc[nf][2]=0.f; acc[nf][3]=0.f; }
  #pragma unroll
  for (int ks = 0; ks < 128; ks += 32){
    s16x8 a;
    if (arow < NN){
      f32x4 a0 = *(const f32x4*)(A + (size_t)arow*DD + ks + kg*8);
      f32x4 a1 = *(const f32x4*)(A + (size_t)arow*DD + ks + kg*8 + 4);
      a[0]=(short)f2bf(a0[0]); a[1]=(short)f2bf(a0[1]); a[2]=(short)f2bf(a0[2]); a[3]=(short)f2bf(a0[3]);
      a[4]=(short)f2bf(a1[0]); a[5]=(short)f2bf(a1[1]); a[6]=(short)f2bf(a1[2]); a[7]=(short)f2bf(a1[3]);
    } else {
      a[0]=0;a[1]=0;a[2]=0;a[3]=0;a[4]=0;a[5]=0;a[6]=0;a[7]=0;
    }
    #pragma unroll
    for (int nf = 0; nf < 8; nf++){
      s16x8 b = *(const s16x8*)(Wtwb + (nf*16 + lc)*DD + ks + kg*8);
      acc[nf] = __builtin_amdgcn_mfma_f32_16x16x32_bf16(a, b, acc[nf], 0, 0, 0);
    }
  }
  // stats from acc (f32 exact)
  float ps[8], pq[8];
  #pragma unroll
  for (int nf = 0; nf < 8; nf++){
    ps[nf] = 0.f; pq[nf] = 0.f;
    #pragma unroll
    for (int r = 0; r < 4; r++){
      int row = m0 + kg*4 + r;
      if (row < NN){
        float v = acc[nf][r];
        ps[nf] += v; pq[nf] += v*v;
      }
    }
  }
  __syncthreads();
  #pragma unroll
  for (int nf = 0; nf < 8; nf++){
    atomicAdd(&ssum[nf*16 + lc], ps[nf]);
    atomicAdd(&ssq [nf*16 + lc], pq[nf]);
  }
  // coalesced store path: wave-local u16 repack -> u16x4 stores
  #pragma unroll
  for (int nf = 0; nf < 8; nf++)
    #pragma unroll
    for (int r = 0; r < 4; r++)
      ltu[w][kg*4 + r][nf*16 + lc] = f2bf(acc[nf][r]);
  const int rl = lane >> 5, cg = lane & 31;
  #pragma unroll
  for (int it = 0; it < 8; it++){
    const int row = it*2 + rl;
    const int grow = m0 + row;
    if (grow < NN){
      u16x4 o = *(const u16x4*)&ltu[w][row][cg*4];
      *(u16x4*)(zb + (size_t)grow*DD + cg*4) = o;
    }
  }
  __syncthreads();
  if (t < 128){
    atomicAdd(&stats[ST_SUM2 + t], ssum[t]);
    atomicAdd(&stats[ST_SQ2  + t], ssq[t]);
  }
}

__global__ void sfin2(const float* gtw, const float* betw, float* __restrict__ stats){
  int c = threadIdx.x;
  if (c < 128){
    float mu = stats[ST_SUM2 + c] / (float)NN;
    float var = stats[ST_SQ2 + c] / (float)NN - mu*mu;
    float sc = gtw[c] * rsqrtf(var + EPSBN);
    stats[ST_SCALE2 + c] = sc;
    stats[ST_SHIFT2 + c] = betw[c] - mu*sc;
  }
}

// ---------------- x += relu(BN(zb)); refresh bf16 copy (vectorized) ----------------
__global__ void fuse_update(const unsigned short* __restrict__ zb,
                            const float* __restrict__ stats,
                            float* __restrict__ xcur, unsigned short* __restrict__ xb){
  const int tot = NN*DD/4;
  int stride = gridDim.x*blockDim.x;
  for (int i = blockIdx.x*blockDim.x + threadIdx.x; i < tot; i += stride){
    u16x4 z4 = ((const u16x4*)zb)[i];
    f32x4 x4 = ((const f32x4*)xcur)[i];
    const int c = (i*4) & 127;
    f32x4 o; u16x4 ob;
    #pragma unroll
    for (int j = 0; j < 4; j++){
      float hv = fmaxf(bf2f(z4[j])*stats[ST_SCALE2 + c + j] + stats[ST_SHIFT2 + c + j], 0.f);
      o[j] = x4[j] + hv;
      ob[j] = f2bf(o[j]);
    }
    ((f32x4*)xcur)[i] = o;
    ((u16x4*)xb)[i] = ob;
  }
}

extern "C" void kernel_launch(void* const* d_in, const int* in_sizes, int n_in,
                              void* d_out, int out_size, void* d_ws, size_t ws_size,
                              hipStream_t stream){
  const float* x    = (const float*)d_in[0];
  const int*   twi  = (const int*)d_in[1];
  const float* W_T  = (const float*)d_in[2];
  const float* W_M  = (const float*)d_in[3];
  const float* W_B  = (const float*)d_in[4];
  const float* W_1  = (const float*)d_in[5];
  const float* W_tw = (const float*)d_in[6];
  const float* g_T  = (const float*)d_in[8];
  const float* be_T = (const float*)d_in[9];
  const float* g_M  = (const float*)d_in[11];
  const float* be_M = (const float*)d_in[12];
  const float* g_B  = (const float*)d_in[14];
  const float* be_B = (const float*)d_in[15];
  const float* g_1  = (const float*)d_in[17];
  const float* be_1 = (const float*)d_in[18];
  const float* g_tw = (const float*)d_in[20];
  const float* be_tw= (const float*)d_in[21];
  float* xcur = (float*)d_out;

  char* ws = (char*)d_ws;
  size_t off = 0;
  auto take = [&](size_t b){ size_t o = off; off += (b + 255) & ~(size_t)255; return o; };
  float* stats = (float*)(ws + take(ST_TOTAL*4));
  unsigned short* Wjcat = (unsigned short*)(ws + take((size_t)3*D3*DD*2));
  unsigned short* Wtwb  = (unsigned short*)(ws + take(128*128*2));
  int* bsums  = (int*)(ws + take((size_t)3*SCB*4));
  int* cnt    = (int*)(ws + take((size_t)3*NN*4));
  int* startA = (int*)(ws + take((size_t)3*NN*4));
  int* cursor = (int*)(ws + take((size_t)3*NN*4));
  int4* einfo = (int4*)(ws + take((size_t)3*NE*16));
  float* sp   = (float*)(ws + take((size_t)NE*4));
  float* S    = (float*)(ws + take((size_t)3*NN*4));
  unsigned short* xb = (unsigned short*)(ws + take((size_t)NN*DD*2));
  float* macc = (float*)(ws + take((size_t)NN*DD*4));
  unsigned short* Y = (unsigned short*)(ws + take((size_t)NN*D3*2));
  unsigned short* zb = Y;   // alias: zb written by g2 only after last escat consumed Y
  if (ws_size < off) return;  // avoid faulting

  hipMemsetAsync(cnt, 0, (size_t)3*NN*4, stream);
  hipMemsetAsync(cursor, 0, (size_t)3*NN*4, stream);
  init_x<<<1024, 256, 0, stream>>>(x, xcur, xb);
  csr_cnt<<<(NE+255)/256, 256, 0, stream>>>(twi, cnt);
  scan_bs<<<dim3(SCB, 3), 256, 0, stream>>>(cnt, bsums);
  scan_top<<<1, 64, 0, stream>>>(bsums);
  scan_fin<<<dim3(SCB, 3), 256, 0, stream>>>(cnt, bsums, startA);
  csr_fill<<<(NE+255)/256, 256, 0, stream>>>(twi, startA, cursor, einfo);

  const int NGB = (NN + 63)/64;     // ngemm/g2 blocks
  const int NDB = (NN + 3)/4;       // node-wave blocks

  for (int l = 0; l < KL; l++){
    hipMemsetAsync(stats, 0, ST_TOTAL*4, stream);
    hipMemsetAsync(macc, 0, (size_t)NN*DD*4, stream);
    wprep<<<640, 256, 0, stream>>>(W_T + (size_t)l*DD*D3, W_M + (size_t)l*DD*D3,
                                   W_B + (size_t)l*DD*D3, W_tw + (size_t)l*DD*DD,
                                   Wjcat, Wtwb);
    const float* gs[3]  = {g_T  + (size_t)l*DD, g_M  + (size_t)l*DD, g_B  + (size_t)l*DD};
    const float* bes[3] = {be_T + (size_t)l*DD, be_M + (size_t)l*DD, be_B + (size_t)l*DD};

    // score path (node-decomposed)
    nscore<<<(NN+255)/256, 256, 0, stream>>>(xb, W_1 + (size_t)l*D3, S);
    escore<<<256, 256, 0, stream>>>(twi, S, sp, stats);
    sfin_score<<<1, 64, 0, stream>>>(g_1 + l, be_1 + l, stats);
    sm_max<<<256, 256, 0, stream>>>(sp, stats);
    sm_sum<<<256, 256, 0, stream>>>(sp, stats);

    // per-part: dense node GEMM -> edge stats -> BN finalize -> node scatter
    for (int j = 0; j < 3; j++){
      ngemm<<<dim3(NGB, 3), 256, 0, stream>>>(xb, Wjcat + (size_t)j*D3*DD, Y);
      estat<<<1024, 256, 0, stream>>>(Y, einfo, cnt, startA, stats, j, (j+1)%3, (j+2)%3);
      sfin_cols<<<1, 128, 0, stream>>>(gs[j], bes[j], stats, j);
      escat<<<NDB, 256, 0, stream>>>(Y, einfo, sp, cnt, startA, stats, macc,
                                     j, (j+1)%3, (j+2)%3);
    }

    g2_gemm<<<NGB, 256, 0, stream>>>(macc, Wtwb, zb, stats);
    sfin2<<<1, 128, 0, stream>>>(g_tw + (size_t)l*DD, be_tw + (size_t)l*DD, stats);
    fuse_update<<<1024, 256, 0, stream>>>(zb, stats, xcur, xb);
  }
}

// Round 17
// 1554.219 us; speedup vs baseline: 2.5235x; 1.0224x over previous
//
#include <hip/hip_runtime.h>

#define NN 100000
#define NE 400000
#define DD 128
#define D3 384
#define KL 2
#define EPSBN 1e-5f
#define SCB ((NN + 1023) / 1024)
#define BPAD 132   // padded u16 row stride for LDS B panel

typedef __attribute__((ext_vector_type(8))) short s16x8;
typedef __attribute__((ext_vector_type(4))) float f32x4;
typedef __attribute__((ext_vector_type(4))) unsigned short u16x4;
typedef __attribute__((ext_vector_type(2))) unsigned short u16x2;

#define ST_SUM    0      // [384]
#define ST_SQ     384    // [384]
#define ST_SCALE  768    // [384]
#define ST_SHIFT  1152   // [384]
#define ST_SUM1   1536
#define ST_SQ1    1537
#define ST_MAX    1538
#define ST_SEXP   1539
#define ST_SCALE1 1540
#define ST_SHIFT1 1541
#define ST_SUM2   1542   // [128]
#define ST_SQ2    1670   // [128]
#define ST_SCALE2 1798   // [128]
#define ST_SHIFT2 1926   // [128]
#define ST_TOTAL  2054

__device__ __forceinline__ float bf2f(unsigned short u){
  return __uint_as_float(((unsigned int)u) << 16);
}
__device__ __forceinline__ unsigned short f2bf(float f){
  unsigned int x = __float_as_uint(f);
  x = x + 0x7FFFu + ((x >> 16) & 1u);
  return (unsigned short)(x >> 16);
}

// ---------------- init: x -> xcur (f32) + xb (bf16), vectorized ----------------
__global__ void init_x(const float* __restrict__ x, float* __restrict__ xcur,
                       unsigned short* __restrict__ xb){
  const int tot = NN*DD/4;
  int stride = gridDim.x * blockDim.x;
  for (int i = blockIdx.x*blockDim.x + threadIdx.x; i < tot; i += stride){
    f32x4 v = ((const f32x4*)x)[i];
    ((f32x4*)xcur)[i] = v;
    u16x4 o; o[0]=f2bf(v[0]); o[1]=f2bf(v[1]); o[2]=f2bf(v[2]); o[3]=f2bf(v[3]);
    ((u16x4*)xb)[i] = o;
  }
}

// --------- weight prep: Wjcat[j][s*128+o][c] = Wj[o][s*128+c]  (bf16) ---------
__global__ void wprep(const float* __restrict__ WT, const float* __restrict__ WM,
                      const float* __restrict__ WB, const float* __restrict__ Wtw,
                      unsigned short* __restrict__ Wjcat, unsigned short* __restrict__ Wtwb){
  int stride = gridDim.x * blockDim.x;
  int tid = blockIdx.x*blockDim.x + threadIdx.x;
  for (int i = tid; i < 3*D3*DD; i += stride){
    int j = i / (D3*DD);
    int rem = i - j*(D3*DD);
    int scol = rem >> 7;      // output col 0..383
    int c = rem & 127;        // input col
    int s = scol >> 7;        // slot
    int o = scol & 127;       // output feature within slot
    const float* Wj = (j==0) ? WT : ((j==1) ? WM : WB);
    Wjcat[i] = f2bf(Wj[o*D3 + s*128 + c]);
  }
  for (int i = tid; i < 128*128; i += stride) Wtwb[i] = f2bf(Wtw[i]);
}

// ---------------- CSR build ----------------
__global__ void csr_cnt(const int* __restrict__ twi, int* __restrict__ cnt){
  int e = blockIdx.x*blockDim.x + threadIdx.x;
  if (e < NE){
    atomicAdd(&cnt[0*NN + twi[0*NE + e]], 1);
    atomicAdd(&cnt[1*NN + twi[1*NE + e]], 1);
    atomicAdd(&cnt[2*NN + twi[2*NE + e]], 1);
  }
}

__global__ void scan_bs(const int* __restrict__ cnt, int* __restrict__ bsums){
  const int p = blockIdx.y, b = blockIdx.x, t = threadIdx.x;
  const int base = b * 1024;
  int s = 0;
  #pragma unroll
  for (int j = 0; j < 4; j++){
    int i = base + t + j*256;
    if (i < NN) s += cnt[p*NN + i];
  }
  __shared__ int red[256];
  red[t] = s; __syncthreads();
  #pragma unroll
  for (int o = 128; o; o >>= 1){
    if (t < o) red[t] += red[t+o];
    __syncthreads();
  }
  if (t == 0) bsums[p*SCB + b] = red[0];
}

__global__ void scan_top(int* __restrict__ bsums){
  const int p = threadIdx.x;
  if (p < 3){
    int run = 0;
    for (int i = 0; i < SCB; i++){ int v = bsums[p*SCB + i]; bsums[p*SCB + i] = run; run += v; }
  }
}

__global__ void scan_fin(const int* __restrict__ cnt, const int* __restrict__ bsums,
                         int* __restrict__ start){
  const int p = blockIdx.y, b = blockIdx.x, t = threadIdx.x;
  const int base = b * 1024;
  int v[4]; int s = 0;
  #pragma unroll
  for (int j = 0; j < 4; j++){
    int i = base + t*4 + j;
    v[j] = (i < NN) ? cnt[p*NN + i] : 0;
    s += v[j];
  }
  __shared__ int red[256];
  red[t] = s; __syncthreads();
  #pragma unroll
  for (int o = 1; o < 256; o <<= 1){
    int other = (t >= o) ? red[t - o] : 0;
    __syncthreads();
    red[t] += other;
    __syncthreads();
  }
  int ex = red[t] - s + bsums[p*SCB + b];
  #pragma unroll
  for (int j = 0; j < 4; j++){
    int i = base + t*4 + j;
    if (i < NN) start[p*NN + i] = ex;
    ex += v[j];
  }
}

// einfo[p][slot] = {e, n_{(p+1)%3}, n_{(p+2)%3}, n_p}
__global__ void csr_fill(const int* __restrict__ twi, const int* __restrict__ start,
                         int* __restrict__ cursor, int4* __restrict__ einfo){
  int e = blockIdx.x*blockDim.x + threadIdx.x;
  if (e < NE){
    int nd0 = twi[e], nd1 = twi[NE+e], nd2 = twi[2*NE+e];
    int nd[3] = {nd0, nd1, nd2};
    #pragma unroll
    for (int p = 0; p < 3; p++){
      int n = nd[p];
      int pos = atomicAdd(&cursor[p*NN + n], 1);
      int4 v;
      v.x = e; v.y = nd[(p+1)%3]; v.z = nd[(p+2)%3]; v.w = n;
      einfo[(size_t)p*NE + start[p*NN + n] + pos] = v;
    }
  }
}

// ---------------- node scores: S[s][n] = x[n] . w1[s*128: s*128+128] ----------------
__global__ void nscore(const unsigned short* __restrict__ xb,
                       const float* __restrict__ W1, float* __restrict__ S){
  __shared__ float w1s[384];
  const int t = threadIdx.x;
  for (int i = t; i < 384; i += 256) w1s[i] = W1[i];
  __syncthreads();
  const int n = blockIdx.x*256 + t;
  if (n >= NN) return;
  float s0 = 0.f, s1 = 0.f, s2 = 0.f;
  for (int k = 0; k < 128; k += 8){
    s16x8 v = *(const s16x8*)(xb + (size_t)n*DD + k);
    #pragma unroll
    for (int u = 0; u < 8; u++){
      float xv = bf2f((unsigned short)v[u]);
      s0 += xv * w1s[k+u];
      s1 += xv * w1s[128+k+u];
      s2 += xv * w1s[256+k+u];
    }
  }
  S[n] = s0; S[NN+n] = s1; S[2*NN+n] = s2;
}

// ------- edge scores: sp[e] = S0[i0]+S1[i1]+S2[i2]; block-reduced sum/sumsq -------
__global__ void escore(const int* __restrict__ twi, const float* __restrict__ S,
                       float* __restrict__ sp, float* __restrict__ stats){
  float lsum = 0.f, lsq = 0.f;
  const int stride = gridDim.x*blockDim.x;
  for (int e = blockIdx.x*blockDim.x + threadIdx.x; e < NE; e += stride){
    float s = S[twi[e]] + S[NN + twi[NE+e]] + S[2*NN + twi[2*NE+e]];
    sp[e] = s;
    lsum += s; lsq += s*s;
  }
  #pragma unroll
  for (int o = 32; o; o >>= 1){ lsum += __shfl_xor(lsum, o); lsq += __shfl_xor(lsq, o); }
  __shared__ float rs[4], rq[4];
  if ((threadIdx.x & 63) == 0){ rs[threadIdx.x >> 6] = lsum; rq[threadIdx.x >> 6] = lsq; }
  __syncthreads();
  if (threadIdx.x == 0){
    atomicAdd(&stats[ST_SUM1], rs[0]+rs[1]+rs[2]+rs[3]);
    atomicAdd(&stats[ST_SQ1],  rq[0]+rq[1]+rq[2]+rq[3]);
  }
}

// --- dense node GEMM, col-tiled: Y[n, ch*128:+128] = xb[n] @ Wj_ch^T, B in LDS ---
__launch_bounds__(256)
__global__ void ngemm(const unsigned short* __restrict__ xb,
                      const unsigned short* __restrict__ Wj,   // pre-offset to part j
                      unsigned short* __restrict__ Y){
  __shared__ unsigned short bsh[128*BPAD];   // 33 KB: B panel, reused as repack buf
  const int t = threadIdx.x;
  const int w = t >> 6, lane = t & 63;
  const int lc = lane & 15, kg = lane >> 4;
  const int ch = blockIdx.y;                 // 128-col chunk of the 384 outputs
  const int m0 = blockIdx.x*64 + w*16;
  const int arow = m0 + lc;

  // stage B panel: rows = output cols ch*128..+127, each 128 k (256B), padded stride
  for (int i = t; i < 128*16; i += 256){
    const int r = i >> 4, cc = (i & 15) * 8;
    *(s16x8*)(bsh + r*BPAD + cc) = *(const s16x8*)(Wj + (size_t)(ch*128 + r)*DD + cc);
  }
  __syncthreads();

  f32x4 acc[8];
  #pragma unroll
  for (int nf = 0; nf < 8; nf++){ acc[nf][0]=0.f; acc[nf][1]=0.f; acc[nf][2]=0.f; acc[nf][3]=0.f; }
  #pragma unroll
  for (int ks = 0; ks < 4; ks++){
    s16x8 a;
    if (arow < NN) a = *(const s16x8*)(xb + (size_t)arow*DD + ks*32 + kg*8);
    else { a[0]=0;a[1]=0;a[2]=0;a[3]=0;a[4]=0;a[5]=0;a[6]=0;a[7]=0; }
    #pragma unroll
    for (int nf = 0; nf < 8; nf++){
      s16x8 b = *(const s16x8*)(bsh + (nf*16 + lc)*BPAD + ks*32 + kg*8);
      acc[nf] = __builtin_amdgcn_mfma_f32_16x16x32_bf16(a, b, acc[nf], 0, 0, 0);
    }
  }
  __syncthreads();   // all waves done reading B panel; reuse bsh for repack

  unsigned short* ltu = bsh + w*16*BPAD;     // wave-local [16][BPAD]
  #pragma unroll
  for (int nf = 0; nf < 8; nf++)
    #pragma unroll
    for (int r = 0; r < 4; r++)
      ltu[(kg*4 + r)*BPAD + nf*16 + lc] = f2bf(acc[nf][r]);
  const int rl = lane >> 5, cg = lane & 31;
  #pragma unroll
  for (int it = 0; it < 8; it++){
    const int row = it*2 + rl;
    const int grow = m0 + row;
    if (grow < NN){
      u16x4 o = *(const u16x4*)&ltu[row*BPAD + cg*4];
      *(u16x4*)(Y + (size_t)grow*D3 + ch*128 + cg*4) = o;
    }
  }
}

// ----- edge stats for part j (node-centric CSR walk, 2 edges/wave-iter) -----
__launch_bounds__(256)
__global__ void estat(const unsigned short* __restrict__ Y,
                      const int4* __restrict__ einfo,
                      const int* __restrict__ cnt, const int* __restrict__ start,
                      float* __restrict__ stats, int j, int a, int b){
  __shared__ float bs[4][128], bq[4][128];
  const int t = threadIdx.x, w = t >> 6, lane = t & 63;
  const int half = lane >> 5, hl = lane & 31;
  const int c0 = hl*4;
  float s0=0,s1=0,s2=0,s3=0, q0=0,q1=0,q2=0,q3=0;
  const int gw = blockIdx.x*4 + w;
  const int nw = gridDim.x*4;
  for (int n = gw; n < NN; n += nw){
    const int c = cnt[j*NN + n];
    if (c == 0) continue;
    const int cs = start[j*NN + n];
    u16x4 lv = *(const u16x4*)(Y + (size_t)n*D3 + j*128 + c0);
    const float l0 = bf2f(lv[0]), l1 = bf2f(lv[1]), l2 = bf2f(lv[2]), l3 = bf2f(lv[3]);
    for (int k = 0; k < c; k += 2){
      const int kk = k + half;
      const bool valid = kk < c;
      const int4 ei = einfo[(size_t)j*NE + cs + (valid ? kk : c-1)];
      u16x4 ga = *(const u16x4*)(Y + (size_t)ei.y*D3 + a*128 + c0);
      u16x4 gb = *(const u16x4*)(Y + (size_t)ei.z*D3 + b*128 + c0);
      if (valid){
        float h0 = l0 + bf2f(ga[0]) + bf2f(gb[0]);
        float h1 = l1 + bf2f(ga[1]) + bf2f(gb[1]);
        float h2 = l2 + bf2f(ga[2]) + bf2f(gb[2]);
        float h3 = l3 + bf2f(ga[3]) + bf2f(gb[3]);
        s0 += h0; s1 += h1; s2 += h2; s3 += h3;
        q0 += h0*h0; q1 += h1*h1; q2 += h2*h2; q3 += h3*h3;
      }
    }
  }
  s0 += __shfl_xor(s0, 32); s1 += __shfl_xor(s1, 32);
  s2 += __shfl_xor(s2, 32); s3 += __shfl_xor(s3, 32);
  q0 += __shfl_xor(q0, 32); q1 += __shfl_xor(q1, 32);
  q2 += __shfl_xor(q2, 32); q3 += __shfl_xor(q3, 32);
  if (half == 0){
    bs[w][c0] = s0; bs[w][c0+1] = s1; bs[w][c0+2] = s2; bs[w][c0+3] = s3;
    bq[w][c0] = q0; bq[w][c0+1] = q1; bq[w][c0+2] = q2; bq[w][c0+3] = q3;
  }
  __syncthreads();
  if (t < 128){
    atomicAdd(&stats[ST_SUM + j*128 + t], bs[0][t]+bs[1][t]+bs[2][t]+bs[3][t]);
    atomicAdd(&stats[ST_SQ  + j*128 + t], bq[0][t]+bq[1][t]+bq[2][t]+bq[3][t]);
  }
}

// -- node-centric scatter for part j (2 edges/wave-iter): macc[n] += mean --
__launch_bounds__(256)
__global__ void escat(const unsigned short* __restrict__ Y,
                      const int4* __restrict__ einfo,
                      const float* __restrict__ att,
                      const int* __restrict__ cnt, const int* __restrict__ start,
                      const float* __restrict__ stats,
                      float* __restrict__ macc, int j, int a, int b){
  const int w = threadIdx.x >> 6, lane = threadIdx.x & 63;
  const int half = lane >> 5, hl = lane & 31;
  const int n = blockIdx.x*4 + w;
  if (n >= NN) return;
  const int c = cnt[j*NN + n];
  if (c == 0) return;
  const float invZ = 1.0f / stats[ST_SEXP];
  const int cs = start[j*NN + n];
  const int c0 = hl*4;
  u16x4 lv = *(const u16x4*)(Y + (size_t)n*D3 + j*128 + c0);
  const float l0 = bf2f(lv[0]), l1 = bf2f(lv[1]), l2 = bf2f(lv[2]), l3 = bf2f(lv[3]);
  f32x4 sc = *(const f32x4*)(stats + ST_SCALE + j*128 + c0);
  f32x4 sh = *(const f32x4*)(stats + ST_SHIFT + j*128 + c0);
  float a0=0,a1=0,a2=0,a3=0;
  for (int k = 0; k < c; k += 2){
    const int kk = k + half;
    const bool valid = kk < c;
    const int4 ei = einfo[(size_t)j*NE + cs + (valid ? kk : c-1)];
    const float av = valid ? att[ei.x] * invZ : 0.f;
    u16x4 ga = *(const u16x4*)(Y + (size_t)ei.y*D3 + a*128 + c0);
    u16x4 gb = *(const u16x4*)(Y + (size_t)ei.z*D3 + b*128 + c0);
    float h0 = l0 + bf2f(ga[0]) + bf2f(gb[0]);
    float h1 = l1 + bf2f(ga[1]) + bf2f(gb[1]);
    float h2 = l2 + bf2f(ga[2]) + bf2f(gb[2]);
    float h3 = l3 + bf2f(ga[3]) + bf2f(gb[3]);
    a0 += av * fmaxf(h0*sc[0] + sh[0], 0.f);
    a1 += av * fmaxf(h1*sc[1] + sh[1], 0.f);
    a2 += av * fmaxf(h2*sc[2] + sh[2], 0.f);
    a3 += av * fmaxf(h3*sc[3] + sh[3], 0.f);
  }
  a0 += __shfl_xor(a0, 32); a1 += __shfl_xor(a1, 32);
  a2 += __shfl_xor(a2, 32); a3 += __shfl_xor(a3, 32);
  if (half == 0){
    const float ic = 1.f / (float)c;
    f32x4* mp = (f32x4*)(macc + (size_t)n*DD + c0);
    f32x4 old = *mp;
    old[0] += a0*ic; old[1] += a1*ic; old[2] += a2*ic; old[3] += a3*ic;
    *mp = old;
  }
}

// ---------------- BN finalize ----------------
__global__ void sfin_score(const float* g1, const float* be1, float* __restrict__ stats){
  if (threadIdx.x == 0){
    float mu = stats[ST_SUM1] / (float)NE;
    float var = stats[ST_SQ1] / (float)NE - mu*mu;
    float sc = g1[0] * rsqrtf(var + EPSBN);
    stats[ST_SCALE1] = sc;
    stats[ST_SHIFT1] = be1[0] - mu*sc;
  }
}

__global__ void sfin_cols(const float* g, const float* be, float* __restrict__ stats, int part){
  int t = threadIdx.x;
  if (t < 128){
    int idx = part*128 + t;
    float mu = stats[ST_SUM + idx] / (float)NE;
    float var = stats[ST_SQ + idx] / (float)NE - mu*mu;
    float sc = g[t] * rsqrtf(var + EPSBN);
    stats[ST_SCALE + idx] = sc;
    stats[ST_SHIFT + idx] = be[t] - mu*sc;
  }
}

// ---------------- softmax: max, then sum (stores exp in place) ----------------
__global__ void sm_max(float* __restrict__ sp, float* __restrict__ stats){
  const float sc = stats[ST_SCALE1], sh = stats[ST_SHIFT1];
  float lmax = 0.f;
  int stride = gridDim.x*blockDim.x;
  for (int i = blockIdx.x*blockDim.x + threadIdx.x; i < NE; i += stride){
    float s = fmaxf(sp[i]*sc + sh, 0.f);
    sp[i] = s;
    lmax = fmaxf(lmax, s);
  }
  #pragma unroll
  for (int o = 32; o; o >>= 1) lmax = fmaxf(lmax, __shfl_xor(lmax, o));
  __shared__ float red[4];
  if ((threadIdx.x & 63) == 0) red[threadIdx.x >> 6] = lmax;
  __syncthreads();
  if (threadIdx.x == 0){
    float m = fmaxf(fmaxf(red[0], red[1]), fmaxf(red[2], red[3]));
    atomicMax((unsigned int*)&stats[ST_MAX], __float_as_uint(m));
  }
}

__global__ void sm_sum(float* __restrict__ sp, float* __restrict__ stats){
  const float mx = __uint_as_float(((const unsigned int*)stats)[ST_MAX]);
  float ls = 0.f;
  int stride = gridDim.x*blockDim.x;
  for (int i = blockIdx.x*blockDim.x + threadIdx.x; i < NE; i += stride){
    float ex = __expf(sp[i] - mx);
    sp[i] = ex;
    ls += ex;
  }
  #pragma unroll
  for (int o = 32; o; o >>= 1) ls += __shfl_xor(ls, o);
  __shared__ float red[4];
  if ((threadIdx.x & 63) == 0) red[threadIdx.x >> 6] = ls;
  __syncthreads();
  if (threadIdx.x == 0)
    atomicAdd(&stats[ST_SEXP], red[0] + red[1] + red[2] + red[3]);
}

// --- zb = bf16(macc @ Wtw^T), fused col stats, B panel in LDS + coalesced stores ---
__launch_bounds__(256)
__global__ void g2_gemm(const float* __restrict__ A,
                        const unsigned short* __restrict__ Wtwb,
                        unsigned short* __restrict__ zb,
                        float* __restrict__ stats){
  __shared__ unsigned short bsh[128*BPAD];   // 33 KB: B panel, reused as repack buf
  __shared__ float ssum[128], ssq[128];
  const int t = threadIdx.x;
  const int w = t >> 6, lane = t & 63;
  const int lc = lane & 15, kg = lane >> 4;
  if (t < 128){ ssum[t] = 0.f; ssq[t] = 0.f; }
  const int m0 = blockIdx.x*64 + w*16;
  const int arow = m0 + lc;

  // stage B panel (Wtwb 128x128 bf16), padded stride
  for (int i = t; i < 128*16; i += 256){
    const int r = i >> 4, cc = (i & 15) * 8;
    *(s16x8*)(bsh + r*BPAD + cc) = *(const s16x8*)(Wtwb + (size_t)r*DD + cc);
  }
  __syncthreads();

  f32x4 acc[8];
  #pragma unroll
  for (int nf = 0; nf < 8; nf++){ acc[nf][0]=0.f; acc[nf][1]=0.f; acc[nf][2]=0.f; acc[nf][3]=0.f; }
  #pragma unroll
  for (int ks = 0; ks < 128; ks += 32){
    s16x8 a;
    if (arow < NN){
      f32x4 a0 = *(const f32x4*)(A + (size_t)arow*DD + ks + kg*8);
      f32x4 a1 = *(const f32x4*)(A + (size_t)arow*DD + ks + kg*8 + 4);
      a[0]=(short)f2bf(a0[0]); a[1]=(short)f2bf(a0[1]); a[2]=(short)f2bf(a0[2]); a[3]=(short)f2bf(a0[3]);
      a[4]=(short)f2bf(a1[0]); a[5]=(short)f2bf(a1[1]); a[6]=(short)f2bf(a1[2]); a[7]=(short)f2bf(a1[3]);
    } else {
      a[0]=0;a[1]=0;a[2]=0;a[3]=0;a[4]=0;a[5]=0;a[6]=0;a[7]=0;
    }
    #pragma unroll
    for (int nf = 0; nf < 8; nf++){
      s16x8 b = *(const s16x8*)(bsh + (nf*16 + lc)*BPAD + ks + kg*8);
      acc[nf] = __builtin_amdgcn_mfma_f32_16x16x32_bf16(a, b, acc[nf], 0, 0, 0);
    }
  }
  // stats from acc (f32 exact)
  float ps[8], pq[8];
  #pragma unroll
  for (int nf = 0; nf < 8; nf++){
    ps[nf] = 0.f; pq[nf] = 0.f;
    #pragma unroll
    for (int r = 0; r < 4; r++){
      int row = m0 + kg*4 + r;
      if (row < NN){
        float v = acc[nf][r];
        ps[nf] += v; pq[nf] += v*v;
      }
    }
  }
  __syncthreads();   // done reading B panel; reuse bsh for repack
  #pragma unroll
  for (int nf = 0; nf < 8; nf++){
    atomicAdd(&ssum[nf*16 + lc], ps[nf]);
    atomicAdd(&ssq [nf*16 + lc], pq[nf]);
  }
  unsigned short* ltu = bsh + w*16*BPAD;     // wave-local [16][BPAD]
  #pragma unroll
  for (int nf = 0; nf < 8; nf++)
    #pragma unroll
    for (int r = 0; r < 4; r++)
      ltu[(kg*4 + r)*BPAD + nf*16 + lc] = f2bf(acc[nf][r]);
  const int rl = lane >> 5, cg = lane & 31;
  #pragma unroll
  for (int it = 0; it < 8; it++){
    const int row = it*2 + rl;
    const int grow = m0 + row;
    if (grow < NN){
      u16x4 o = *(const u16x4*)&ltu[row*BPAD + cg*4];
      *(u16x4*)(zb + (size_t)grow*DD + cg*4) = o;
    }
  }
  __syncthreads();
  if (t < 128){
    atomicAdd(&stats[ST_SUM2 + t], ssum[t]);
    atomicAdd(&stats[ST_SQ2  + t], ssq[t]);
  }
}

__global__ void sfin2(const float* gtw, const float* betw, float* __restrict__ stats){
  int c = threadIdx.x;
  if (c < 128){
    float mu = stats[ST_SUM2 + c] / (float)NN;
    float var = stats[ST_SQ2 + c] / (float)NN - mu*mu;
    float sc = gtw[c] * rsqrtf(var + EPSBN);
    stats[ST_SCALE2 + c] = sc;
    stats[ST_SHIFT2 + c] = betw[c] - mu*sc;
  }
}

// ---------------- x += relu(BN(zb)); refresh bf16 copy (vectorized) ----------------
__global__ void fuse_update(const unsigned short* __restrict__ zb,
                            const float* __restrict__ stats,
                            float* __restrict__ xcur, unsigned short* __restrict__ xb){
  const int tot = NN*DD/4;
  int stride = gridDim.x*blockDim.x;
  for (int i = blockIdx.x*blockDim.x + threadIdx.x; i < tot; i += stride){
    u16x4 z4 = ((const u16x4*)zb)[i];
    f32x4 x4 = ((const f32x4*)xcur)[i];
    const int c = (i*4) & 127;
    f32x4 o; u16x4 ob;
    #pragma unroll
    for (int j = 0; j < 4; j++){
      float hv = fmaxf(bf2f(z4[j])*stats[ST_SCALE2 + c + j] + stats[ST_SHIFT2 + c + j], 0.f);
      o[j] = x4[j] + hv;
      ob[j] = f2bf(o[j]);
    }
    ((f32x4*)xcur)[i] = o;
    ((u16x4*)xb)[i] = ob;
  }
}

extern "C" void kernel_launch(void* const* d_in, const int* in_sizes, int n_in,
                              void* d_out, int out_size, void* d_ws, size_t ws_size,
                              hipStream_t stream){
  const float* x    = (const float*)d_in[0];
  const int*   twi  = (const int*)d_in[1];
  const float* W_T  = (const float*)d_in[2];
  const float* W_M  = (const float*)d_in[3];
  const float* W_B  = (const float*)d_in[4];
  const float* W_1  = (const float*)d_in[5];
  const float* W_tw = (const float*)d_in[6];
  const float* g_T  = (const float*)d_in[8];
  const float* be_T = (const float*)d_in[9];
  const float* g_M  = (const float*)d_in[11];
  const float* be_M = (const float*)d_in[12];
  const float* g_B  = (const float*)d_in[14];
  const float* be_B = (const float*)d_in[15];
  const float* g_1  = (const float*)d_in[17];
  const float* be_1 = (const float*)d_in[18];
  const float* g_tw = (const float*)d_in[20];
  const float* be_tw= (const float*)d_in[21];
  float* xcur = (float*)d_out;

  char* ws = (char*)d_ws;
  size_t off = 0;
  auto take = [&](size_t b){ size_t o = off; off += (b + 255) & ~(size_t)255; return o; };
  float* stats = (float*)(ws + take(ST_TOTAL*4));
  unsigned short* Wjcat = (unsigned short*)(ws + take((size_t)3*D3*DD*2));
  unsigned short* Wtwb  = (unsigned short*)(ws + take(128*128*2));
  int* bsums  = (int*)(ws + take((size_t)3*SCB*4));
  int* cnt    = (int*)(ws + take((size_t)3*NN*4));
  int* startA = (int*)(ws + take((size_t)3*NN*4));
  int* cursor = (int*)(ws + take((size_t)3*NN*4));
  int4* einfo = (int4*)(ws + take((size_t)3*NE*16));
  float* sp   = (float*)(ws + take((size_t)NE*4));
  float* S    = (float*)(ws + take((size_t)3*NN*4));
  unsigned short* xb = (unsigned short*)(ws + take((size_t)NN*DD*2));
  float* macc = (float*)(ws + take((size_t)NN*DD*4));
  unsigned short* Y = (unsigned short*)(ws + take((size_t)NN*D3*2));
  unsigned short* zb = Y;   // alias: zb written by g2 only after last escat consumed Y
  if (ws_size < off) return;  // avoid faulting

  hipMemsetAsync(cnt, 0, (size_t)3*NN*4, stream);
  hipMemsetAsync(cursor, 0, (size_t)3*NN*4, stream);
  init_x<<<1024, 256, 0, stream>>>(x, xcur, xb);
  csr_cnt<<<(NE+255)/256, 256, 0, stream>>>(twi, cnt);
  scan_bs<<<dim3(SCB, 3), 256, 0, stream>>>(cnt, bsums);
  scan_top<<<1, 64, 0, stream>>>(bsums);
  scan_fin<<<dim3(SCB, 3), 256, 0, stream>>>(cnt, bsums, startA);
  csr_fill<<<(NE+255)/256, 256, 0, stream>>>(twi, startA, cursor, einfo);

  const int NGB = (NN + 63)/64;     // ngemm/g2 blocks
  const int NDB = (NN + 3)/4;       // node-wave blocks

  for (int l = 0; l < KL; l++){
    hipMemsetAsync(stats, 0, ST_TOTAL*4, stream);
    hipMemsetAsync(macc, 0, (size_t)NN*DD*4, stream);
    wprep<<<640, 256, 0, stream>>>(W_T + (size_t)l*DD*D3, W_M + (size_t)l*DD*D3,
                                   W_B + (size_t)l*DD*D3, W_tw + (size_t)l*DD*DD,
                                   Wjcat, Wtwb);
    const float* gs[3]  = {g_T  + (size_t)l*DD, g_M  + (size_t)l*DD, g_B  + (size_t)l*DD};
    const float* bes[3] = {be_T + (size_t)l*DD, be_M + (size_t)l*DD, be_B + (size_t)l*DD};

    // score path (node-decomposed)
    nscore<<<(NN+255)/256, 256, 0, stream>>>(xb, W_1 + (size_t)l*D3, S);
    escore<<<256, 256, 0, stream>>>(twi, S, sp, stats);
    sfin_score<<<1, 64, 0, stream>>>(g_1 + l, be_1 + l, stats);
    sm_max<<<256, 256, 0, stream>>>(sp, stats);
    sm_sum<<<256, 256, 0, stream>>>(sp, stats);

    // per-part: dense node GEMM -> edge stats -> BN finalize -> node scatter
    for (int j = 0; j < 3; j++){
      ngemm<<<dim3(NGB, 3), 256, 0, stream>>>(xb, Wjcat + (size_t)j*D3*DD, Y);
      estat<<<1024, 256, 0, stream>>>(Y, einfo, cnt, startA, stats, j, (j+1)%3, (j+2)%3);
      sfin_cols<<<1, 128, 0, stream>>>(gs[j], bes[j], stats, j);
      escat<<<NDB, 256, 0, stream>>>(Y, einfo, sp, cnt, startA, stats, macc,
                                     j, (j+1)%3, (j+2)%3);
    }

    g2_gemm<<<NGB, 256, 0, stream>>>(macc, Wtwb, zb, stats);
    sfin2<<<1, 128, 0, stream>>>(g_tw + (size_t)l*DD, be_tw + (size_t)l*DD, stats);
    fuse_update<<<1024, 256, 0, stream>>>(zb, stats, xcur, xb);
  }
}

// Round 18
// 1433.060 us; speedup vs baseline: 2.7369x; 1.0845x over previous
//
#include <hip/hip_runtime.h>

#define NN 100000
#define NE 400000
#define DD 128
#define D3 384
#define KL 2
#define EPSBN 1e-5f
#define SCB ((NN + 1023) / 1024)
#define BPAD 132   // padded u16 row stride for LDS B panel

typedef __attribute__((ext_vector_type(8))) short s16x8;
typedef __attribute__((ext_vector_type(4))) float f32x4;
typedef __attribute__((ext_vector_type(4))) unsigned short u16x4;
typedef __attribute__((ext_vector_type(8))) unsigned short u16x8;

#define ST_SUM    0      // [384]
#define ST_SQ     384    // [384]
#define ST_SCALE  768    // [384]
#define ST_SHIFT  1152   // [384]
#define ST_SUM1   1536
#define ST_SQ1    1537
#define ST_MAX    1538
#define ST_SEXP   1539
#define ST_SCALE1 1540
#define ST_SHIFT1 1541
#define ST_SUM2   1542   // [128]
#define ST_SQ2    1670   // [128]
#define ST_SCALE2 1798   // [128]
#define ST_SHIFT2 1926   // [128]
#define ST_TOTAL  2054

__device__ __forceinline__ float bf2f(unsigned short u){
  return __uint_as_float(((unsigned int)u) << 16);
}
__device__ __forceinline__ unsigned short f2bf(float f){
  unsigned int x = __float_as_uint(f);
  x = x + 0x7FFFu + ((x >> 16) & 1u);
  return (unsigned short)(x >> 16);
}

// ---------------- init: x -> xcur (f32) + xb (bf16), vectorized ----------------
__global__ void init_x(const float* __restrict__ x, float* __restrict__ xcur,
                       unsigned short* __restrict__ xb){
  const int tot = NN*DD/4;
  int stride = gridDim.x * blockDim.x;
  for (int i = blockIdx.x*blockDim.x + threadIdx.x; i < tot; i += stride){
    f32x4 v = ((const f32x4*)x)[i];
    ((f32x4*)xcur)[i] = v;
    u16x4 o; o[0]=f2bf(v[0]); o[1]=f2bf(v[1]); o[2]=f2bf(v[2]); o[3]=f2bf(v[3]);
    ((u16x4*)xb)[i] = o;
  }
}

// --------- weight prep: Wjcat[j][s*128+o][c] = Wj[o][s*128+c]  (bf16) ---------
__global__ void wprep(const float* __restrict__ WT, const float* __restrict__ WM,
                      const float* __restrict__ WB, const float* __restrict__ Wtw,
                      unsigned short* __restrict__ Wjcat, unsigned short* __restrict__ Wtwb){
  int stride = gridDim.x * blockDim.x;
  int tid = blockIdx.x*blockDim.x + threadIdx.x;
  for (int i = tid; i < 3*D3*DD; i += stride){
    int j = i / (D3*DD);
    int rem = i - j*(D3*DD);
    int scol = rem >> 7;      // output col 0..383
    int c = rem & 127;        // input col
    int s = scol >> 7;        // slot
    int o = scol & 127;       // output feature within slot
    const float* Wj = (j==0) ? WT : ((j==1) ? WM : WB);
    Wjcat[i] = f2bf(Wj[o*D3 + s*128 + c]);
  }
  for (int i = tid; i < 128*128; i += stride) Wtwb[i] = f2bf(Wtw[i]);
}

// ---------------- CSR build ----------------
__global__ void csr_cnt(const int* __restrict__ twi, int* __restrict__ cnt){
  int e = blockIdx.x*blockDim.x + threadIdx.x;
  if (e < NE){
    atomicAdd(&cnt[0*NN + twi[0*NE + e]], 1);
    atomicAdd(&cnt[1*NN + twi[1*NE + e]], 1);
    atomicAdd(&cnt[2*NN + twi[2*NE + e]], 1);
  }
}

__global__ void scan_bs(const int* __restrict__ cnt, int* __restrict__ bsums){
  const int p = blockIdx.y, b = blockIdx.x, t = threadIdx.x;
  const int base = b * 1024;
  int s = 0;
  #pragma unroll
  for (int j = 0; j < 4; j++){
    int i = base + t + j*256;
    if (i < NN) s += cnt[p*NN + i];
  }
  __shared__ int red[256];
  red[t] = s; __syncthreads();
  #pragma unroll
  for (int o = 128; o; o >>= 1){
    if (t < o) red[t] += red[t+o];
    __syncthreads();
  }
  if (t == 0) bsums[p*SCB + b] = red[0];
}

__global__ void scan_top(int* __restrict__ bsums){
  const int p = threadIdx.x;
  if (p < 3){
    int run = 0;
    for (int i = 0; i < SCB; i++){ int v = bsums[p*SCB + i]; bsums[p*SCB + i] = run; run += v; }
  }
}

__global__ void scan_fin(const int* __restrict__ cnt, const int* __restrict__ bsums,
                         int* __restrict__ start){
  const int p = blockIdx.y, b = blockIdx.x, t = threadIdx.x;
  const int base = b * 1024;
  int v[4]; int s = 0;
  #pragma unroll
  for (int j = 0; j < 4; j++){
    int i = base + t*4 + j;
    v[j] = (i < NN) ? cnt[p*NN + i] : 0;
    s += v[j];
  }
  __shared__ int red[256];
  red[t] = s; __syncthreads();
  #pragma unroll
  for (int o = 1; o < 256; o <<= 1){
    int other = (t >= o) ? red[t - o] : 0;
    __syncthreads();
    red[t] += other;
    __syncthreads();
  }
  int ex = red[t] - s + bsums[p*SCB + b];
  #pragma unroll
  for (int j = 0; j < 4; j++){
    int i = base + t*4 + j;
    if (i < NN) start[p*NN + i] = ex;
    ex += v[j];
  }
}

// einfo[p][slot] = {e, n_{(p+1)%3}, n_{(p+2)%3}, n_p}
__global__ void csr_fill(const int* __restrict__ twi, const int* __restrict__ start,
                         int* __restrict__ cursor, int4* __restrict__ einfo){
  int e = blockIdx.x*blockDim.x + threadIdx.x;
  if (e < NE){
    int nd0 = twi[e], nd1 = twi[NE+e], nd2 = twi[2*NE+e];
    int nd[3] = {nd0, nd1, nd2};
    #pragma unroll
    for (int p = 0; p < 3; p++){
      int n = nd[p];
      int pos = atomicAdd(&cursor[p*NN + n], 1);
      int4 v;
      v.x = e; v.y = nd[(p+1)%3]; v.z = nd[(p+2)%3]; v.w = n;
      einfo[(size_t)p*NE + start[p*NN + n] + pos] = v;
    }
  }
}

// ---------------- node scores: S[s][n] = x[n] . w1[s*128: s*128+128] ----------------
__global__ void nscore(const unsigned short* __restrict__ xb,
                       const float* __restrict__ W1, float* __restrict__ S){
  __shared__ float w1s[384];
  const int t = threadIdx.x;
  for (int i = t; i < 384; i += 256) w1s[i] = W1[i];
  __syncthreads();
  const int n = blockIdx.x*256 + t;
  if (n >= NN) return;
  float s0 = 0.f, s1 = 0.f, s2 = 0.f;
  for (int k = 0; k < 128; k += 8){
    s16x8 v = *(const s16x8*)(xb + (size_t)n*DD + k);
    #pragma unroll
    for (int u = 0; u < 8; u++){
      float xv = bf2f((unsigned short)v[u]);
      s0 += xv * w1s[k+u];
      s1 += xv * w1s[128+k+u];
      s2 += xv * w1s[256+k+u];
    }
  }
  S[n] = s0; S[NN+n] = s1; S[2*NN+n] = s2;
}

// ------- edge scores: sp[e] = S0[i0]+S1[i1]+S2[i2]; block-reduced sum/sumsq -------
__global__ void escore(const int* __restrict__ twi, const float* __restrict__ S,
                       float* __restrict__ sp, float* __restrict__ stats){
  float lsum = 0.f, lsq = 0.f;
  const int stride = gridDim.x*blockDim.x;
  for (int e = blockIdx.x*blockDim.x + threadIdx.x; e < NE; e += stride){
    float s = S[twi[e]] + S[NN + twi[NE+e]] + S[2*NN + twi[2*NE+e]];
    sp[e] = s;
    lsum += s; lsq += s*s;
  }
  #pragma unroll
  for (int o = 32; o; o >>= 1){ lsum += __shfl_xor(lsum, o); lsq += __shfl_xor(lsq, o); }
  __shared__ float rs[4], rq[4];
  if ((threadIdx.x & 63) == 0){ rs[threadIdx.x >> 6] = lsum; rq[threadIdx.x >> 6] = lsq; }
  __syncthreads();
  if (threadIdx.x == 0){
    atomicAdd(&stats[ST_SUM1], rs[0]+rs[1]+rs[2]+rs[3]);
    atomicAdd(&stats[ST_SQ1],  rq[0]+rq[1]+rq[2]+rq[3]);
  }
}

// --- dense node GEMM, col-tiled: Y[n, ch*128:+128] = xb[n] @ Wj_ch^T, B in LDS ---
__launch_bounds__(256)
__global__ void ngemm(const unsigned short* __restrict__ xb,
                      const unsigned short* __restrict__ Wj,   // pre-offset to part j
                      unsigned short* __restrict__ Y){
  __shared__ unsigned short bsh[128*BPAD];   // 33 KB: B panel, reused as repack buf
  const int t = threadIdx.x;
  const int w = t >> 6, lane = t & 63;
  const int lc = lane & 15, kg = lane >> 4;
  const int ch = blockIdx.y;                 // 128-col chunk of the 384 outputs
  const int m0 = blockIdx.x*64 + w*16;
  const int arow = m0 + lc;

  for (int i = t; i < 128*16; i += 256){
    const int r = i >> 4, cc = (i & 15) * 8;
    *(s16x8*)(bsh + r*BPAD + cc) = *(const s16x8*)(Wj + (size_t)(ch*128 + r)*DD + cc);
  }
  __syncthreads();

  f32x4 acc[8];
  #pragma unroll
  for (int nf = 0; nf < 8; nf++){ acc[nf][0]=0.f; acc[nf][1]=0.f; acc[nf][2]=0.f; acc[nf][3]=0.f; }
  #pragma unroll
  for (int ks = 0; ks < 4; ks++){
    s16x8 a;
    if (arow < NN) a = *(const s16x8*)(xb + (size_t)arow*DD + ks*32 + kg*8);
    else { a[0]=0;a[1]=0;a[2]=0;a[3]=0;a[4]=0;a[5]=0;a[6]=0;a[7]=0; }
    #pragma unroll
    for (int nf = 0; nf < 8; nf++){
      s16x8 b = *(const s16x8*)(bsh + (nf*16 + lc)*BPAD + ks*32 + kg*8);
      acc[nf] = __builtin_amdgcn_mfma_f32_16x16x32_bf16(a, b, acc[nf], 0, 0, 0);
    }
  }
  __syncthreads();   // all waves done reading B panel; reuse bsh for repack

  unsigned short* ltu = bsh + w*16*BPAD;     // wave-local [16][BPAD]
  #pragma unroll
  for (int nf = 0; nf < 8; nf++)
    #pragma unroll
    for (int r = 0; r < 4; r++)
      ltu[(kg*4 + r)*BPAD + nf*16 + lc] = f2bf(acc[nf][r]);
  const int rl = lane >> 5, cg = lane & 31;
  #pragma unroll
  for (int it = 0; it < 8; it++){
    const int row = it*2 + rl;
    const int grow = m0 + row;
    if (grow < NN){
      u16x4 o = *(const u16x4*)&ltu[row*BPAD + cg*4];
      *(u16x4*)(Y + (size_t)grow*D3 + ch*128 + cg*4) = o;
    }
  }
}

// ----- edge stats for part j (node-centric CSR walk, 4 edges/wave-iter) -----
__launch_bounds__(256)
__global__ void estat(const unsigned short* __restrict__ Y,
                      const int4* __restrict__ einfo,
                      const int* __restrict__ cnt, const int* __restrict__ start,
                      float* __restrict__ stats, int j, int a, int b){
  __shared__ float bs[4][128], bq[4][128];
  const int t = threadIdx.x, w = t >> 6, lane = t & 63;
  const int q = lane >> 4, ql = lane & 15;
  const int c0 = ql*8;
  float s[8] = {0,0,0,0,0,0,0,0}, qq[8] = {0,0,0,0,0,0,0,0};
  const int gw = blockIdx.x*4 + w;
  const int nw = gridDim.x*4;
  for (int n = gw; n < NN; n += nw){
    const int c = cnt[j*NN + n];
    if (c == 0) continue;
    const int cs = start[j*NN + n];
    u16x8 lv = *(const u16x8*)(Y + (size_t)n*D3 + j*128 + c0);
    float lf[8];
    #pragma unroll
    for (int u = 0; u < 8; u++) lf[u] = bf2f(lv[u]);
    for (int k = 0; k < c; k += 4){
      const int kk = k + q;
      const bool valid = kk < c;
      const int4 ei = einfo[(size_t)j*NE + cs + (valid ? kk : c-1)];
      u16x8 ga = *(const u16x8*)(Y + (size_t)ei.y*D3 + a*128 + c0);
      u16x8 gb = *(const u16x8*)(Y + (size_t)ei.z*D3 + b*128 + c0);
      if (valid){
        #pragma unroll
        for (int u = 0; u < 8; u++){
          float h = lf[u] + bf2f(ga[u]) + bf2f(gb[u]);
          s[u] += h; qq[u] += h*h;
        }
      }
    }
  }
  #pragma unroll
  for (int u = 0; u < 8; u++){
    s[u]  += __shfl_xor(s[u], 16);  s[u]  += __shfl_xor(s[u], 32);
    qq[u] += __shfl_xor(qq[u], 16); qq[u] += __shfl_xor(qq[u], 32);
  }
  if (q == 0){
    #pragma unroll
    for (int u = 0; u < 8; u++){ bs[w][c0+u] = s[u]; bq[w][c0+u] = qq[u]; }
  }
  __syncthreads();
  if (t < 128){
    atomicAdd(&stats[ST_SUM + j*128 + t], bs[0][t]+bs[1][t]+bs[2][t]+bs[3][t]);
    atomicAdd(&stats[ST_SQ  + j*128 + t], bq[0][t]+bq[1][t]+bq[2][t]+bq[3][t]);
  }
}

// -- node-centric scatter for part j (4 edges/wave-iter): macc[n] += mean --
__launch_bounds__(256)
__global__ void escat(const unsigned short* __restrict__ Y,
                      const int4* __restrict__ einfo,
                      const float* __restrict__ att,
                      const int* __restrict__ cnt, const int* __restrict__ start,
                      const float* __restrict__ stats,
                      float* __restrict__ macc, int j, int a, int b){
  const int w = threadIdx.x >> 6, lane = threadIdx.x & 63;
  const int q = lane >> 4, ql = lane & 15;
  const int n = blockIdx.x*4 + w;
  if (n >= NN) return;
  const int c = cnt[j*NN + n];
  if (c == 0) return;
  const float invZ = 1.0f / stats[ST_SEXP];
  const int cs = start[j*NN + n];
  const int c0 = ql*8;
  u16x8 lv = *(const u16x8*)(Y + (size_t)n*D3 + j*128 + c0);
  float lf[8];
  #pragma unroll
  for (int u = 0; u < 8; u++) lf[u] = bf2f(lv[u]);
  f32x4 scA = *(const f32x4*)(stats + ST_SCALE + j*128 + c0);
  f32x4 scB = *(const f32x4*)(stats + ST_SCALE + j*128 + c0 + 4);
  f32x4 shA = *(const f32x4*)(stats + ST_SHIFT + j*128 + c0);
  f32x4 shB = *(const f32x4*)(stats + ST_SHIFT + j*128 + c0 + 4);
  float sc[8] = {scA[0],scA[1],scA[2],scA[3],scB[0],scB[1],scB[2],scB[3]};
  float sh[8] = {shA[0],shA[1],shA[2],shA[3],shB[0],shB[1],shB[2],shB[3]};
  float acc[8] = {0,0,0,0,0,0,0,0};
  for (int k = 0; k < c; k += 4){
    const int kk = k + q;
    const bool valid = kk < c;
    const int4 ei = einfo[(size_t)j*NE + cs + (valid ? kk : c-1)];
    const float av = valid ? att[ei.x] * invZ : 0.f;
    u16x8 ga = *(const u16x8*)(Y + (size_t)ei.y*D3 + a*128 + c0);
    u16x8 gb = *(const u16x8*)(Y + (size_t)ei.z*D3 + b*128 + c0);
    #pragma unroll
    for (int u = 0; u < 8; u++){
      float h = lf[u] + bf2f(ga[u]) + bf2f(gb[u]);
      acc[u] += av * fmaxf(h*sc[u] + sh[u], 0.f);
    }
  }
  #pragma unroll
  for (int u = 0; u < 8; u++){
    acc[u] += __shfl_xor(acc[u], 16);
    acc[u] += __shfl_xor(acc[u], 32);
  }
  if (q == 0){
    const float ic = 1.f / (float)c;
    f32x4* mp0 = (f32x4*)(macc + (size_t)n*DD + c0);
    f32x4* mp1 = (f32x4*)(macc + (size_t)n*DD + c0 + 4);
    f32x4 o0 = *mp0, o1 = *mp1;
    o0[0] += acc[0]*ic; o0[1] += acc[1]*ic; o0[2] += acc[2]*ic; o0[3] += acc[3]*ic;
    o1[0] += acc[4]*ic; o1[1] += acc[5]*ic; o1[2] += acc[6]*ic; o1[3] += acc[7]*ic;
    *mp0 = o0; *mp1 = o1;
  }
}

// ---------------- BN finalize ----------------
__global__ void sfin_score(const float* g1, const float* be1, float* __restrict__ stats){
  if (threadIdx.x == 0){
    float mu = stats[ST_SUM1] / (float)NE;
    float var = stats[ST_SQ1] / (float)NE - mu*mu;
    float sc = g1[0] * rsqrtf(var + EPSBN);
    stats[ST_SCALE1] = sc;
    stats[ST_SHIFT1] = be1[0] - mu*sc;
  }
}

__global__ void sfin_cols(const float* g, const float* be, float* __restrict__ stats, int part){
  int t = threadIdx.x;
  if (t < 128){
    int idx = part*128 + t;
    float mu = stats[ST_SUM + idx] / (float)NE;
    float var = stats[ST_SQ + idx] / (float)NE - mu*mu;
    float sc = g[t] * rsqrtf(var + EPSBN);
    stats[ST_SCALE + idx] = sc;
    stats[ST_SHIFT + idx] = be[t] - mu*sc;
  }
}

// ---------------- softmax: max, then sum (stores exp in place) ----------------
__global__ void sm_max(float* __restrict__ sp, float* __restrict__ stats){
  const float sc = stats[ST_SCALE1], sh = stats[ST_SHIFT1];
  float lmax = 0.f;
  int stride = gridDim.x*blockDim.x;
  for (int i = blockIdx.x*blockDim.x + threadIdx.x; i < NE; i += stride){
    float s = fmaxf(sp[i]*sc + sh, 0.f);
    sp[i] = s;
    lmax = fmaxf(lmax, s);
  }
  #pragma unroll
  for (int o = 32; o; o >>= 1) lmax = fmaxf(lmax, __shfl_xor(lmax, o));
  __shared__ float red[4];
  if ((threadIdx.x & 63) == 0) red[threadIdx.x >> 6] = lmax;
  __syncthreads();
  if (threadIdx.x == 0){
    float m = fmaxf(fmaxf(red[0], red[1]), fmaxf(red[2], red[3]));
    atomicMax((unsigned int*)&stats[ST_MAX], __float_as_uint(m));
  }
}

__global__ void sm_sum(float* __restrict__ sp, float* __restrict__ stats){
  const float mx = __uint_as_float(((const unsigned int*)stats)[ST_MAX]);
  float ls = 0.f;
  int stride = gridDim.x*blockDim.x;
  for (int i = blockIdx.x*blockDim.x + threadIdx.x; i < NE; i += stride){
    float ex = __expf(sp[i] - mx);
    sp[i] = ex;
    ls += ex;
  }
  #pragma unroll
  for (int o = 32; o; o >>= 1) ls += __shfl_xor(ls, o);
  __shared__ float red[4];
  if ((threadIdx.x & 63) == 0) red[threadIdx.x >> 6] = ls;
  __syncthreads();
  if (threadIdx.x == 0)
    atomicAdd(&stats[ST_SEXP], red[0] + red[1] + red[2] + red[3]);
}

// --- zb = bf16(macc @ Wtw^T), fused col stats, B panel in LDS + coalesced stores ---
__launch_bounds__(256)
__global__ void g2_gemm(const float* __restrict__ A,
                        const unsigned short* __restrict__ Wtwb,
                        unsigned short* __restrict__ zb,
                        float* __restrict__ stats){
  __shared__ unsigned short bsh[128*BPAD];   // 33 KB: B panel, reused as repack buf
  __shared__ float ssum[128], ssq[128];
  const int t = threadIdx.x;
  const int w = t >> 6, lane = t & 63;
  const int lc = lane & 15, kg = lane >> 4;
  if (t < 128){ ssum[t] = 0.f; ssq[t] = 0.f; }
  const int m0 = blockIdx.x*64 + w*16;
  const int arow = m0 + lc;

  for (int i = t; i < 128*16; i += 256){
    const int r = i >> 4, cc = (i & 15) * 8;
    *(s16x8*)(bsh + r*BPAD + cc) = *(const s16x8*)(Wtwb + (size_t)r*DD + cc);
  }
  __syncthreads();

  f32x4 acc[8];
  #pragma unroll
  for (int nf = 0; nf < 8; nf++){ acc[nf][0]=0.f; acc[nf][1]=0.f; acc[nf][2]=0.f; acc[nf][3]=0.f; }
  #pragma unroll
  for (int ks = 0; ks < 128; ks += 32){
    s16x8 a;
    if (arow < NN){
      f32x4 a0 = *(const f32x4*)(A + (size_t)arow*DD + ks + kg*8);
      f32x4 a1 = *(const f32x4*)(A + (size_t)arow*DD + ks + kg*8 + 4);
      a[0]=(short)f2bf(a0[0]); a[1]=(short)f2bf(a0[1]); a[2]=(short)f2bf(a0[2]); a[3]=(short)f2bf(a0[3]);
      a[4]=(short)f2bf(a1[0]); a[5]=(short)f2bf(a1[1]); a[6]=(short)f2bf(a1[2]); a[7]=(short)f2bf(a1[3]);
    } else {
      a[0]=0;a[1]=0;a[2]=0;a[3]=0;a[4]=0;a[5]=0;a[6]=0;a[7]=0;
    }
    #pragma unroll
    for (int nf = 0; nf < 8; nf++){
      s16x8 b = *(const s16x8*)(bsh + (nf*16 + lc)*BPAD + ks + kg*8);
      acc[nf] = __builtin_amdgcn_mfma_f32_16x16x32_bf16(a, b, acc[nf], 0, 0, 0);
    }
  }
  float ps[8], pq[8];
  #pragma unroll
  for (int nf = 0; nf < 8; nf++){
    ps[nf] = 0.f; pq[nf] = 0.f;
    #pragma unroll
    for (int r = 0; r < 4; r++){
      int row = m0 + kg*4 + r;
      if (row < NN){
        float v = acc[nf][r];
        ps[nf] += v; pq[nf] += v*v;
      }
    }
  }
  __syncthreads();   // done reading B panel; reuse bsh for repack
  #pragma unroll
  for (int nf = 0; nf < 8; nf++){
    atomicAdd(&ssum[nf*16 + lc], ps[nf]);
    atomicAdd(&ssq [nf*16 + lc], pq[nf]);
  }
  unsigned short* ltu = bsh + w*16*BPAD;     // wave-local [16][BPAD]
  #pragma unroll
  for (int nf = 0; nf < 8; nf++)
    #pragma unroll
    for (int r = 0; r < 4; r++)
      ltu[(kg*4 + r)*BPAD + nf*16 + lc] = f2bf(acc[nf][r]);
  const int rl = lane >> 5, cg = lane & 31;
  #pragma unroll
  for (int it = 0; it < 8; it++){
    const int row = it*2 + rl;
    const int grow = m0 + row;
    if (grow < NN){
      u16x4 o = *(const u16x4*)&ltu[row*BPAD + cg*4];
      *(u16x4*)(zb + (size_t)grow*DD + cg*4) = o;
    }
  }
  __syncthreads();
  if (t < 128){
    atomicAdd(&stats[ST_SUM2 + t], ssum[t]);
    atomicAdd(&stats[ST_SQ2  + t], ssq[t]);
  }
}

__global__ void sfin2(const float* gtw, const float* betw, float* __restrict__ stats){
  int c = threadIdx.x;
  if (c < 128){
    float mu = stats[ST_SUM2 + c] / (float)NN;
    float var = stats[ST_SQ2 + c] / (float)NN - mu*mu;
    float sc = gtw[c] * rsqrtf(var + EPSBN);
    stats[ST_SCALE2 + c] = sc;
    stats[ST_SHIFT2 + c] = betw[c] - mu*sc;
  }
}

// ---------------- x += relu(BN(zb)); refresh bf16 copy (vectorized) ----------------
__global__ void fuse_update(const unsigned short* __restrict__ zb,
                            const float* __restrict__ stats,
                            float* __restrict__ xcur, unsigned short* __restrict__ xb){
  const int tot = NN*DD/4;
  int stride = gridDim.x*blockDim.x;
  for (int i = blockIdx.x*blockDim.x + threadIdx.x; i < tot; i += stride){
    u16x4 z4 = ((const u16x4*)zb)[i];
    f32x4 x4 = ((const f32x4*)xcur)[i];
    const int c = (i*4) & 127;
    f32x4 o; u16x4 ob;
    #pragma unroll
    for (int j = 0; j < 4; j++){
      float hv = fmaxf(bf2f(z4[j])*stats[ST_SCALE2 + c + j] + stats[ST_SHIFT2 + c + j], 0.f);
      o[j] = x4[j] + hv;
      ob[j] = f2bf(o[j]);
    }
    ((f32x4*)xcur)[i] = o;
    ((u16x4*)xb)[i] = ob;
  }
}

extern "C" void kernel_launch(void* const* d_in, const int* in_sizes, int n_in,
                              void* d_out, int out_size, void* d_ws, size_t ws_size,
                              hipStream_t stream){
  const float* x    = (const float*)d_in[0];
  const int*   twi  = (const int*)d_in[1];
  const float* W_T  = (const float*)d_in[2];
  const float* W_M  = (const float*)d_in[3];
  const float* W_B  = (const float*)d_in[4];
  const float* W_1  = (const float*)d_in[5];
  const float* W_tw = (const float*)d_in[6];
  const float* g_T  = (const float*)d_in[8];
  const float* be_T = (const float*)d_in[9];
  const float* g_M  = (const float*)d_in[11];
  const float* be_M = (const float*)d_in[12];
  const float* g_B  = (const float*)d_in[14];
  const float* be_B = (const float*)d_in[15];
  const float* g_1  = (const float*)d_in[17];
  const float* be_1 = (const float*)d_in[18];
  const float* g_tw = (const float*)d_in[20];
  const float* be_tw= (const float*)d_in[21];
  float* xcur = (float*)d_out;

  char* ws = (char*)d_ws;
  size_t off = 0;
  auto take = [&](size_t b){ size_t o = off; off += (b + 255) & ~(size_t)255; return o; };
  float* stats = (float*)(ws + take(ST_TOTAL*4));
  unsigned short* Wjcat = (unsigned short*)(ws + take((size_t)3*D3*DD*2));
  unsigned short* Wtwb  = (unsigned short*)(ws + take(128*128*2));
  int* bsums  = (int*)(ws + take((size_t)3*SCB*4));
  int* cnt    = (int*)(ws + take((size_t)3*NN*4));
  int* startA = (int*)(ws + take((size_t)3*NN*4));
  int* cursor = (int*)(ws + take((size_t)3*NN*4));
  int4* einfo = (int4*)(ws + take((size_t)3*NE*16));
  float* sp   = (float*)(ws + take((size_t)NE*4));
  float* S    = (float*)(ws + take((size_t)3*NN*4));
  unsigned short* xb = (unsigned short*)(ws + take((size_t)NN*DD*2));
  float* macc = (float*)(ws + take((size_t)NN*DD*4));
  unsigned short* Y = (unsigned short*)(ws + take((size_t)NN*D3*2));
  unsigned short* zb = Y;   // alias: zb written by g2 only after last escat consumed Y
  if (ws_size < off) return;  // avoid faulting

  hipMemsetAsync(cnt, 0, (size_t)3*NN*4, stream);
  hipMemsetAsync(cursor, 0, (size_t)3*NN*4, stream);
  init_x<<<1024, 256, 0, stream>>>(x, xcur, xb);
  csr_cnt<<<(NE+255)/256, 256, 0, stream>>>(twi, cnt);
  scan_bs<<<dim3(SCB, 3), 256, 0, stream>>>(cnt, bsums);
  scan_top<<<1, 64, 0, stream>>>(bsums);
  scan_fin<<<dim3(SCB, 3), 256, 0, stream>>>(cnt, bsums, startA);
  csr_fill<<<(NE+255)/256, 256, 0, stream>>>(twi, startA, cursor, einfo);

  const int NGB = (NN + 63)/64;     // ngemm/g2 blocks
  const int NDB = (NN + 3)/4;       // node-wave blocks

  for (int l = 0; l < KL; l++){
    hipMemsetAsync(stats, 0, ST_TOTAL*4, stream);
    hipMemsetAsync(macc, 0, (size_t)NN*DD*4, stream);
    wprep<<<640, 256, 0, stream>>>(W_T + (size_t)l*DD*D3, W_M + (size_t)l*DD*D3,
                                   W_B + (size_t)l*DD*D3, W_tw + (size_t)l*DD*DD,
                                   Wjcat, Wtwb);
    const float* gs[3]  = {g_T  + (size_t)l*DD, g_M  + (size_t)l*DD, g_B  + (size_t)l*DD};
    const float* bes[3] = {be_T + (size_t)l*DD, be_M + (size_t)l*DD, be_B + (size_t)l*DD};

    // score path (node-decomposed)
    nscore<<<(NN+255)/256, 256, 0, stream>>>(xb, W_1 + (size_t)l*D3, S);
    escore<<<256, 256, 0, stream>>>(twi, S, sp, stats);
    sfin_score<<<1, 64, 0, stream>>>(g_1 + l, be_1 + l, stats);
    sm_max<<<256, 256, 0, stream>>>(sp, stats);
    sm_sum<<<256, 256, 0, stream>>>(sp, stats);

    // per-part: dense node GEMM -> edge stats -> BN finalize -> node scatter
    for (int j = 0; j < 3; j++){
      ngemm<<<dim3(NGB, 3), 256, 0, stream>>>(xb, Wjcat + (size_t)j*D3*DD, Y);
      estat<<<1024, 256, 0, stream>>>(Y, einfo, cnt, startA, stats, j, (j+1)%3, (j+2)%3);
      sfin_cols<<<1, 128, 0, stream>>>(gs[j], bes[j], stats, j);
      escat<<<NDB, 256, 0, stream>>>(Y, einfo, sp, cnt, startA, stats, macc,
                                     j, (j+1)%3, (j+2)%3);
    }

    g2_gemm<<<NGB, 256, 0, stream>>>(macc, Wtwb, zb, stats);
    sfin2<<<1, 128, 0, stream>>>(g_tw + (size_t)l*DD, be_tw + (size_t)l*DD, stats);
    fuse_update<<<1024, 256, 0, stream>>>(zb, stats, xcur, xb);
  }
}

// Round 19
// 1410.057 us; speedup vs baseline: 2.7815x; 1.0163x over previous
//
#include <hip/hip_runtime.h>

#define NN 100000
#define NE 400000
#define DD 128
#define D3 384
#define KL 2
#define EPSBN 1e-5f
#define SCB ((NN + 1023) / 1024)
#define BPAD 132   // padded u16 row stride for LDS B panel

typedef __attribute__((ext_vector_type(8))) short s16x8;
typedef __attribute__((ext_vector_type(4))) float f32x4;
typedef __attribute__((ext_vector_type(4))) unsigned short u16x4;
typedef __attribute__((ext_vector_type(8))) unsigned short u16x8;

#define ST_SUM    0      // [384]
#define ST_SQ     384    // [384]
#define ST_SCALE  768    // [384]
#define ST_SHIFT  1152   // [384]
#define ST_SUM1   1536
#define ST_SQ1    1537
#define ST_MAX    1538
#define ST_SEXP   1539
#define ST_SCALE1 1540
#define ST_SHIFT1 1541
#define ST_SUM2   1542   // [128]
#define ST_SQ2    1670   // [128]
#define ST_SCALE2 1798   // [128]
#define ST_SHIFT2 1926   // [128]
#define ST_TOTAL  2054

__device__ __forceinline__ float bf2f(unsigned short u){
  return __uint_as_float(((unsigned int)u) << 16);
}
__device__ __forceinline__ unsigned short f2bf(float f){
  unsigned int x = __float_as_uint(f);
  x = x + 0x7FFFu + ((x >> 16) & 1u);
  return (unsigned short)(x >> 16);
}

// ---------------- init: x -> xcur (f32) + xb (bf16), vectorized ----------------
__global__ void init_x(const float* __restrict__ x, float* __restrict__ xcur,
                       unsigned short* __restrict__ xb){
  const int tot = NN*DD/4;
  int stride = gridDim.x * blockDim.x;
  for (int i = blockIdx.x*blockDim.x + threadIdx.x; i < tot; i += stride){
    f32x4 v = ((const f32x4*)x)[i];
    ((f32x4*)xcur)[i] = v;
    u16x4 o; o[0]=f2bf(v[0]); o[1]=f2bf(v[1]); o[2]=f2bf(v[2]); o[3]=f2bf(v[3]);
    ((u16x4*)xb)[i] = o;
  }
}

// --------- weight prep: Wjcat[j][s*128+o][c] = Wj[o][s*128+c]  (bf16) ---------
__global__ void wprep(const float* __restrict__ WT, const float* __restrict__ WM,
                      const float* __restrict__ WB, const float* __restrict__ Wtw,
                      unsigned short* __restrict__ Wjcat, unsigned short* __restrict__ Wtwb){
  int stride = gridDim.x * blockDim.x;
  int tid = blockIdx.x*blockDim.x + threadIdx.x;
  for (int i = tid; i < 3*D3*DD; i += stride){
    int j = i / (D3*DD);
    int rem = i - j*(D3*DD);
    int scol = rem >> 7;      // output col 0..383
    int c = rem & 127;        // input col
    int s = scol >> 7;        // slot
    int o = scol & 127;       // output feature within slot
    const float* Wj = (j==0) ? WT : ((j==1) ? WM : WB);
    Wjcat[i] = f2bf(Wj[o*D3 + s*128 + c]);
  }
  for (int i = tid; i < 128*128; i += stride) Wtwb[i] = f2bf(Wtw[i]);
}

// ---------------- CSR build ----------------
__global__ void csr_cnt(const int* __restrict__ twi, int* __restrict__ cnt){
  int e = blockIdx.x*blockDim.x + threadIdx.x;
  if (e < NE){
    atomicAdd(&cnt[0*NN + twi[0*NE + e]], 1);
    atomicAdd(&cnt[1*NN + twi[1*NE + e]], 1);
    atomicAdd(&cnt[2*NN + twi[2*NE + e]], 1);
  }
}

__global__ void scan_bs(const int* __restrict__ cnt, int* __restrict__ bsums){
  const int p = blockIdx.y, b = blockIdx.x, t = threadIdx.x;
  const int base = b * 1024;
  int s = 0;
  #pragma unroll
  for (int j = 0; j < 4; j++){
    int i = base + t + j*256;
    if (i < NN) s += cnt[p*NN + i];
  }
  __shared__ int red[256];
  red[t] = s; __syncthreads();
  #pragma unroll
  for (int o = 128; o; o >>= 1){
    if (t < o) red[t] += red[t+o];
    __syncthreads();
  }
  if (t == 0) bsums[p*SCB + b] = red[0];
}

__global__ void scan_top(int* __restrict__ bsums){
  const int p = threadIdx.x;
  if (p < 3){
    int run = 0;
    for (int i = 0; i < SCB; i++){ int v = bsums[p*SCB + i]; bsums[p*SCB + i] = run; run += v; }
  }
}

__global__ void scan_fin(const int* __restrict__ cnt, const int* __restrict__ bsums,
                         int* __restrict__ start){
  const int p = blockIdx.y, b = blockIdx.x, t = threadIdx.x;
  const int base = b * 1024;
  int v[4]; int s = 0;
  #pragma unroll
  for (int j = 0; j < 4; j++){
    int i = base + t*4 + j;
    v[j] = (i < NN) ? cnt[p*NN + i] : 0;
    s += v[j];
  }
  __shared__ int red[256];
  red[t] = s; __syncthreads();
  #pragma unroll
  for (int o = 1; o < 256; o <<= 1){
    int other = (t >= o) ? red[t - o] : 0;
    __syncthreads();
    red[t] += other;
    __syncthreads();
  }
  int ex = red[t] - s + bsums[p*SCB + b];
  #pragma unroll
  for (int j = 0; j < 4; j++){
    int i = base + t*4 + j;
    if (i < NN) start[p*NN + i] = ex;
    ex += v[j];
  }
}

// einfo[p][slot] = {e, n_{(p+1)%3}, n_{(p+2)%3}, n_p}
__global__ void csr_fill(const int* __restrict__ twi, const int* __restrict__ start,
                         int* __restrict__ cursor, int4* __restrict__ einfo){
  int e = blockIdx.x*blockDim.x + threadIdx.x;
  if (e < NE){
    int nd0 = twi[e], nd1 = twi[NE+e], nd2 = twi[2*NE+e];
    int nd[3] = {nd0, nd1, nd2};
    #pragma unroll
    for (int p = 0; p < 3; p++){
      int n = nd[p];
      int pos = atomicAdd(&cursor[p*NN + n], 1);
      int4 v;
      v.x = e; v.y = nd[(p+1)%3]; v.z = nd[(p+2)%3]; v.w = n;
      einfo[(size_t)p*NE + start[p*NN + n] + pos] = v;
    }
  }
}

// ---------------- node scores: S[s][n] = x[n] . w1[s*128: s*128+128] ----------------
__global__ void nscore(const unsigned short* __restrict__ xb,
                       const float* __restrict__ W1, float* __restrict__ S){
  __shared__ float w1s[384];
  const int t = threadIdx.x;
  for (int i = t; i < 384; i += 256) w1s[i] = W1[i];
  __syncthreads();
  const int n = blockIdx.x*256 + t;
  if (n >= NN) return;
  float s0 = 0.f, s1 = 0.f, s2 = 0.f;
  for (int k = 0; k < 128; k += 8){
    s16x8 v = *(const s16x8*)(xb + (size_t)n*DD + k);
    #pragma unroll
    for (int u = 0; u < 8; u++){
      float xv = bf2f((unsigned short)v[u]);
      s0 += xv * w1s[k+u];
      s1 += xv * w1s[128+k+u];
      s2 += xv * w1s[256+k+u];
    }
  }
  S[n] = s0; S[NN+n] = s1; S[2*NN+n] = s2;
}

// ------- edge scores: sp[e] = S0[i0]+S1[i1]+S2[i2]; block-reduced sum/sumsq -------
__global__ void escore(const int* __restrict__ twi, const float* __restrict__ S,
                       float* __restrict__ sp, float* __restrict__ stats){
  float lsum = 0.f, lsq = 0.f;
  const int stride = gridDim.x*blockDim.x;
  for (int e = blockIdx.x*blockDim.x + threadIdx.x; e < NE; e += stride){
    float s = S[twi[e]] + S[NN + twi[NE+e]] + S[2*NN + twi[2*NE+e]];
    sp[e] = s;
    lsum += s; lsq += s*s;
  }
  #pragma unroll
  for (int o = 32; o; o >>= 1){ lsum += __shfl_xor(lsum, o); lsq += __shfl_xor(lsq, o); }
  __shared__ float rs[4], rq[4];
  if ((threadIdx.x & 63) == 0){ rs[threadIdx.x >> 6] = lsum; rq[threadIdx.x >> 6] = lsq; }
  __syncthreads();
  if (threadIdx.x == 0){
    atomicAdd(&stats[ST_SUM1], rs[0]+rs[1]+rs[2]+rs[3]);
    atomicAdd(&stats[ST_SQ1],  rq[0]+rq[1]+rq[2]+rq[3]);
  }
}

// --- dense node GEMM, col-tiled: 512 thr / 8 waves / 128 rows per block, B in LDS ---
__launch_bounds__(512)
__global__ void ngemm(const unsigned short* __restrict__ xb,
                      const unsigned short* __restrict__ Wj,   // pre-offset to part j
                      unsigned short* __restrict__ Y){
  __shared__ unsigned short bsh[128*BPAD];   // 33.8 KB: B panel, reused as repack buf
  const int t = threadIdx.x;
  const int w = t >> 6, lane = t & 63;
  const int lc = lane & 15, kg = lane >> 4;
  const int ch = blockIdx.y;                 // 128-col chunk of the 384 outputs
  const int m0 = blockIdx.x*128 + w*16;
  const int arow = m0 + lc;

  // stage B panel: rows = output cols ch*128..+127, each 128 k (256B), padded stride
  for (int i = t; i < 128*16; i += 512){
    const int r = i >> 4, cc = (i & 15) * 8;
    *(s16x8*)(bsh + r*BPAD + cc) = *(const s16x8*)(Wj + (size_t)(ch*128 + r)*DD + cc);
  }
  __syncthreads();

  f32x4 acc[8];
  #pragma unroll
  for (int nf = 0; nf < 8; nf++){ acc[nf][0]=0.f; acc[nf][1]=0.f; acc[nf][2]=0.f; acc[nf][3]=0.f; }
  #pragma unroll
  for (int ks = 0; ks < 4; ks++){
    s16x8 a;
    if (arow < NN) a = *(const s16x8*)(xb + (size_t)arow*DD + ks*32 + kg*8);
    else { a[0]=0;a[1]=0;a[2]=0;a[3]=0;a[4]=0;a[5]=0;a[6]=0;a[7]=0; }
    #pragma unroll
    for (int nf = 0; nf < 8; nf++){
      s16x8 b = *(const s16x8*)(bsh + (nf*16 + lc)*BPAD + ks*32 + kg*8);
      acc[nf] = __builtin_amdgcn_mfma_f32_16x16x32_bf16(a, b, acc[nf], 0, 0, 0);
    }
  }
  __syncthreads();   // all waves done reading B panel; reuse bsh for repack

  unsigned short* ltu = bsh + w*16*BPAD;     // wave-local [16][BPAD] (8 waves fit exactly)
  #pragma unroll
  for (int nf = 0; nf < 8; nf++)
    #pragma unroll
    for (int r = 0; r < 4; r++)
      ltu[(kg*4 + r)*BPAD + nf*16 + lc] = f2bf(acc[nf][r]);
  const int rl = lane >> 5, cg = lane & 31;
  #pragma unroll
  for (int it = 0; it < 8; it++){
    const int row = it*2 + rl;
    const int grow = m0 + row;
    if (grow < NN){
      u16x4 o = *(const u16x4*)&ltu[row*BPAD + cg*4];
      *(u16x4*)(Y + (size_t)grow*D3 + ch*128 + cg*4) = o;
    }
  }
}

// ----- edge stats for part j (node-centric CSR walk, 4 edges/wave-iter) -----
__launch_bounds__(256)
__global__ void estat(const unsigned short* __restrict__ Y,
                      const int4* __restrict__ einfo,
                      const int* __restrict__ cnt, const int* __restrict__ start,
                      float* __restrict__ stats, int j, int a, int b){
  __shared__ float bs[4][128], bq[4][128];
  const int t = threadIdx.x, w = t >> 6, lane = t & 63;
  const int q = lane >> 4, ql = lane & 15;
  const int c0 = ql*8;
  float s[8] = {0,0,0,0,0,0,0,0}, qq[8] = {0,0,0,0,0,0,0,0};
  const int gw = blockIdx.x*4 + w;
  const int nw = gridDim.x*4;
  for (int n = gw; n < NN; n += nw){
    const int c = cnt[j*NN + n];
    if (c == 0) continue;
    const int cs = start[j*NN + n];
    u16x8 lv = *(const u16x8*)(Y + (size_t)n*D3 + j*128 + c0);
    float lf[8];
    #pragma unroll
    for (int u = 0; u < 8; u++) lf[u] = bf2f(lv[u]);
    for (int k = 0; k < c; k += 4){
      const int kk = k + q;
      const bool valid = kk < c;
      const int4 ei = einfo[(size_t)j*NE + cs + (valid ? kk : c-1)];
      u16x8 ga = *(const u16x8*)(Y + (size_t)ei.y*D3 + a*128 + c0);
      u16x8 gb = *(const u16x8*)(Y + (size_t)ei.z*D3 + b*128 + c0);
      if (valid){
        #pragma unroll
        for (int u = 0; u < 8; u++){
          float h = lf[u] + bf2f(ga[u]) + bf2f(gb[u]);
          s[u] += h; qq[u] += h*h;
        }
      }
    }
  }
  #pragma unroll
  for (int u = 0; u < 8; u++){
    s[u]  += __shfl_xor(s[u], 16);  s[u]  += __shfl_xor(s[u], 32);
    qq[u] += __shfl_xor(qq[u], 16); qq[u] += __shfl_xor(qq[u], 32);
  }
  if (q == 0){
    #pragma unroll
    for (int u = 0; u < 8; u++){ bs[w][c0+u] = s[u]; bq[w][c0+u] = qq[u]; }
  }
  __syncthreads();
  if (t < 128){
    atomicAdd(&stats[ST_SUM + j*128 + t], bs[0][t]+bs[1][t]+bs[2][t]+bs[3][t]);
    atomicAdd(&stats[ST_SQ  + j*128 + t], bq[0][t]+bq[1][t]+bq[2][t]+bq[3][t]);
  }
}

// -- node-centric scatter for part j (4 edges/wave-iter): macc[n] += mean --
__launch_bounds__(256)
__global__ void escat(const unsigned short* __restrict__ Y,
                      const int4* __restrict__ einfo,
                      const float* __restrict__ att,
                      const int* __restrict__ cnt, const int* __restrict__ start,
                      const float* __restrict__ stats,
                      float* __restrict__ macc, int j, int a, int b){
  const int w = threadIdx.x >> 6, lane = threadIdx.x & 63;
  const int q = lane >> 4, ql = lane & 15;
  const int n = blockIdx.x*4 + w;
  if (n >= NN) return;
  const int c = cnt[j*NN + n];
  if (c == 0) return;
  const float invZ = 1.0f / stats[ST_SEXP];
  const int cs = start[j*NN + n];
  const int c0 = ql*8;
  u16x8 lv = *(const u16x8*)(Y + (size_t)n*D3 + j*128 + c0);
  float lf[8];
  #pragma unroll
  for (int u = 0; u < 8; u++) lf[u] = bf2f(lv[u]);
  f32x4 scA = *(const f32x4*)(stats + ST_SCALE + j*128 + c0);
  f32x4 scB = *(const f32x4*)(stats + ST_SCALE + j*128 + c0 + 4);
  f32x4 shA = *(const f32x4*)(stats + ST_SHIFT + j*128 + c0);
  f32x4 shB = *(const f32x4*)(stats + ST_SHIFT + j*128 + c0 + 4);
  float sc[8] = {scA[0],scA[1],scA[2],scA[3],scB[0],scB[1],scB[2],scB[3]};
  float sh[8] = {shA[0],shA[1],shA[2],shA[3],shB[0],shB[1],shB[2],shB[3]};
  float acc[8] = {0,0,0,0,0,0,0,0};
  for (int k = 0; k < c; k += 4){
    const int kk = k + q;
    const bool valid = kk < c;
    const int4 ei = einfo[(size_t)j*NE + cs + (valid ? kk : c-1)];
    const float av = valid ? att[ei.x] * invZ : 0.f;
    u16x8 ga = *(const u16x8*)(Y + (size_t)ei.y*D3 + a*128 + c0);
    u16x8 gb = *(const u16x8*)(Y + (size_t)ei.z*D3 + b*128 + c0);
    #pragma unroll
    for (int u = 0; u < 8; u++){
      float h = lf[u] + bf2f(ga[u]) + bf2f(gb[u]);
      acc[u] += av * fmaxf(h*sc[u] + sh[u], 0.f);
    }
  }
  #pragma unroll
  for (int u = 0; u < 8; u++){
    acc[u] += __shfl_xor(acc[u], 16);
    acc[u] += __shfl_xor(acc[u], 32);
  }
  if (q == 0){
    const float ic = 1.f / (float)c;
    f32x4* mp0 = (f32x4*)(macc + (size_t)n*DD + c0);
    f32x4* mp1 = (f32x4*)(macc + (size_t)n*DD + c0 + 4);
    f32x4 o0 = *mp0, o1 = *mp1;
    o0[0] += acc[0]*ic; o0[1] += acc[1]*ic; o0[2] += acc[2]*ic; o0[3] += acc[3]*ic;
    o1[0] += acc[4]*ic; o1[1] += acc[5]*ic; o1[2] += acc[6]*ic; o1[3] += acc[7]*ic;
    *mp0 = o0; *mp1 = o1;
  }
}

// ---------------- BN finalize ----------------
__global__ void sfin_score(const float* g1, const float* be1, float* __restrict__ stats){
  if (threadIdx.x == 0){
    float mu = stats[ST_SUM1] / (float)NE;
    float var = stats[ST_SQ1] / (float)NE - mu*mu;
    float sc = g1[0] * rsqrtf(var + EPSBN);
    stats[ST_SCALE1] = sc;
    stats[ST_SHIFT1] = be1[0] - mu*sc;
  }
}

__global__ void sfin_cols(const float* g, const float* be, float* __restrict__ stats, int part){
  int t = threadIdx.x;
  if (t < 128){
    int idx = part*128 + t;
    float mu = stats[ST_SUM + idx] / (float)NE;
    float var = stats[ST_SQ + idx] / (float)NE - mu*mu;
    float sc = g[t] * rsqrtf(var + EPSBN);
    stats[ST_SCALE + idx] = sc;
    stats[ST_SHIFT + idx] = be[t] - mu*sc;
  }
}

// ---------------- softmax: max, then sum (stores exp in place) ----------------
__global__ void sm_max(float* __restrict__ sp, float* __restrict__ stats){
  const float sc = stats[ST_SCALE1], sh = stats[ST_SHIFT1];
  float lmax = 0.f;
  int stride = gridDim.x*blockDim.x;
  for (int i = blockIdx.x*blockDim.x + threadIdx.x; i < NE; i += stride){
    float s = fmaxf(sp[i]*sc + sh, 0.f);
    sp[i] = s;
    lmax = fmaxf(lmax, s);
  }
  #pragma unroll
  for (int o = 32; o; o >>= 1) lmax = fmaxf(lmax, __shfl_xor(lmax, o));
  __shared__ float red[4];
  if ((threadIdx.x & 63) == 0) red[threadIdx.x >> 6] = lmax;
  __syncthreads();
  if (threadIdx.x == 0){
    float m = fmaxf(fmaxf(red[0], red[1]), fmaxf(red[2], red[3]));
    atomicMax((unsigned int*)&stats[ST_MAX], __float_as_uint(m));
  }
}

__global__ void sm_sum(float* __restrict__ sp, float* __restrict__ stats){
  const float mx = __uint_as_float(((const unsigned int*)stats)[ST_MAX]);
  float ls = 0.f;
  int stride = gridDim.x*blockDim.x;
  for (int i = blockIdx.x*blockDim.x + threadIdx.x; i < NE; i += stride){
    float ex = __expf(sp[i] - mx);
    sp[i] = ex;
    ls += ex;
  }
  #pragma unroll
  for (int o = 32; o; o >>= 1) ls += __shfl_xor(ls, o);
  __shared__ float red[4];
  if ((threadIdx.x & 63) == 0) red[threadIdx.x >> 6] = ls;
  __syncthreads();
  if (threadIdx.x == 0)
    atomicAdd(&stats[ST_SEXP], red[0] + red[1] + red[2] + red[3]);
}

// --- zb = bf16(macc @ Wtw^T): 512 thr / 8 waves / 128 rows, B in LDS, fused stats ---
__launch_bounds__(512)
__global__ void g2_gemm(const float* __restrict__ A,
                        const unsigned short* __restrict__ Wtwb,
                        unsigned short* __restrict__ zb,
                        float* __restrict__ stats){
  __shared__ unsigned short bsh[128*BPAD];   // 33.8 KB: B panel, reused as repack buf
  __shared__ float ssum[128], ssq[128];
  const int t = threadIdx.x;
  const int w = t >> 6, lane = t & 63;
  const int lc = lane & 15, kg = lane >> 4;
  if (t < 128){ ssum[t] = 0.f; ssq[t] = 0.f; }
  const int m0 = blockIdx.x*128 + w*16;
  const int arow = m0 + lc;

  for (int i = t; i < 128*16; i += 512){
    const int r = i >> 4, cc = (i & 15) * 8;
    *(s16x8*)(bsh + r*BPAD + cc) = *(const s16x8*)(Wtwb + (size_t)r*DD + cc);
  }
  __syncthreads();

  f32x4 acc[8];
  #pragma unroll
  for (int nf = 0; nf < 8; nf++){ acc[nf][0]=0.f; acc[nf][1]=0.f; acc[nf][2]=0.f; acc[nf][3]=0.f; }
  #pragma unroll
  for (int ks = 0; ks < 128; ks += 32){
    s16x8 a;
    if (arow < NN){
      f32x4 a0 = *(const f32x4*)(A + (size_t)arow*DD + ks + kg*8);
      f32x4 a1 = *(const f32x4*)(A + (size_t)arow*DD + ks + kg*8 + 4);
      a[0]=(short)f2bf(a0[0]); a[1]=(short)f2bf(a0[1]); a[2]=(short)f2bf(a0[2]); a[3]=(short)f2bf(a0[3]);
      a[4]=(short)f2bf(a1[0]); a[5]=(short)f2bf(a1[1]); a[6]=(short)f2bf(a1[2]); a[7]=(short)f2bf(a1[3]);
    } else {
      a[0]=0;a[1]=0;a[2]=0;a[3]=0;a[4]=0;a[5]=0;a[6]=0;a[7]=0;
    }
    #pragma unroll
    for (int nf = 0; nf < 8; nf++){
      s16x8 b = *(const s16x8*)(bsh + (nf*16 + lc)*BPAD + ks + kg*8);
      acc[nf] = __builtin_amdgcn_mfma_f32_16x16x32_bf16(a, b, acc[nf], 0, 0, 0);
    }
  }
  float ps[8], pq[8];
  #pragma unroll
  for (int nf = 0; nf < 8; nf++){
    ps[nf] = 0.f; pq[nf] = 0.f;
    #pragma unroll
    for (int r = 0; r < 4; r++){
      int row = m0 + kg*4 + r;
      if (row < NN){
        float v = acc[nf][r];
        ps[nf] += v; pq[nf] += v*v;
      }
    }
  }
  __syncthreads();   // done reading B panel; reuse bsh for repack
  #pragma unroll
  for (int nf = 0; nf < 8; nf++){
    atomicAdd(&ssum[nf*16 + lc], ps[nf]);
    atomicAdd(&ssq [nf*16 + lc], pq[nf]);
  }
  unsigned short* ltu = bsh + w*16*BPAD;     // wave-local [16][BPAD] (8 waves fit)
  #pragma unroll
  for (int nf = 0; nf < 8; nf++)
    #pragma unroll
    for (int r = 0; r < 4; r++)
      ltu[(kg*4 + r)*BPAD + nf*16 + lc] = f2bf(acc[nf][r]);
  const int rl = lane >> 5, cg = lane & 31;
  #pragma unroll
  for (int it = 0; it < 8; it++){
    const int row = it*2 + rl;
    const int grow = m0 + row;
    if (grow < NN){
      u16x4 o = *(const u16x4*)&ltu[row*BPAD + cg*4];
      *(u16x4*)(zb + (size_t)grow*DD + cg*4) = o;
    }
  }
  __syncthreads();
  if (t < 128){
    atomicAdd(&stats[ST_SUM2 + t], ssum[t]);
    atomicAdd(&stats[ST_SQ2  + t], ssq[t]);
  }
}

__global__ void sfin2(const float* gtw, const float* betw, float* __restrict__ stats){
  int c = threadIdx.x;
  if (c < 128){
    float mu = stats[ST_SUM2 + c] / (float)NN;
    float var = stats[ST_SQ2 + c] / (float)NN - mu*mu;
    float sc = gtw[c] * rsqrtf(var + EPSBN);
    stats[ST_SCALE2 + c] = sc;
    stats[ST_SHIFT2 + c] = betw[c] - mu*sc;
  }
}

// ---------------- x += relu(BN(zb)); refresh bf16 copy (vectorized) ----------------
__global__ void fuse_update(const unsigned short* __restrict__ zb,
                            const float* __restrict__ stats,
                            float* __restrict__ xcur, unsigned short* __restrict__ xb){
  const int tot = NN*DD/4;
  int stride = gridDim.x*blockDim.x;
  for (int i = blockIdx.x*blockDim.x + threadIdx.x; i < tot; i += stride){
    u16x4 z4 = ((const u16x4*)zb)[i];
    f32x4 x4 = ((const f32x4*)xcur)[i];
    const int c = (i*4) & 127;
    f32x4 o; u16x4 ob;
    #pragma unroll
    for (int j = 0; j < 4; j++){
      float hv = fmaxf(bf2f(z4[j])*stats[ST_SCALE2 + c + j] + stats[ST_SHIFT2 + c + j], 0.f);
      o[j] = x4[j] + hv;
      ob[j] = f2bf(o[j]);
    }
    ((f32x4*)xcur)[i] = o;
    ((u16x4*)xb)[i] = ob;
  }
}

extern "C" void kernel_launch(void* const* d_in, const int* in_sizes, int n_in,
                              void* d_out, int out_size, void* d_ws, size_t ws_size,
                              hipStream_t stream){
  const float* x    = (const float*)d_in[0];
  const int*   twi  = (const int*)d_in[1];
  const float* W_T  = (const float*)d_in[2];
  const float* W_M  = (const float*)d_in[3];
  const float* W_B  = (const float*)d_in[4];
  const float* W_1  = (const float*)d_in[5];
  const float* W_tw = (const float*)d_in[6];
  const float* g_T  = (const float*)d_in[8];
  const float* be_T = (const float*)d_in[9];
  const float* g_M  = (const float*)d_in[11];
  const float* be_M = (const float*)d_in[12];
  const float* g_B  = (const float*)d_in[14];
  const float* be_B = (const float*)d_in[15];
  const float* g_1  = (const float*)d_in[17];
  const float* be_1 = (const float*)d_in[18];
  const float* g_tw = (const float*)d_in[20];
  const float* be_tw= (const float*)d_in[21];
  float* xcur = (float*)d_out;

  char* ws = (char*)d_ws;
  size_t off = 0;
  auto take = [&](size_t b){ size_t o = off; off += (b + 255) & ~(size_t)255; return o; };
  float* stats = (float*)(ws + take(ST_TOTAL*4));
  unsigned short* Wjcat = (unsigned short*)(ws + take((size_t)3*D3*DD*2));
  unsigned short* Wtwb  = (unsigned short*)(ws + take(128*128*2));
  int* bsums  = (int*)(ws + take((size_t)3*SCB*4));
  int* cnt    = (int*)(ws + take((size_t)3*NN*4));
  int* startA = (int*)(ws + take((size_t)3*NN*4));
  int* cursor = (int*)(ws + take((size_t)3*NN*4));
  int4* einfo = (int4*)(ws + take((size_t)3*NE*16));
  float* sp   = (float*)(ws + take((size_t)NE*4));
  float* S    = (float*)(ws + take((size_t)3*NN*4));
  unsigned short* xb = (unsigned short*)(ws + take((size_t)NN*DD*2));
  float* macc = (float*)(ws + take((size_t)NN*DD*4));
  unsigned short* Y = (unsigned short*)(ws + take((size_t)NN*D3*2));
  unsigned short* zb = Y;   // alias: zb written by g2 only after last escat consumed Y
  if (ws_size < off) return;  // avoid faulting

  hipMemsetAsync(cnt, 0, (size_t)3*NN*4, stream);
  hipMemsetAsync(cursor, 0, (size_t)3*NN*4, stream);
  init_x<<<1024, 256, 0, stream>>>(x, xcur, xb);
  csr_cnt<<<(NE+255)/256, 256, 0, stream>>>(twi, cnt);
  scan_bs<<<dim3(SCB, 3), 256, 0, stream>>>(cnt, bsums);
  scan_top<<<1, 64, 0, stream>>>(bsums);
  scan_fin<<<dim3(SCB, 3), 256, 0, stream>>>(cnt, bsums, startA);
  csr_fill<<<(NE+255)/256, 256, 0, stream>>>(twi, startA, cursor, einfo);

  const int NGB2 = (NN + 127)/128;  // 512-thread gemm blocks
  const int NDB = (NN + 3)/4;       // node-wave blocks

  for (int l = 0; l < KL; l++){
    hipMemsetAsync(stats, 0, ST_TOTAL*4, stream);
    hipMemsetAsync(macc, 0, (size_t)NN*DD*4, stream);
    wprep<<<640, 256, 0, stream>>>(W_T + (size_t)l*DD*D3, W_M + (size_t)l*DD*D3,
                                   W_B + (size_t)l*DD*D3, W_tw + (size_t)l*DD*DD,
                                   Wjcat, Wtwb);
    const float* gs[3]  = {g_T  + (size_t)l*DD, g_M  + (size_t)l*DD, g_B  + (size_t)l*DD};
    const float* bes[3] = {be_T + (size_t)l*DD, be_M + (size_t)l*DD, be_B + (size_t)l*DD};

    // score path (node-decomposed)
    nscore<<<(NN+255)/256, 256, 0, stream>>>(xb, W_1 + (size_t)l*D3, S);
    escore<<<256, 256, 0, stream>>>(twi, S, sp, stats);
    sfin_score<<<1, 64, 0, stream>>>(g_1 + l, be_1 + l, stats);
    sm_max<<<256, 256, 0, stream>>>(sp, stats);
    sm_sum<<<256, 256, 0, stream>>>(sp, stats);

    // per-part: dense node GEMM -> edge stats -> BN finalize -> node scatter
    for (int j = 0; j < 3; j++){
      ngemm<<<dim3(NGB2, 3), 512, 0, stream>>>(xb, Wjcat + (size_t)j*D3*DD, Y);
      estat<<<1024, 256, 0, stream>>>(Y, einfo, cnt, startA, stats, j, (j+1)%3, (j+2)%3);
      sfin_cols<<<1, 128, 0, stream>>>(gs[j], bes[j], stats, j);
      escat<<<NDB, 256, 0, stream>>>(Y, einfo, sp, cnt, startA, stats, macc,
                                     j, (j+1)%3, (j+2)%3);
    }

    g2_gemm<<<NGB2, 512, 0, stream>>>(macc, Wtwb, zb, stats);
    sfin2<<<1, 128, 0, stream>>>(g_tw + (size_t)l*DD, be_tw + (size_t)l*DD, stats);
    fuse_update<<<1024, 256, 0, stream>>>(zb, stats, xcur, xb);
  }
}